// Round 1
// baseline (329.305 us; speedup 1.0000x reference)
//
#include <hip/hip_runtime.h>
#include <stdint.h>

#define SEQ   2048
#define NB    2
#define LDQKV 3072
#define HD    128
#define QSCALE 0.08838834764831845f

typedef __attribute__((ext_vector_type(8))) short short8;
typedef __attribute__((ext_vector_type(4))) short short4v;
typedef __attribute__((ext_vector_type(4))) float f32x4;
typedef __attribute__((ext_vector_type(8))) __bf16 bf16x8;

__device__ __forceinline__ float bs2f(short s) {
  unsigned int u = ((unsigned int)(unsigned short)s) << 16;
  return __builtin_bit_cast(float, u);
}
__device__ __forceinline__ short f2bs(float f) {
  unsigned int u = __builtin_bit_cast(unsigned int, f);
  u += 0x7fffu + ((u >> 16) & 1u);
  return (short)(u >> 16);
}
__device__ __forceinline__ f32x4 mfma16(short8 a, short8 b, f32x4 c) {
  return __builtin_amdgcn_mfma_f32_16x16x32_bf16(
      __builtin_bit_cast(bf16x8, a), __builtin_bit_cast(bf16x8, b), c, 0, 0, 0);
}
// global -> LDS direct (wave-uniform LDS base + lane*16). AS casts via integer
// round-trip (LDS generic pointers carry the AS3 offset in the low 32 bits).
__device__ __forceinline__ void gload_lds16(const void* g, void* l) {
  __builtin_amdgcn_global_load_lds(
      (__attribute__((address_space(1))) const void*)(uintptr_t)g,
      (__attribute__((address_space(3))) void*)(unsigned int)(uintptr_t)l,
      16, 0, 0);
}

// ---------------- fp32 -> bf16 convert (vectorized) ----------------
__global__ __launch_bounds__(256) void k_cvt(const float* __restrict__ src,
                                             short* __restrict__ dst, int n8) {
  int i = blockIdx.x * 256 + threadIdx.x;
  if (i >= n8) return;
  f32x4 a = *(const f32x4*)(src + (size_t)i * 8);
  f32x4 b = *(const f32x4*)(src + (size_t)i * 8 + 4);
  short8 o;
#pragma unroll
  for (int j = 0; j < 4; ++j) { o[j] = f2bs(a[j]); o[4 + j] = f2bs(b[j]); }
  *(short8*)(dst + (size_t)i * 8) = o;
}

// ------------- weight transpose: [K][N] fp32 -> [N][K] bf16 -------------
__global__ __launch_bounds__(256) void k_wtrans(const float* __restrict__ src,
                                                short* __restrict__ dst,
                                                int K, int N) {
  __shared__ __align__(16) float tile[64][68];
  int k0 = blockIdx.x * 64, n0 = blockIdx.y * 64;
  int t = threadIdx.x;
#pragma unroll
  for (int rep = 0; rep < 4; ++rep) {
    int lin = rep * 1024 + t * 4;
    int kk = lin >> 6, nn = lin & 63;
    f32x4 v = *(const f32x4*)(src + (size_t)(k0 + kk) * N + n0 + nn);
    *(f32x4*)(&tile[kk][nn]) = v;
  }
  __syncthreads();
#pragma unroll
  for (int rep = 0; rep < 4; ++rep) {
    int lin = rep * 1024 + t * 4;
    int nn = lin >> 6, kk = lin & 63;
    short4v o;
#pragma unroll
    for (int j = 0; j < 4; ++j) o[j] = f2bs(tile[kk + j][nn]);
    *(short4v*)(dst + (size_t)(n0 + nn) * K + k0 + kk) = o;
  }
}

// ---------------- GEMM: C[M][N] = A[M][K] * Bt[N][K]^T ----------------
// 128x128 tile, BK=32, 4 waves (2x2), 16x16x32 bf16 MFMA. global_load_lds
// staging with XOR-swizzled global source (involution on 8-elem k-blocks).
template <int FP32OUT>
__global__ __launch_bounds__(256) void k_gemm_bt(const short* __restrict__ A,
                                                 const short* __restrict__ Bt,
                                                 void* __restrict__ Cp,
                                                 int M, int N, int K) {
  __shared__ short As[128 * 32];
  __shared__ short Bs[128 * 32];
  const int t = threadIdx.x, l = t & 63, w = t >> 6;
  const int wr = w >> 1, wc = w & 1;
  const int m0 = blockIdx.x * 128, n0 = blockIdx.y * 128;
  const int lrow = l & 15, lg = l >> 4;

  f32x4 acc[4][4] = {};

  const int srow0 = (t >> 2);
  const int srow1 = 64 + (t >> 2);
  const int sk0 = (((t & 3) ^ (srow0 & 3)) * 8);
  const int sk1 = (((t & 3) ^ (srow1 & 3)) * 8);
  const short* Ab = A + (size_t)m0 * K;
  const short* Bb = Bt + (size_t)n0 * K;
  short* AsB0 = As + w * 512;
  short* AsB1 = As + 2048 + w * 512;
  short* BsB0 = Bs + w * 512;
  short* BsB1 = Bs + 2048 + w * 512;

  for (int k0 = 0; k0 < K; k0 += 32) {
    gload_lds16(Ab + (size_t)srow0 * K + k0 + sk0, AsB0);
    gload_lds16(Ab + (size_t)srow1 * K + k0 + sk1, AsB1);
    gload_lds16(Bb + (size_t)srow0 * K + k0 + sk0, BsB0);
    gload_lds16(Bb + (size_t)srow1 * K + k0 + sk1, BsB1);
    __syncthreads();
    short8 af[4], bf[4];
#pragma unroll
    for (int mi = 0; mi < 4; ++mi) {
      int r = wr * 64 + mi * 16 + lrow;
      af[mi] = *(const short8*)(As + r * 32 + ((lg ^ (r & 3)) * 8));
    }
#pragma unroll
    for (int ni = 0; ni < 4; ++ni) {
      int r = wc * 64 + ni * 16 + lrow;
      bf[ni] = *(const short8*)(Bs + r * 32 + ((lg ^ (r & 3)) * 8));
    }
#pragma unroll
    for (int mi = 0; mi < 4; ++mi)
#pragma unroll
      for (int ni = 0; ni < 4; ++ni)
        acc[mi][ni] = mfma16(af[mi], bf[ni], acc[mi][ni]);
    __syncthreads();
  }
#pragma unroll
  for (int mi = 0; mi < 4; ++mi)
#pragma unroll
    for (int ni = 0; ni < 4; ++ni) {
      int row = m0 + wr * 64 + mi * 16 + lg * 4;
      int col = n0 + wc * 64 + ni * 16 + lrow;
#pragma unroll
      for (int v = 0; v < 4; ++v) {
        float val = acc[mi][ni][v];
        if constexpr (FP32OUT)
          ((float*)Cp)[(size_t)(row + v) * N + col] = val;
        else
          ((short*)Cp)[(size_t)(row + v) * N + col] = f2bs(val);
      }
    }
}

// ---------------- RoPE (in-place on q,k slices of qkv; q also *1/sqrt(D)) ---
__global__ __launch_bounds__(256) void k_rope(short* __restrict__ qkv,
                                              const float* __restrict__ fcos,
                                              const float* __restrict__ fsin) {
  int tid = blockIdx.x * 256 + threadIdx.x;  // total NB*SEQ*20*16
  int p16 = tid & 15;
  int slice = (tid >> 4) % 20;
  int bs = tid / 320;
  int col = (slice < 16) ? slice * 128 + p16 * 8
                         : 2048 + (slice - 16) * 128 + p16 * 8;
  short8 x = *(short8*)(qkv + (size_t)bs * LDQKV + col);
  f32x4 c = *(const f32x4*)(fcos + (size_t)bs * 64 + p16 * 4);
  f32x4 s = *(const f32x4*)(fsin + (size_t)bs * 64 + p16 * 4);
  float sc = (slice < 16) ? QSCALE : 1.0f;
  short8 o;
#pragma unroll
  for (int j = 0; j < 4; ++j) {
    float xr = bs2f(x[2 * j]), xi = bs2f(x[2 * j + 1]);
    o[2 * j] = f2bs((xr * c[j] - xi * s[j]) * sc);
    o[2 * j + 1] = f2bs((xr * s[j] + xi * c[j]) * sc);
  }
  *(short8*)(qkv + (size_t)bs * LDQKV + col) = o;
}

// ------------- V transpose: qkv v-slice [s][d] -> vt [b][kvh][d][s] ---------
__global__ __launch_bounds__(256) void k_vtrans(const short* __restrict__ qkv,
                                                short* __restrict__ vt) {
  __shared__ short tile[128 * 137];
  int s0 = blockIdx.x * 128;
  int kvh = blockIdx.y, b = blockIdx.z;
  int t = threadIdx.x;
  const short* src = qkv + (size_t)(b * SEQ) * LDQKV + 2560 + kvh * 128;
#pragma unroll
  for (int rep = 0; rep < 8; ++rep) {
    int lin = rep * 2048 + t * 8;
    int si = lin >> 7, d = lin & 127;
    short8 v = *(const short8*)(src + (size_t)(s0 + si) * LDQKV + d);
#pragma unroll
    for (int j = 0; j < 8; ++j) tile[si * 137 + d + j] = v[j];
  }
  __syncthreads();
  short* dst = vt + (size_t)((b * 4 + kvh) * 128) * SEQ;
#pragma unroll
  for (int rep = 0; rep < 8; ++rep) {
    int lin = rep * 2048 + t * 8;
    int d = lin >> 7, sb = lin & 127;
    short8 o;
#pragma unroll
    for (int j = 0; j < 8; ++j) o[j] = tile[(sb + j) * 137 + d];
    *(short8*)(dst + (size_t)d * SEQ + s0 + sb) = o;
  }
}

// ---------------- flash attention (causal, GQA) ----------------
// grid (S/64, 16, 2); 4 waves x 16 q-rows. K/V tiles of 64 staged with
// swizzled global_load_lds; P via padded LDS; online softmax in fp32.
__global__ __launch_bounds__(256) void k_attn(const short* __restrict__ qkv,
                                              const short* __restrict__ vt,
                                              short* __restrict__ outp) {
  __shared__ short Ks[64 * 128];
  __shared__ short Vs[128 * 64];
  __shared__ short Ps[4][16 * 72];
  const int t = threadIdx.x, l = t & 63, w = t >> 6;
  const int qt = blockIdx.x, h = blockIdx.y, b = blockIdx.z;
  const int kvh = h >> 2;
  const int q0 = qt * 64;
  const int lrow = l & 15, lg = l >> 4;

  short8 qf[4];
  const short* qrow =
      qkv + (size_t)(b * SEQ + q0 + w * 16 + lrow) * LDQKV + h * HD;
#pragma unroll
  for (int kk = 0; kk < 4; ++kk)
    qf[kk] = *(const short8*)(qrow + kk * 32 + lg * 8);

  f32x4 of[8] = {};
  float mrun[4], lrun[4];
#pragma unroll
  for (int v = 0; v < 4; ++v) { mrun[v] = -3.0e38f; lrun[v] = 0.f; }

  const int kkey = (t >> 4);  // 0..15 (+16*i)
  const int kd8 = (t & 15);
  const int vdd = (t >> 3);   // 0..31 (+32*i)
  const int vs8 = (t & 7);
  const short* kbase = qkv + (size_t)(b * SEQ) * LDQKV + 2048 + kvh * HD;
  const short* vbase = vt + (size_t)((b * 4 + kvh) * 128) * SEQ;
  short* KsB = Ks + w * 512;
  short* VsB = Vs + w * 512;

  const int nt = qt + 1;
  for (int it = 0; it < nt; ++it) {
    const int kt = it * 64;
    __syncthreads();
#pragma unroll
    for (int i = 0; i < 4; ++i) {
      int key = i * 16 + kkey;
      int sd = (kd8 ^ (key & 7)) * 8;
      gload_lds16(kbase + (size_t)(kt + key) * LDQKV + sd, KsB + i * 2048);
    }
#pragma unroll
    for (int i = 0; i < 4; ++i) {
      int d = i * 32 + vdd;
      int ss = (vs8 ^ (d & 7)) * 8;
      gload_lds16(vbase + (size_t)d * SEQ + kt + ss, VsB + i * 2048);
    }
    __syncthreads();

    // QK^T
    f32x4 sc[4] = {};
#pragma unroll
    for (int kk = 0; kk < 4; ++kk) {
      int d0 = kk * 32 + lg * 8;
#pragma unroll
      for (int ni = 0; ni < 4; ++ni) {
        int key = ni * 16 + lrow;
        short8 kf = *(const short8*)(Ks + key * 128 + (d0 ^ (8 * (key & 7))));
        sc[ni] = mfma16(qf[kk], kf, sc[ni]);
      }
    }

    const bool diag = (kt == q0);
    const int rowb = q0 + w * 16 + lg * 4;
    float mnew[4];
#pragma unroll
    for (int v = 0; v < 4; ++v) {
      if (diag) {
#pragma unroll
        for (int ni = 0; ni < 4; ++ni) {
          int key = kt + ni * 16 + lrow;
          if (key > rowb + v) sc[ni][v] = -1e30f;
        }
      }
      float mx = fmaxf(fmaxf(sc[0][v], sc[1][v]), fmaxf(sc[2][v], sc[3][v]));
      mx = fmaxf(mx, __shfl_xor(mx, 1, 16));
      mx = fmaxf(mx, __shfl_xor(mx, 2, 16));
      mx = fmaxf(mx, __shfl_xor(mx, 4, 16));
      mx = fmaxf(mx, __shfl_xor(mx, 8, 16));
      mnew[v] = mx;
    }
    float rs[4];
#pragma unroll
    for (int v = 0; v < 4; ++v) {
      float mm = fmaxf(mrun[v], mnew[v]);
      rs[v] = __expf(mrun[v] - mm);
      mrun[v] = mm;
    }
    float rowsum[4] = {0.f, 0.f, 0.f, 0.f};
#pragma unroll
    for (int ni = 0; ni < 4; ++ni) {
#pragma unroll
      for (int v = 0; v < 4; ++v) {
        float p = __expf(sc[ni][v] - mrun[v]);
        rowsum[v] += p;
        Ps[w][(lg * 4 + v) * 72 + ni * 16 + lrow] = f2bs(p);
      }
    }
#pragma unroll
    for (int v = 0; v < 4; ++v) {
      float s = rowsum[v];
      s += __shfl_xor(s, 1, 16);
      s += __shfl_xor(s, 2, 16);
      s += __shfl_xor(s, 4, 16);
      s += __shfl_xor(s, 8, 16);
      lrun[v] = lrun[v] * rs[v] + s;
    }
#pragma unroll
    for (int ni = 0; ni < 8; ++ni)
#pragma unroll
      for (int v = 0; v < 4; ++v) of[ni][v] *= rs[v];
    __syncthreads();  // P visible + LDS fence
    // PV
#pragma unroll
    for (int kk = 0; kk < 2; ++kk) {
      short8 pa = *(const short8*)(&Ps[w][lrow * 72 + kk * 32 + lg * 8]);
#pragma unroll
      for (int ni = 0; ni < 8; ++ni) {
        int d = ni * 16 + lrow;
        short8 vf =
            *(const short8*)(Vs + d * 64 + ((kk * 32 + lg * 8) ^ (8 * (d & 7))));
        of[ni] = mfma16(pa, vf, of[ni]);
      }
    }
  }
  short* ob = outp + (size_t)(b * SEQ + q0 + w * 16 + lg * 4) * 2048 + h * HD;
#pragma unroll
  for (int v = 0; v < 4; ++v) {
    float inv = 1.0f / lrun[v];
#pragma unroll
    for (int ni = 0; ni < 8; ++ni)
      ob[(size_t)v * 2048 + ni * 16 + lrow] = f2bs(of[ni][v] * inv);
  }
}

extern "C" void kernel_launch(void* const* d_in, const int* in_sizes, int n_in,
                              void* d_out, int out_size, void* d_ws,
                              size_t ws_size, hipStream_t stream) {
  const float* x = (const float*)d_in[0];
  const float* wq = (const float*)d_in[1];
  const float* wk = (const float*)d_in[2];
  const float* wv = (const float*)d_in[3];
  const float* wo = (const float*)d_in[4];
  const float* fc = (const float*)d_in[5];
  const float* fs = (const float*)d_in[6];

  char* ws = (char*)d_ws;
  short* xb = (short*)(ws);                           // [4096][2048] 16MB
  short* wT = (short*)(ws + (16ull << 20));           // [3072][2048] 12MB
  short* woT = (short*)(ws + (28ull << 20));          // [2048][2048] 8MB
  short* qkvb = (short*)(ws + (36ull << 20));         // [4096][3072] 24MB
  short* vtb = (short*)(ws + (16ull << 20));          // alias wT (dead) 4MB
  short* attn = (short*)(ws);                         // alias xb (dead) 16MB

  k_cvt<<<4096, 256, 0, stream>>>(x, xb, 1048576);
  k_wtrans<<<dim3(32, 32), 256, 0, stream>>>(wq, wT, 2048, 2048);
  k_wtrans<<<dim3(32, 8), 256, 0, stream>>>(wk, wT + (size_t)2048 * 2048, 2048, 512);
  k_wtrans<<<dim3(32, 8), 256, 0, stream>>>(wv, wT + (size_t)2560 * 2048, 2048, 512);
  k_wtrans<<<dim3(32, 32), 256, 0, stream>>>(wo, woT, 2048, 2048);
  k_gemm_bt<0><<<dim3(32, 24), 256, 0, stream>>>(xb, wT, qkvb, 4096, 3072, 2048);
  k_rope<<<5120, 256, 0, stream>>>(qkvb, fc, fs);
  k_vtrans<<<dim3(16, 4, 2), 256, 0, stream>>>(qkvb, vtb);
  k_attn<<<dim3(32, 16, 2), 256, 0, stream>>>(qkvb, vtb, attn);
  k_gemm_bt<1><<<dim3(32, 16), 256, 0, stream>>>(attn, woT, d_out, 4096, 2048, 2048);
}

// Round 2
// 266.878 us; speedup vs baseline: 1.2339x; 1.2339x over previous
//
#include <hip/hip_runtime.h>
#include <stdint.h>

#define SEQ   2048
#define NB    2
#define LDQKV 3072
#define HD    128
#define QSCALE 0.08838834764831845f

typedef __attribute__((ext_vector_type(8))) short short8;
typedef __attribute__((ext_vector_type(4))) short short4v;
typedef __attribute__((ext_vector_type(4))) float f32x4;
typedef __attribute__((ext_vector_type(8))) __bf16 bf16x8;

__device__ __forceinline__ float bs2f(short s) {
  unsigned int u = ((unsigned int)(unsigned short)s) << 16;
  return __builtin_bit_cast(float, u);
}
__device__ __forceinline__ short f2bs(float f) {
  unsigned int u = __builtin_bit_cast(unsigned int, f);
  u += 0x7fffu + ((u >> 16) & 1u);
  return (short)(u >> 16);
}
__device__ __forceinline__ f32x4 mfma16(short8 a, short8 b, f32x4 c) {
  return __builtin_amdgcn_mfma_f32_16x16x32_bf16(
      __builtin_bit_cast(bf16x8, a), __builtin_bit_cast(bf16x8, b), c, 0, 0, 0);
}
// global -> LDS direct (wave-uniform LDS base + lane*16).
__device__ __forceinline__ void gload_lds16(const void* g, void* l) {
  __builtin_amdgcn_global_load_lds(
      (__attribute__((address_space(1))) const void*)(uintptr_t)g,
      (__attribute__((address_space(3))) void*)(unsigned int)(uintptr_t)l,
      16, 0, 0);
}

// ---------------- fp32 -> bf16 convert (vectorized) ----------------
__global__ __launch_bounds__(256) void k_cvt(const float* __restrict__ src,
                                             short* __restrict__ dst, int n8) {
  int i = blockIdx.x * 256 + threadIdx.x;
  if (i >= n8) return;
  f32x4 a = *(const f32x4*)(src + (size_t)i * 8);
  f32x4 b = *(const f32x4*)(src + (size_t)i * 8 + 4);
  short8 o;
#pragma unroll
  for (int j = 0; j < 4; ++j) { o[j] = f2bs(a[j]); o[4 + j] = f2bs(b[j]); }
  *(short8*)(dst + (size_t)i * 8) = o;
}

// ------------- weight transpose: [K][N] fp32 -> [N][K] bf16 -------------
__global__ __launch_bounds__(256) void k_wtrans(const float* __restrict__ src,
                                                short* __restrict__ dst,
                                                int K, int N) {
  __shared__ __align__(16) float tile[64][68];
  int k0 = blockIdx.x * 64, n0 = blockIdx.y * 64;
  int t = threadIdx.x;
#pragma unroll
  for (int rep = 0; rep < 4; ++rep) {
    int lin = rep * 1024 + t * 4;
    int kk = lin >> 6, nn = lin & 63;
    f32x4 v = *(const f32x4*)(src + (size_t)(k0 + kk) * N + n0 + nn);
    *(f32x4*)(&tile[kk][nn]) = v;
  }
  __syncthreads();
#pragma unroll
  for (int rep = 0; rep < 4; ++rep) {
    int lin = rep * 1024 + t * 4;
    int nn = lin >> 6, kk = lin & 63;
    short4v o;
#pragma unroll
    for (int j = 0; j < 4; ++j) o[j] = f2bs(tile[kk + j][nn]);
    *(short4v*)(dst + (size_t)(n0 + nn) * K + k0 + kk) = o;
  }
}

// ---------------- GEMM: C[M][N] = A[M][K] * Bt[N][K]^T ----------------
template <int FP32OUT>
__global__ __launch_bounds__(256) void k_gemm_bt(const short* __restrict__ A,
                                                 const short* __restrict__ Bt,
                                                 void* __restrict__ Cp,
                                                 int M, int N, int K) {
  __shared__ short As[128 * 32];
  __shared__ short Bs[128 * 32];
  const int t = threadIdx.x, l = t & 63, w = t >> 6;
  const int wr = w >> 1, wc = w & 1;
  const int m0 = blockIdx.x * 128, n0 = blockIdx.y * 128;
  const int lrow = l & 15, lg = l >> 4;

  f32x4 acc[4][4] = {};

  const int srow0 = (t >> 2);
  const int srow1 = 64 + (t >> 2);
  const int sk0 = (((t & 3) ^ (srow0 & 3)) * 8);
  const int sk1 = (((t & 3) ^ (srow1 & 3)) * 8);
  const short* Ab = A + (size_t)m0 * K;
  const short* Bb = Bt + (size_t)n0 * K;
  short* AsB0 = As + w * 512;
  short* AsB1 = As + 2048 + w * 512;
  short* BsB0 = Bs + w * 512;
  short* BsB1 = Bs + 2048 + w * 512;

  for (int k0 = 0; k0 < K; k0 += 32) {
    gload_lds16(Ab + (size_t)srow0 * K + k0 + sk0, AsB0);
    gload_lds16(Ab + (size_t)srow1 * K + k0 + sk1, AsB1);
    gload_lds16(Bb + (size_t)srow0 * K + k0 + sk0, BsB0);
    gload_lds16(Bb + (size_t)srow1 * K + k0 + sk1, BsB1);
    __syncthreads();
    short8 af[4], bf[4];
#pragma unroll
    for (int mi = 0; mi < 4; ++mi) {
      int r = wr * 64 + mi * 16 + lrow;
      af[mi] = *(const short8*)(As + r * 32 + ((lg ^ (r & 3)) * 8));
    }
#pragma unroll
    for (int ni = 0; ni < 4; ++ni) {
      int r = wc * 64 + ni * 16 + lrow;
      bf[ni] = *(const short8*)(Bs + r * 32 + ((lg ^ (r & 3)) * 8));
    }
#pragma unroll
    for (int mi = 0; mi < 4; ++mi)
#pragma unroll
      for (int ni = 0; ni < 4; ++ni)
        acc[mi][ni] = mfma16(af[mi], bf[ni], acc[mi][ni]);
    __syncthreads();
  }
#pragma unroll
  for (int mi = 0; mi < 4; ++mi)
#pragma unroll
    for (int ni = 0; ni < 4; ++ni) {
      int row = m0 + wr * 64 + mi * 16 + lg * 4;
      int col = n0 + wc * 64 + ni * 16 + lrow;
#pragma unroll
      for (int v = 0; v < 4; ++v) {
        float val = acc[mi][ni][v];
        if constexpr (FP32OUT)
          ((float*)Cp)[(size_t)(row + v) * N + col] = val;
        else
          ((short*)Cp)[(size_t)(row + v) * N + col] = f2bs(val);
      }
    }
}

// ---------------- RoPE (in-place on q,k slices of qkv; q also *1/sqrt(D)) ---
__global__ __launch_bounds__(256) void k_rope(short* __restrict__ qkv,
                                              const float* __restrict__ fcos,
                                              const float* __restrict__ fsin) {
  int tid = blockIdx.x * 256 + threadIdx.x;  // total NB*SEQ*20*16
  int p16 = tid & 15;
  int slice = (tid >> 4) % 20;
  int bs = tid / 320;
  int col = (slice < 16) ? slice * 128 + p16 * 8
                         : 2048 + (slice - 16) * 128 + p16 * 8;
  short8 x = *(short8*)(qkv + (size_t)bs * LDQKV + col);
  f32x4 c = *(const f32x4*)(fcos + (size_t)bs * 64 + p16 * 4);
  f32x4 s = *(const f32x4*)(fsin + (size_t)bs * 64 + p16 * 4);
  float sc = (slice < 16) ? QSCALE : 1.0f;
  short8 o;
#pragma unroll
  for (int j = 0; j < 4; ++j) {
    float xr = bs2f(x[2 * j]), xi = bs2f(x[2 * j + 1]);
    o[2 * j] = f2bs((xr * c[j] - xi * s[j]) * sc);
    o[2 * j + 1] = f2bs((xr * s[j] + xi * c[j]) * sc);
  }
  *(short8*)(qkv + (size_t)bs * LDQKV + col) = o;
}

// ------------- V transpose: qkv v-slice [s][d] -> vt [b][kvh][d][s] ---------
__global__ __launch_bounds__(256) void k_vtrans(const short* __restrict__ qkv,
                                                short* __restrict__ vt) {
  __shared__ short tile[128 * 137];
  int s0 = blockIdx.x * 128;
  int kvh = blockIdx.y, b = blockIdx.z;
  int t = threadIdx.x;
  const short* src = qkv + (size_t)(b * SEQ) * LDQKV + 2560 + kvh * 128;
#pragma unroll
  for (int rep = 0; rep < 8; ++rep) {
    int lin = rep * 2048 + t * 8;
    int si = lin >> 7, d = lin & 127;
    short8 v = *(const short8*)(src + (size_t)(s0 + si) * LDQKV + d);
#pragma unroll
    for (int j = 0; j < 8; ++j) tile[si * 137 + d + j] = v[j];
  }
  __syncthreads();
  short* dst = vt + (size_t)((b * 4 + kvh) * 128) * SEQ;
#pragma unroll
  for (int rep = 0; rep < 8; ++rep) {
    int lin = rep * 2048 + t * 8;
    int d = lin >> 7, sb = lin & 127;
    short8 o;
#pragma unroll
    for (int j = 0; j < 8; ++j) o[j] = tile[(sb + j) * 137 + d];
    *(short8*)(dst + (size_t)d * SEQ + s0 + sb) = o;
  }
}

// ---------------- flash attention (causal, GQA) ----------------
// grid (16, 16, 2); Q-tile 128 rows, 4 waves x 32 rows (2x16 strips).
// K/V double-buffered (stage issued at top of iter, drained by the single
// end-of-iter __syncthreads -> loads in flight under compute). qt mapped
// b-complementary so co-resident blocks have complementary work.
__global__ __launch_bounds__(256, 2) void k_attn(const short* __restrict__ qkv,
                                                 const short* __restrict__ vt,
                                                 short* __restrict__ outp) {
  __shared__ short Ks[2][64 * 128];
  __shared__ short Vs[2][128 * 64];
  __shared__ short Ps[4][32 * 64];
  const int t = threadIdx.x, l = t & 63, w = t >> 6;
  const int h = blockIdx.y, b = blockIdx.z;
  const int qt = b ? blockIdx.x : (15 - blockIdx.x);
  const int kvh = h >> 2;
  const int q0 = qt * 128;
  const int lrow = l & 15, lg = l >> 4;

  short8 qf[2][4];
#pragma unroll
  for (int mi = 0; mi < 2; ++mi) {
    const short* qrow =
        qkv + (size_t)(b * SEQ + q0 + w * 32 + mi * 16 + lrow) * LDQKV + h * HD;
#pragma unroll
    for (int kk = 0; kk < 4; ++kk)
      qf[mi][kk] = *(const short8*)(qrow + kk * 32 + lg * 8);
  }

  f32x4 of[2][8] = {};
  float mrun[2][4], lrun[2][4];
#pragma unroll
  for (int mi = 0; mi < 2; ++mi)
#pragma unroll
    for (int v = 0; v < 4; ++v) { mrun[mi][v] = -3.0e38f; lrun[mi][v] = 0.f; }

  const int kkey = t >> 4, kd8 = t & 15;
  const int vdd = t >> 3, vs8 = t & 7;
  const short* kbase = qkv + (size_t)(b * SEQ) * LDQKV + 2048 + kvh * HD;
  const short* vbase = vt + (size_t)((b * 4 + kvh) * 128) * SEQ;

  auto stageKV = [&](int buf, int it) {
    const int kt = it * 64;
    short* kdst = &Ks[buf][w * 512];
    short* vdst = &Vs[buf][w * 512];
#pragma unroll
    for (int i = 0; i < 4; ++i) {
      int key = i * 16 + kkey;
      int sd = (kd8 ^ (key & 7)) * 8;
      gload_lds16(kbase + (size_t)(kt + key) * LDQKV + sd, kdst + i * 2048);
    }
#pragma unroll
    for (int i = 0; i < 4; ++i) {
      int d = i * 32 + vdd;
      int ss = (vs8 ^ (d & 7)) * 8;
      gload_lds16(vbase + (size_t)d * SEQ + kt + ss, vdst + i * 2048);
    }
  };

  const int nt = 2 * qt + 2;
  stageKV(0, 0);
  __syncthreads();

  for (int it = 0; it < nt; ++it) {
    const int cur = it & 1;
    if (it + 1 < nt) stageKV(cur ^ 1, it + 1);  // prefetch: drained at barrier
    const int kt = it * 64;
    const short* KsC = Ks[cur];
    const short* VsC = Vs[cur];

    // QK^T: 16 K-frag reads feed 32 MFMAs (reused across both strips)
    f32x4 sc[2][4] = {};
#pragma unroll
    for (int ni = 0; ni < 4; ++ni) {
      int key = ni * 16 + lrow;
#pragma unroll
      for (int kk = 0; kk < 4; ++kk) {
        int d0 = kk * 32 + lg * 8;
        short8 kf = *(const short8*)(KsC + key * 128 + (d0 ^ (8 * (key & 7))));
        sc[0][ni] = mfma16(qf[0][kk], kf, sc[0][ni]);
        sc[1][ni] = mfma16(qf[1][kk], kf, sc[1][ni]);
      }
    }

    const bool diag = (it >= nt - 2);
#pragma unroll
    for (int mi = 0; mi < 2; ++mi) {
      const int rowb = q0 + w * 32 + mi * 16 + lg * 4;
      float mnew[4];
#pragma unroll
      for (int v = 0; v < 4; ++v) {
        if (diag) {
#pragma unroll
          for (int ni = 0; ni < 4; ++ni) {
            int key = kt + ni * 16 + lrow;
            if (key > rowb + v) sc[mi][ni][v] = -1e30f;
          }
        }
        float mx = fmaxf(fmaxf(sc[mi][0][v], sc[mi][1][v]),
                         fmaxf(sc[mi][2][v], sc[mi][3][v]));
        mx = fmaxf(mx, __shfl_xor(mx, 1, 16));
        mx = fmaxf(mx, __shfl_xor(mx, 2, 16));
        mx = fmaxf(mx, __shfl_xor(mx, 4, 16));
        mx = fmaxf(mx, __shfl_xor(mx, 8, 16));
        mnew[v] = mx;
      }
      float rs[4];
#pragma unroll
      for (int v = 0; v < 4; ++v) {
        float mm = fmaxf(mrun[mi][v], mnew[v]);
        rs[v] = __expf(mrun[mi][v] - mm);
        mrun[mi][v] = mm;
      }
      float rowsum[4] = {0.f, 0.f, 0.f, 0.f};
#pragma unroll
      for (int ni = 0; ni < 4; ++ni) {
#pragma unroll
        for (int v = 0; v < 4; ++v) {
          float p = __expf(sc[mi][ni][v] - mrun[mi][v]);
          rowsum[v] += p;
          int r = mi * 16 + lg * 4 + v;
          Ps[w][r * 64 + ((ni * 16 + lrow) ^ (8 * (r & 7)))] = f2bs(p);
        }
      }
#pragma unroll
      for (int v = 0; v < 4; ++v) {
        float s = rowsum[v];
        s += __shfl_xor(s, 1, 16);
        s += __shfl_xor(s, 2, 16);
        s += __shfl_xor(s, 4, 16);
        s += __shfl_xor(s, 8, 16);
        lrun[mi][v] = lrun[mi][v] * rs[v] + s;
      }
#pragma unroll
      for (int ni = 0; ni < 8; ++ni)
#pragma unroll
        for (int v = 0; v < 4; ++v) of[mi][ni][v] *= rs[v];
    }

    // PV: P is wave-private LDS -> no barrier needed before reading it back
    short8 pa[2][2];
#pragma unroll
    for (int mi = 0; mi < 2; ++mi)
#pragma unroll
      for (int kk = 0; kk < 2; ++kk)
        pa[mi][kk] = *(const short8*)(&Ps[w][(mi * 16 + lrow) * 64 +
                                             ((kk * 32 + lg * 8) ^
                                              (8 * (lrow & 7)))]);
#pragma unroll
    for (int kk = 0; kk < 2; ++kk)
#pragma unroll
      for (int ni = 0; ni < 8; ++ni) {
        int d = ni * 16 + lrow;
        short8 vf = *(const short8*)(VsC + d * 64 +
                                     ((kk * 32 + lg * 8) ^ (8 * (d & 7))));
        of[0][ni] = mfma16(pa[0][kk], vf, of[0][ni]);
        of[1][ni] = mfma16(pa[1][kk], vf, of[1][ni]);
      }
    __syncthreads();  // drains prefetch vmcnt + fences buffer swap
  }

#pragma unroll
  for (int mi = 0; mi < 2; ++mi) {
    short* ob = outp +
                (size_t)(b * SEQ + q0 + w * 32 + mi * 16 + lg * 4) * 2048 +
                h * HD;
#pragma unroll
    for (int v = 0; v < 4; ++v) {
      float inv = 1.0f / lrun[mi][v];
#pragma unroll
      for (int ni = 0; ni < 8; ++ni)
        ob[(size_t)v * 2048 + ni * 16 + lrow] = f2bs(of[mi][ni][v] * inv);
    }
  }
}

extern "C" void kernel_launch(void* const* d_in, const int* in_sizes, int n_in,
                              void* d_out, int out_size, void* d_ws,
                              size_t ws_size, hipStream_t stream) {
  const float* x = (const float*)d_in[0];
  const float* wq = (const float*)d_in[1];
  const float* wk = (const float*)d_in[2];
  const float* wv = (const float*)d_in[3];
  const float* wo = (const float*)d_in[4];
  const float* fc = (const float*)d_in[5];
  const float* fs = (const float*)d_in[6];

  char* ws = (char*)d_ws;
  short* xb = (short*)(ws);                           // [4096][2048] 16MB
  short* wT = (short*)(ws + (16ull << 20));           // [3072][2048] 12MB
  short* woT = (short*)(ws + (28ull << 20));          // [2048][2048] 8MB
  short* qkvb = (short*)(ws + (36ull << 20));         // [4096][3072] 24MB
  short* vtb = (short*)(ws + (16ull << 20));          // alias wT (dead) 4MB
  short* attn = (short*)(ws);                         // alias xb (dead) 16MB

  k_cvt<<<4096, 256, 0, stream>>>(x, xb, 1048576);
  k_wtrans<<<dim3(32, 32), 256, 0, stream>>>(wq, wT, 2048, 2048);
  k_wtrans<<<dim3(32, 8), 256, 0, stream>>>(wk, wT + (size_t)2048 * 2048, 2048, 512);
  k_wtrans<<<dim3(32, 8), 256, 0, stream>>>(wv, wT + (size_t)2560 * 2048, 2048, 512);
  k_wtrans<<<dim3(32, 32), 256, 0, stream>>>(wo, woT, 2048, 2048);
  k_gemm_bt<0><<<dim3(32, 24), 256, 0, stream>>>(xb, wT, qkvb, 4096, 3072, 2048);
  k_rope<<<5120, 256, 0, stream>>>(qkvb, fc, fs);
  k_vtrans<<<dim3(16, 4, 2), 256, 0, stream>>>(qkvb, vtb);
  k_attn<<<dim3(16, 16, 2), 256, 0, stream>>>(qkvb, vtb, attn);
  k_gemm_bt<1><<<dim3(32, 16), 256, 0, stream>>>(attn, woT, d_out, 4096, 2048, 2048);
}

// Round 3
// 251.376 us; speedup vs baseline: 1.3100x; 1.0617x over previous
//
#include <hip/hip_runtime.h>
#include <stdint.h>

#define SEQ   2048
#define NB    2
#define LDQKV 3072
#define HD    128
// 1/sqrt(128) * log2(e): QK^T scores land in base-2 domain -> exp2 directly.
#define QSCALE2 (0.08838834764831845f * 1.44269504088896340f)

typedef __attribute__((ext_vector_type(8))) short short8;
typedef __attribute__((ext_vector_type(4))) short short4v;
typedef __attribute__((ext_vector_type(4))) float f32x4;
typedef __attribute__((ext_vector_type(8))) __bf16 bf16x8;

__device__ __forceinline__ float bs2f(short s) {
  unsigned int u = ((unsigned int)(unsigned short)s) << 16;
  return __builtin_bit_cast(float, u);
}
__device__ __forceinline__ short f2bs(float f) {
  unsigned int u = __builtin_bit_cast(unsigned int, f);
  u += 0x7fffu + ((u >> 16) & 1u);
  return (short)(u >> 16);
}
__device__ __forceinline__ f32x4 mfma16(short8 a, short8 b, f32x4 c) {
  return __builtin_amdgcn_mfma_f32_16x16x32_bf16(
      __builtin_bit_cast(bf16x8, a), __builtin_bit_cast(bf16x8, b), c, 0, 0, 0);
}
__device__ __forceinline__ void gload_lds16(const void* g, void* l) {
  __builtin_amdgcn_global_load_lds(
      (__attribute__((address_space(1))) const void*)(uintptr_t)g,
      (__attribute__((address_space(3))) void*)(unsigned int)(uintptr_t)l,
      16, 0, 0);
}

// ---------------- fp32 -> bf16 convert (vectorized) ----------------
__global__ __launch_bounds__(256) void k_cvt(const float* __restrict__ src,
                                             short* __restrict__ dst, int n8) {
  int i = blockIdx.x * 256 + threadIdx.x;
  if (i >= n8) return;
  f32x4 a = *(const f32x4*)(src + (size_t)i * 8);
  f32x4 b = *(const f32x4*)(src + (size_t)i * 8 + 4);
  short8 o;
#pragma unroll
  for (int j = 0; j < 4; ++j) { o[j] = f2bs(a[j]); o[4 + j] = f2bs(b[j]); }
  *(short8*)(dst + (size_t)i * 8) = o;
}

// ------------- weight transpose: [K][N] fp32 -> [N][K] bf16 -------------
__global__ __launch_bounds__(256) void k_wtrans(const float* __restrict__ src,
                                                short* __restrict__ dst,
                                                int K, int N) {
  __shared__ __align__(16) float tile[64][68];
  int k0 = blockIdx.x * 64, n0 = blockIdx.y * 64;
  int t = threadIdx.x;
#pragma unroll
  for (int rep = 0; rep < 4; ++rep) {
    int lin = rep * 1024 + t * 4;
    int kk = lin >> 6, nn = lin & 63;
    f32x4 v = *(const f32x4*)(src + (size_t)(k0 + kk) * N + n0 + nn);
    *(f32x4*)(&tile[kk][nn]) = v;
  }
  __syncthreads();
#pragma unroll
  for (int rep = 0; rep < 4; ++rep) {
    int lin = rep * 1024 + t * 4;
    int nn = lin >> 6, kk = lin & 63;
    short4v o;
#pragma unroll
    for (int j = 0; j < 4; ++j) o[j] = f2bs(tile[kk + j][nn]);
    *(short4v*)(dst + (size_t)(n0 + nn) * K + k0 + kk) = o;
  }
}

// ---------------- GEMM: C[M][N] = A[M][K] * Bt[N][K]^T ----------------
// 128x128 tile, XCD-aware bijective block swizzle (grid % 8 == 0).
template <int FP32OUT>
__global__ __launch_bounds__(256) void k_gemm_bt(const short* __restrict__ A,
                                                 const short* __restrict__ Bt,
                                                 void* __restrict__ Cp,
                                                 int M, int N, int K) {
  __shared__ short As[128 * 32];
  __shared__ short Bs[128 * 32];
  const int t = threadIdx.x, l = t & 63, w = t >> 6;
  const int wr = w >> 1, wc = w & 1;
  const int gx = gridDim.x;
  const int id = blockIdx.y * gx + blockIdx.x;
  const int per = (gx * gridDim.y) >> 3;
  const int id2 = (id & 7) * per + (id >> 3);
  const int m0 = (id2 % gx) * 128, n0 = (id2 / gx) * 128;
  const int lrow = l & 15, lg = l >> 4;

  f32x4 acc[4][4] = {};

  const int srow0 = (t >> 2);
  const int srow1 = 64 + (t >> 2);
  const int sk0 = (((t & 3) ^ (srow0 & 3)) * 8);
  const int sk1 = (((t & 3) ^ (srow1 & 3)) * 8);
  const short* Ab = A + (size_t)m0 * K;
  const short* Bb = Bt + (size_t)n0 * K;
  short* AsB0 = As + w * 512;
  short* AsB1 = As + 2048 + w * 512;
  short* BsB0 = Bs + w * 512;
  short* BsB1 = Bs + 2048 + w * 512;

  for (int k0 = 0; k0 < K; k0 += 32) {
    gload_lds16(Ab + (size_t)srow0 * K + k0 + sk0, AsB0);
    gload_lds16(Ab + (size_t)srow1 * K + k0 + sk1, AsB1);
    gload_lds16(Bb + (size_t)srow0 * K + k0 + sk0, BsB0);
    gload_lds16(Bb + (size_t)srow1 * K + k0 + sk1, BsB1);
    __syncthreads();
    short8 af[4], bf[4];
#pragma unroll
    for (int mi = 0; mi < 4; ++mi) {
      int r = wr * 64 + mi * 16 + lrow;
      af[mi] = *(const short8*)(As + r * 32 + ((lg ^ (r & 3)) * 8));
    }
#pragma unroll
    for (int ni = 0; ni < 4; ++ni) {
      int r = wc * 64 + ni * 16 + lrow;
      bf[ni] = *(const short8*)(Bs + r * 32 + ((lg ^ (r & 3)) * 8));
    }
#pragma unroll
    for (int mi = 0; mi < 4; ++mi)
#pragma unroll
      for (int ni = 0; ni < 4; ++ni)
        acc[mi][ni] = mfma16(af[mi], bf[ni], acc[mi][ni]);
    __syncthreads();
  }
#pragma unroll
  for (int mi = 0; mi < 4; ++mi)
#pragma unroll
    for (int ni = 0; ni < 4; ++ni) {
      int row = m0 + wr * 64 + mi * 16 + lg * 4;
      int col = n0 + wc * 64 + ni * 16 + lrow;
#pragma unroll
      for (int v = 0; v < 4; ++v) {
        float val = acc[mi][ni][v];
        if constexpr (FP32OUT)
          ((float*)Cp)[(size_t)(row + v) * N + col] = val;
        else
          ((short*)Cp)[(size_t)(row + v) * N + col] = f2bs(val);
      }
    }
}

// ------ RoPE in-place on q,k slices; q also * (1/sqrt(D) * log2e) ------
__global__ __launch_bounds__(256) void k_rope(short* __restrict__ qkv,
                                              const float* __restrict__ fcos,
                                              const float* __restrict__ fsin) {
  int tid = blockIdx.x * 256 + threadIdx.x;  // total NB*SEQ*20*16
  int p16 = tid & 15;
  int slice = (tid >> 4) % 20;
  int bs = tid / 320;
  int col = (slice < 16) ? slice * 128 + p16 * 8
                         : 2048 + (slice - 16) * 128 + p16 * 8;
  short8 x = *(short8*)(qkv + (size_t)bs * LDQKV + col);
  f32x4 c = *(const f32x4*)(fcos + (size_t)bs * 64 + p16 * 4);
  f32x4 s = *(const f32x4*)(fsin + (size_t)bs * 64 + p16 * 4);
  float sc = (slice < 16) ? QSCALE2 : 1.0f;
  short8 o;
#pragma unroll
  for (int j = 0; j < 4; ++j) {
    float xr = bs2f(x[2 * j]), xi = bs2f(x[2 * j + 1]);
    o[2 * j] = f2bs((xr * c[j] - xi * s[j]) * sc);
    o[2 * j + 1] = f2bs((xr * s[j] + xi * c[j]) * sc);
  }
  *(short8*)(qkv + (size_t)bs * LDQKV + col) = o;
}

// ------------- V transpose: qkv v-slice [s][d] -> vt [b][kvh][d][s] ---------
__global__ __launch_bounds__(256) void k_vtrans(const short* __restrict__ qkv,
                                                short* __restrict__ vt) {
  __shared__ short tile[128 * 137];
  int s0 = blockIdx.x * 128;
  int kvh = blockIdx.y, b = blockIdx.z;
  int t = threadIdx.x;
  const short* src = qkv + (size_t)(b * SEQ) * LDQKV + 2560 + kvh * 128;
#pragma unroll
  for (int rep = 0; rep < 8; ++rep) {
    int lin = rep * 2048 + t * 8;
    int si = lin >> 7, d = lin & 127;
    short8 v = *(const short8*)(src + (size_t)(s0 + si) * LDQKV + d);
#pragma unroll
    for (int j = 0; j < 8; ++j) tile[si * 137 + d + j] = v[j];
  }
  __syncthreads();
  short* dst = vt + (size_t)((b * 4 + kvh) * 128) * SEQ;
#pragma unroll
  for (int rep = 0; rep < 8; ++rep) {
    int lin = rep * 2048 + t * 8;
    int d = lin >> 7, sb = lin & 127;
    short8 o;
#pragma unroll
    for (int j = 0; j < 8; ++j) o[j] = tile[(sb + j) * 137 + d];
    *(short8*)(dst + (size_t)d * SEQ + s0 + sb) = o;
  }
}

// ---------------- flash attention (causal, GQA) ----------------
// grid (8,16,2) = 256 blocks = 1/CU. Each block does the qt-pair {bx, 15-bx}
// -> exactly 34 tile-iters per block (perfect static balance). Defer-max
// softmax: scores are base-2 (log2e folded into Q); m=0 unless any local max
// exceeds m+8 (rare slow path does the full reduce/rescale). Row sums kept
// as per-lane partials, reduced once at the end.
__global__ __launch_bounds__(256, 1) void k_attn(const short* __restrict__ qkv,
                                                 const short* __restrict__ vt,
                                                 short* __restrict__ outp) {
  __shared__ short Ks[2][64 * 128];
  __shared__ short Vs[2][128 * 64];
  __shared__ short Ps[4][32 * 64];
  const int t = threadIdx.x, l = t & 63, w = t >> 6;
  const int h = blockIdx.y, b = blockIdx.z;
  const int kvh = h >> 2;
  const int lrow = l & 15, lg = l >> 4;

  const int kkey = t >> 4, kd8 = t & 15;
  const int vdd = t >> 3, vs8 = t & 7;
  const short* kbase = qkv + (size_t)(b * SEQ) * LDQKV + 2048 + kvh * HD;
  const short* vbase = vt + (size_t)((b * 4 + kvh) * 128) * SEQ;

  auto stageKV = [&](int buf, int it) {
    const int kt = it * 64;
    short* kdst = &Ks[buf][w * 512];
    short* vdst = &Vs[buf][w * 512];
#pragma unroll
    for (int i = 0; i < 4; ++i) {
      int key = i * 16 + kkey;
      int sd = (kd8 ^ (key & 7)) * 8;
      gload_lds16(kbase + (size_t)(kt + key) * LDQKV + sd, kdst + i * 2048);
    }
#pragma unroll
    for (int i = 0; i < 4; ++i) {
      int d = i * 32 + vdd;
      int ss = (vs8 ^ (d & 7)) * 8;
      gload_lds16(vbase + (size_t)d * SEQ + kt + ss, vdst + i * 2048);
    }
  };

  for (int part = 0; part < 2; ++part) {
    const int qt = part ? (15 - (int)blockIdx.x) : (int)blockIdx.x;
    const int q0 = qt * 128;

    short8 qf[2][4];
#pragma unroll
    for (int mi = 0; mi < 2; ++mi) {
      const short* qrow =
          qkv + (size_t)(b * SEQ + q0 + w * 32 + mi * 16 + lrow) * LDQKV +
          h * HD;
#pragma unroll
      for (int kk = 0; kk < 4; ++kk)
        qf[mi][kk] = *(const short8*)(qrow + kk * 32 + lg * 8);
    }

    f32x4 of[2][8] = {};
    float mrun[2][4], lsum[2][4];
#pragma unroll
    for (int mi = 0; mi < 2; ++mi)
#pragma unroll
      for (int v = 0; v < 4; ++v) { mrun[mi][v] = 0.f; lsum[mi][v] = 0.f; }

    const int nt = 2 * qt + 2;
    stageKV(0, 0);
    __syncthreads();

    for (int it = 0; it < nt; ++it) {
      const int cur = it & 1;
      if (it + 1 < nt) stageKV(cur ^ 1, it + 1);  // prefetch; drained at barrier
      const int kt = it * 64;
      const short* KsC = Ks[cur];
      const short* VsC = Vs[cur];

      // QK^T (K-frag reads shared across both row-strips)
      f32x4 sc[2][4] = {};
#pragma unroll
      for (int ni = 0; ni < 4; ++ni) {
        int key = ni * 16 + lrow;
#pragma unroll
        for (int kk = 0; kk < 4; ++kk) {
          int d0 = kk * 32 + lg * 8;
          short8 kf =
              *(const short8*)(KsC + key * 128 + (d0 ^ (8 * (key & 7))));
          sc[0][ni] = mfma16(qf[0][kk], kf, sc[0][ni]);
          sc[1][ni] = mfma16(qf[1][kk], kf, sc[1][ni]);
        }
      }

      if (it >= nt - 2) {  // diagonal masking (base-2 domain, exp2 -> 0)
#pragma unroll
        for (int mi = 0; mi < 2; ++mi) {
          const int rowb = q0 + w * 32 + mi * 16 + lg * 4;
#pragma unroll
          for (int ni = 0; ni < 4; ++ni) {
            int key = kt + ni * 16 + lrow;
#pragma unroll
            for (int v = 0; v < 4; ++v)
              if (key > rowb + v) sc[mi][ni][v] = -1e30f;
          }
        }
      }

      // defer-max check: rescale only if some lane's local max > mrun + 8
      float lmax[2][4];
      bool need = false;
#pragma unroll
      for (int mi = 0; mi < 2; ++mi)
#pragma unroll
        for (int v = 0; v < 4; ++v) {
          float mx = fmaxf(fmaxf(sc[mi][0][v], sc[mi][1][v]),
                           fmaxf(sc[mi][2][v], sc[mi][3][v]));
          lmax[mi][v] = mx;
          need |= (mx > mrun[mi][v] + 8.f);
        }
      if (__any(need)) {  // rare slow path: full max-reduce + rescale
#pragma unroll
        for (int mi = 0; mi < 2; ++mi) {
          float rs[4];
#pragma unroll
          for (int v = 0; v < 4; ++v) {
            float mx = lmax[mi][v];
            mx = fmaxf(mx, __shfl_xor(mx, 1, 16));
            mx = fmaxf(mx, __shfl_xor(mx, 2, 16));
            mx = fmaxf(mx, __shfl_xor(mx, 4, 16));
            mx = fmaxf(mx, __shfl_xor(mx, 8, 16));
            float mm = fmaxf(mrun[mi][v], mx);
            rs[v] = exp2f(mrun[mi][v] - mm);
            mrun[mi][v] = mm;
            lsum[mi][v] *= rs[v];
          }
#pragma unroll
          for (int ni = 0; ni < 8; ++ni)
#pragma unroll
            for (int v = 0; v < 4; ++v) of[mi][ni][v] *= rs[v];
        }
      }

      // P = exp2(sc - m); accumulate per-lane partial row sums
#pragma unroll
      for (int mi = 0; mi < 2; ++mi)
#pragma unroll
        for (int ni = 0; ni < 4; ++ni)
#pragma unroll
          for (int v = 0; v < 4; ++v) {
            float p = exp2f(sc[mi][ni][v] - mrun[mi][v]);
            lsum[mi][v] += p;
            int r = mi * 16 + lg * 4 + v;
            Ps[w][r * 64 + ((ni * 16 + lrow) ^ (8 * (r & 7)))] = f2bs(p);
          }

      // PV (P is wave-private LDS; no barrier needed)
      short8 pa[2][2];
#pragma unroll
      for (int mi = 0; mi < 2; ++mi)
#pragma unroll
        for (int kk = 0; kk < 2; ++kk)
          pa[mi][kk] = *(const short8*)(&Ps[w][(mi * 16 + lrow) * 64 +
                                               ((kk * 32 + lg * 8) ^
                                                (8 * (lrow & 7)))]);
#pragma unroll
      for (int kk = 0; kk < 2; ++kk)
#pragma unroll
        for (int ni = 0; ni < 8; ++ni) {
          int d = ni * 16 + lrow;
          short8 vf = *(const short8*)(VsC + d * 64 +
                                       ((kk * 32 + lg * 8) ^ (8 * (d & 7))));
          of[0][ni] = mfma16(pa[0][kk], vf, of[0][ni]);
          of[1][ni] = mfma16(pa[1][kk], vf, of[1][ni]);
        }
      __syncthreads();  // drains prefetch vmcnt + fences buffer swap
    }

    // final row-sum reduce (once per part) + output
#pragma unroll
    for (int mi = 0; mi < 2; ++mi) {
      short* ob = outp +
                  (size_t)(b * SEQ + q0 + w * 32 + mi * 16 + lg * 4) * 2048 +
                  h * HD;
#pragma unroll
      for (int v = 0; v < 4; ++v) {
        float s = lsum[mi][v];
        s += __shfl_xor(s, 1, 16);
        s += __shfl_xor(s, 2, 16);
        s += __shfl_xor(s, 4, 16);
        s += __shfl_xor(s, 8, 16);
        float inv = 1.0f / s;
#pragma unroll
        for (int ni = 0; ni < 8; ++ni)
          ob[(size_t)v * 2048 + ni * 16 + lrow] = f2bs(of[mi][ni][v] * inv);
      }
    }
  }
}

extern "C" void kernel_launch(void* const* d_in, const int* in_sizes, int n_in,
                              void* d_out, int out_size, void* d_ws,
                              size_t ws_size, hipStream_t stream) {
  const float* x = (const float*)d_in[0];
  const float* wq = (const float*)d_in[1];
  const float* wk = (const float*)d_in[2];
  const float* wv = (const float*)d_in[3];
  const float* wo = (const float*)d_in[4];
  const float* fc = (const float*)d_in[5];
  const float* fs = (const float*)d_in[6];

  char* ws = (char*)d_ws;
  short* xb = (short*)(ws);                           // [4096][2048] 16MB
  short* wT = (short*)(ws + (16ull << 20));           // [3072][2048] 12MB
  short* woT = (short*)(ws + (28ull << 20));          // [2048][2048] 8MB
  short* qkvb = (short*)(ws + (36ull << 20));         // [4096][3072] 24MB
  short* vtb = (short*)(ws + (16ull << 20));          // alias wT (dead) 4MB
  short* attn = (short*)(ws);                         // alias xb (dead) 16MB

  k_cvt<<<4096, 256, 0, stream>>>(x, xb, 1048576);
  k_wtrans<<<dim3(32, 32), 256, 0, stream>>>(wq, wT, 2048, 2048);
  k_wtrans<<<dim3(32, 8), 256, 0, stream>>>(wk, wT + (size_t)2048 * 2048, 2048, 512);
  k_wtrans<<<dim3(32, 8), 256, 0, stream>>>(wv, wT + (size_t)2560 * 2048, 2048, 512);
  k_wtrans<<<dim3(32, 32), 256, 0, stream>>>(wo, woT, 2048, 2048);
  k_gemm_bt<0><<<dim3(32, 24), 256, 0, stream>>>(xb, wT, qkvb, 4096, 3072, 2048);
  k_rope<<<5120, 256, 0, stream>>>(qkvb, fc, fs);
  k_vtrans<<<dim3(16, 4, 2), 256, 0, stream>>>(qkvb, vtb);
  k_attn<<<dim3(8, 16, 2), 256, 0, stream>>>(qkvb, vtb, attn);
  k_gemm_bt<1><<<dim3(32, 16), 256, 0, stream>>>(attn, woT, d_out, 4096, 2048, 2048);
}

// Round 4
// 237.450 us; speedup vs baseline: 1.3868x; 1.0586x over previous
//
#include <hip/hip_runtime.h>
#include <stdint.h>

#define SEQ   2048
#define NB    2
#define LDQKV 3072
#define HD    128
// 1/sqrt(128) * log2(e): QK^T scores land in base-2 domain -> exp2 directly.
#define QSCALE2 (0.08838834764831845f * 1.44269504088896340f)

typedef __attribute__((ext_vector_type(8))) short short8;
typedef __attribute__((ext_vector_type(4))) short short4v;
typedef __attribute__((ext_vector_type(4))) float f32x4;
typedef __attribute__((ext_vector_type(8))) __bf16 bf16x8;

__device__ __forceinline__ float bs2f(short s) {
  unsigned int u = ((unsigned int)(unsigned short)s) << 16;
  return __builtin_bit_cast(float, u);
}
__device__ __forceinline__ short f2bs(float f) {
  unsigned int u = __builtin_bit_cast(unsigned int, f);
  u += 0x7fffu + ((u >> 16) & 1u);
  return (short)(u >> 16);
}
__device__ __forceinline__ f32x4 mfma16(short8 a, short8 b, f32x4 c) {
  return __builtin_amdgcn_mfma_f32_16x16x32_bf16(
      __builtin_bit_cast(bf16x8, a), __builtin_bit_cast(bf16x8, b), c, 0, 0, 0);
}
__device__ __forceinline__ void gload_lds16(const void* g, void* l) {
  __builtin_amdgcn_global_load_lds(
      (__attribute__((address_space(1))) const void*)(uintptr_t)g,
      (__attribute__((address_space(3))) void*)(unsigned int)(uintptr_t)l,
      16, 0, 0);
}

// ---------------- fp32 -> bf16 convert (vectorized) ----------------
__global__ __launch_bounds__(256) void k_cvt(const float* __restrict__ src,
                                             short* __restrict__ dst, int n8) {
  int i = blockIdx.x * 256 + threadIdx.x;
  if (i >= n8) return;
  f32x4 a = *(const f32x4*)(src + (size_t)i * 8);
  f32x4 b = *(const f32x4*)(src + (size_t)i * 8 + 4);
  short8 o;
#pragma unroll
  for (int j = 0; j < 4; ++j) { o[j] = f2bs(a[j]); o[4 + j] = f2bs(b[j]); }
  *(short8*)(dst + (size_t)i * 8) = o;
}

// ------------- weight transpose: [K][N] fp32 -> [N][K] bf16 -------------
__global__ __launch_bounds__(256) void k_wtrans(const float* __restrict__ src,
                                                short* __restrict__ dst,
                                                int K, int N) {
  __shared__ __align__(16) float tile[64][68];
  int k0 = blockIdx.x * 64, n0 = blockIdx.y * 64;
  int t = threadIdx.x;
#pragma unroll
  for (int rep = 0; rep < 4; ++rep) {
    int lin = rep * 1024 + t * 4;
    int kk = lin >> 6, nn = lin & 63;
    f32x4 v = *(const f32x4*)(src + (size_t)(k0 + kk) * N + n0 + nn);
    *(f32x4*)(&tile[kk][nn]) = v;
  }
  __syncthreads();
#pragma unroll
  for (int rep = 0; rep < 4; ++rep) {
    int lin = rep * 1024 + t * 4;
    int nn = lin >> 6, kk = lin & 63;
    short4v o;
#pragma unroll
    for (int j = 0; j < 4; ++j) o[j] = f2bs(tile[kk + j][nn]);
    *(short4v*)(dst + (size_t)(n0 + nn) * K + k0 + kk) = o;
  }
}

// ---------------- GEMM: C[M][N] = A[M][K] * Bt[N][K]^T ----------------
template <int FP32OUT>
__global__ __launch_bounds__(256) void k_gemm_bt(const short* __restrict__ A,
                                                 const short* __restrict__ Bt,
                                                 void* __restrict__ Cp,
                                                 int M, int N, int K) {
  __shared__ short As[128 * 32];
  __shared__ short Bs[128 * 32];
  const int t = threadIdx.x, l = t & 63, w = t >> 6;
  const int wr = w >> 1, wc = w & 1;
  const int gx = gridDim.x;
  const int id = blockIdx.y * gx + blockIdx.x;
  const int per = (gx * gridDim.y) >> 3;
  const int id2 = (id & 7) * per + (id >> 3);
  const int m0 = (id2 % gx) * 128, n0 = (id2 / gx) * 128;
  const int lrow = l & 15, lg = l >> 4;

  f32x4 acc[4][4] = {};

  const int srow0 = (t >> 2);
  const int srow1 = 64 + (t >> 2);
  const int sk0 = (((t & 3) ^ (srow0 & 3)) * 8);
  const int sk1 = (((t & 3) ^ (srow1 & 3)) * 8);
  const short* Ab = A + (size_t)m0 * K;
  const short* Bb = Bt + (size_t)n0 * K;
  short* AsB0 = As + w * 512;
  short* AsB1 = As + 2048 + w * 512;
  short* BsB0 = Bs + w * 512;
  short* BsB1 = Bs + 2048 + w * 512;

  for (int k0 = 0; k0 < K; k0 += 32) {
    gload_lds16(Ab + (size_t)srow0 * K + k0 + sk0, AsB0);
    gload_lds16(Ab + (size_t)srow1 * K + k0 + sk1, AsB1);
    gload_lds16(Bb + (size_t)srow0 * K + k0 + sk0, BsB0);
    gload_lds16(Bb + (size_t)srow1 * K + k0 + sk1, BsB1);
    __syncthreads();
    short8 af[4], bf[4];
#pragma unroll
    for (int mi = 0; mi < 4; ++mi) {
      int r = wr * 64 + mi * 16 + lrow;
      af[mi] = *(const short8*)(As + r * 32 + ((lg ^ (r & 3)) * 8));
    }
#pragma unroll
    for (int ni = 0; ni < 4; ++ni) {
      int r = wc * 64 + ni * 16 + lrow;
      bf[ni] = *(const short8*)(Bs + r * 32 + ((lg ^ (r & 3)) * 8));
    }
#pragma unroll
    for (int mi = 0; mi < 4; ++mi)
#pragma unroll
      for (int ni = 0; ni < 4; ++ni)
        acc[mi][ni] = mfma16(af[mi], bf[ni], acc[mi][ni]);
    __syncthreads();
  }
#pragma unroll
  for (int mi = 0; mi < 4; ++mi)
#pragma unroll
    for (int ni = 0; ni < 4; ++ni) {
      int row = m0 + wr * 64 + mi * 16 + lg * 4;
      int col = n0 + wc * 64 + ni * 16 + lrow;
#pragma unroll
      for (int v = 0; v < 4; ++v) {
        float val = acc[mi][ni][v];
        if constexpr (FP32OUT)
          ((float*)Cp)[(size_t)(row + v) * N + col] = val;
        else
          ((short*)Cp)[(size_t)(row + v) * N + col] = f2bs(val);
      }
    }
}

// ------ RoPE in-place on q,k slices; q also * (1/sqrt(D) * log2e) ------
__global__ __launch_bounds__(256) void k_rope(short* __restrict__ qkv,
                                              const float* __restrict__ fcos,
                                              const float* __restrict__ fsin) {
  int tid = blockIdx.x * 256 + threadIdx.x;  // total NB*SEQ*20*16
  int p16 = tid & 15;
  int slice = (tid >> 4) % 20;
  int bs = tid / 320;
  int col = (slice < 16) ? slice * 128 + p16 * 8
                         : 2048 + (slice - 16) * 128 + p16 * 8;
  short8 x = *(short8*)(qkv + (size_t)bs * LDQKV + col);
  f32x4 c = *(const f32x4*)(fcos + (size_t)bs * 64 + p16 * 4);
  f32x4 s = *(const f32x4*)(fsin + (size_t)bs * 64 + p16 * 4);
  float sc = (slice < 16) ? QSCALE2 : 1.0f;
  short8 o;
#pragma unroll
  for (int j = 0; j < 4; ++j) {
    float xr = bs2f(x[2 * j]), xi = bs2f(x[2 * j + 1]);
    o[2 * j] = f2bs((xr * c[j] - xi * s[j]) * sc);
    o[2 * j + 1] = f2bs((xr * s[j] + xi * c[j]) * sc);
  }
  *(short8*)(qkv + (size_t)bs * LDQKV + col) = o;
}

// ------------- V transpose: qkv v-slice [s][d] -> vt [b][kvh][d][s] ---------
__global__ __launch_bounds__(256) void k_vtrans(const short* __restrict__ qkv,
                                                short* __restrict__ vt) {
  __shared__ short tile[128 * 137];
  int s0 = blockIdx.x * 128;
  int kvh = blockIdx.y, b = blockIdx.z;
  int t = threadIdx.x;
  const short* src = qkv + (size_t)(b * SEQ) * LDQKV + 2560 + kvh * 128;
#pragma unroll
  for (int rep = 0; rep < 8; ++rep) {
    int lin = rep * 2048 + t * 8;
    int si = lin >> 7, d = lin & 127;
    short8 v = *(const short8*)(src + (size_t)(s0 + si) * LDQKV + d);
#pragma unroll
    for (int j = 0; j < 8; ++j) tile[si * 137 + d + j] = v[j];
  }
  __syncthreads();
  short* dst = vt + (size_t)((b * 4 + kvh) * 128) * SEQ;
#pragma unroll
  for (int rep = 0; rep < 8; ++rep) {
    int lin = rep * 2048 + t * 8;
    int d = lin >> 7, sb = lin & 127;
    short8 o;
#pragma unroll
    for (int j = 0; j < 8; ++j) o[j] = tile[(sb + j) * 137 + d];
    *(short8*)(dst + (size_t)d * SEQ + s0 + sb) = o;
  }
}

// ---------------- flash attention (causal, GQA) ----------------
// grid (16,16,2) = 512 blocks, 72KB LDS -> 2 blocks/CU, 8 waves/CU (2/SIMD).
// Q-tile 64 rows (wave = 16 rows); block does qt-pair {bx, 31-bx} = 33 iters
// (perfect balance). Defer-max base-2 softmax with per-lane deferred sums.
__global__ __launch_bounds__(256) void k_attn(const short* __restrict__ qkv,
                                              const short* __restrict__ vt,
                                              short* __restrict__ outp) {
  __shared__ short Ks[2][64 * 128];
  __shared__ short Vs[2][128 * 64];
  __shared__ short Ps[4][16 * 64];
  const int t = threadIdx.x, l = t & 63, w = t >> 6;
  const int h = blockIdx.y, b = blockIdx.z;
  const int kvh = h >> 2;
  const int lrow = l & 15, lg = l >> 4;

  const int kkey = t >> 4, kd8 = t & 15;
  const int vdd = t >> 3, vs8 = t & 7;
  const short* kbase = qkv + (size_t)(b * SEQ) * LDQKV + 2048 + kvh * HD;
  const short* vbase = vt + (size_t)((b * 4 + kvh) * 128) * SEQ;

  auto stageKV = [&](int buf, int it) {
    const int kt = it * 64;
    short* kdst = &Ks[buf][w * 512];
    short* vdst = &Vs[buf][w * 512];
#pragma unroll
    for (int i = 0; i < 4; ++i) {
      int key = i * 16 + kkey;
      int sd = (kd8 ^ (key & 7)) * 8;
      gload_lds16(kbase + (size_t)(kt + key) * LDQKV + sd, kdst + i * 2048);
    }
#pragma unroll
    for (int i = 0; i < 4; ++i) {
      int d = i * 32 + vdd;
      int ss = (vs8 ^ (d & 7)) * 8;
      gload_lds16(vbase + (size_t)d * SEQ + kt + ss, vdst + i * 2048);
    }
  };

  for (int part = 0; part < 2; ++part) {
    const int qt = part ? (31 - (int)blockIdx.x) : (int)blockIdx.x;
    const int q0 = qt * 64;

    short8 qf[4];
    {
      const short* qrow =
          qkv + (size_t)(b * SEQ + q0 + w * 16 + lrow) * LDQKV + h * HD;
#pragma unroll
      for (int kk = 0; kk < 4; ++kk)
        qf[kk] = *(const short8*)(qrow + kk * 32 + lg * 8);
    }

    f32x4 of[8] = {};
    float mrun[4], lsum[4];
#pragma unroll
    for (int v = 0; v < 4; ++v) { mrun[v] = 0.f; lsum[v] = 0.f; }

    const int nt = qt + 1;
    stageKV(0, 0);
    __syncthreads();

    for (int it = 0; it < nt; ++it) {
      const int cur = it & 1;
      if (it + 1 < nt) stageKV(cur ^ 1, it + 1);  // prefetch; drained at barrier
      const int kt = it * 64;
      const short* KsC = Ks[cur];
      const short* VsC = Vs[cur];

      // QK^T
      f32x4 sc[4] = {};
      __builtin_amdgcn_s_setprio(1);
#pragma unroll
      for (int ni = 0; ni < 4; ++ni) {
        int key = ni * 16 + lrow;
#pragma unroll
        for (int kk = 0; kk < 4; ++kk) {
          int d0 = kk * 32 + lg * 8;
          short8 kf =
              *(const short8*)(KsC + key * 128 + (d0 ^ (8 * (key & 7))));
          sc[ni] = mfma16(qf[kk], kf, sc[ni]);
        }
      }
      __builtin_amdgcn_s_setprio(0);

      if (it == nt - 1) {  // diagonal masking (base-2 domain, exp2 -> 0)
        const int rowb = q0 + w * 16 + lg * 4;
#pragma unroll
        for (int ni = 0; ni < 4; ++ni) {
          int key = kt + ni * 16 + lrow;
#pragma unroll
          for (int v = 0; v < 4; ++v)
            if (key > rowb + v) sc[ni][v] = -1e30f;
        }
      }

      // defer-max check: rescale only if some lane's local max > mrun + 8
      float lmax[4];
      bool need = false;
#pragma unroll
      for (int v = 0; v < 4; ++v) {
        float mx = fmaxf(fmaxf(sc[0][v], sc[1][v]), fmaxf(sc[2][v], sc[3][v]));
        lmax[v] = mx;
        need |= (mx > mrun[v] + 8.f);
      }
      if (__any(need)) {  // rare slow path: full max-reduce + rescale
        float rs[4];
#pragma unroll
        for (int v = 0; v < 4; ++v) {
          float mx = lmax[v];
          mx = fmaxf(mx, __shfl_xor(mx, 1, 16));
          mx = fmaxf(mx, __shfl_xor(mx, 2, 16));
          mx = fmaxf(mx, __shfl_xor(mx, 4, 16));
          mx = fmaxf(mx, __shfl_xor(mx, 8, 16));
          float mm = fmaxf(mrun[v], mx);
          rs[v] = exp2f(mrun[v] - mm);
          mrun[v] = mm;
          lsum[v] *= rs[v];
        }
#pragma unroll
        for (int ni = 0; ni < 8; ++ni)
#pragma unroll
          for (int v = 0; v < 4; ++v) of[ni][v] *= rs[v];
      }

      // P = exp2(sc - m); accumulate per-lane partial row sums
#pragma unroll
      for (int ni = 0; ni < 4; ++ni)
#pragma unroll
        for (int v = 0; v < 4; ++v) {
          float p = exp2f(sc[ni][v] - mrun[v]);
          lsum[v] += p;
          int r = lg * 4 + v;
          Ps[w][r * 64 + ((ni * 16 + lrow) ^ (8 * (r & 7)))] = f2bs(p);
        }

      // PV (P is wave-private LDS; no barrier needed)
      short8 pa[2];
#pragma unroll
      for (int kk = 0; kk < 2; ++kk)
        pa[kk] = *(const short8*)(&Ps[w][lrow * 64 + ((kk * 32 + lg * 8) ^
                                                      (8 * (lrow & 7)))]);
      __builtin_amdgcn_s_setprio(1);
#pragma unroll
      for (int kk = 0; kk < 2; ++kk)
#pragma unroll
        for (int ni = 0; ni < 8; ++ni) {
          int d = ni * 16 + lrow;
          short8 vf = *(const short8*)(VsC + d * 64 +
                                       ((kk * 32 + lg * 8) ^ (8 * (d & 7))));
          of[ni] = mfma16(pa[kk], vf, of[ni]);
        }
      __builtin_amdgcn_s_setprio(0);
      __syncthreads();  // drains prefetch vmcnt + fences buffer swap
    }

    // final row-sum reduce (once per part) + output
    {
      short* ob = outp + (size_t)(b * SEQ + q0 + w * 16 + lg * 4) * 2048 +
                  h * HD;
#pragma unroll
      for (int v = 0; v < 4; ++v) {
        float s = lsum[v];
        s += __shfl_xor(s, 1, 16);
        s += __shfl_xor(s, 2, 16);
        s += __shfl_xor(s, 4, 16);
        s += __shfl_xor(s, 8, 16);
        float inv = 1.0f / s;
#pragma unroll
        for (int ni = 0; ni < 8; ++ni)
          ob[(size_t)v * 2048 + ni * 16 + lrow] = f2bs(of[ni][v] * inv);
      }
    }
  }
}

extern "C" void kernel_launch(void* const* d_in, const int* in_sizes, int n_in,
                              void* d_out, int out_size, void* d_ws,
                              size_t ws_size, hipStream_t stream) {
  const float* x = (const float*)d_in[0];
  const float* wq = (const float*)d_in[1];
  const float* wk = (const float*)d_in[2];
  const float* wv = (const float*)d_in[3];
  const float* wo = (const float*)d_in[4];
  const float* fc = (const float*)d_in[5];
  const float* fs = (const float*)d_in[6];

  char* ws = (char*)d_ws;
  short* xb = (short*)(ws);                           // [4096][2048] 16MB
  short* wT = (short*)(ws + (16ull << 20));           // [3072][2048] 12MB
  short* woT = (short*)(ws + (28ull << 20));          // [2048][2048] 8MB
  short* qkvb = (short*)(ws + (36ull << 20));         // [4096][3072] 24MB
  short* vtb = (short*)(ws + (16ull << 20));          // alias wT (dead) 4MB
  short* attn = (short*)(ws);                         // alias xb (dead) 16MB

  k_cvt<<<4096, 256, 0, stream>>>(x, xb, 1048576);
  k_wtrans<<<dim3(32, 32), 256, 0, stream>>>(wq, wT, 2048, 2048);
  k_wtrans<<<dim3(32, 8), 256, 0, stream>>>(wk, wT + (size_t)2048 * 2048, 2048, 512);
  k_wtrans<<<dim3(32, 8), 256, 0, stream>>>(wv, wT + (size_t)2560 * 2048, 2048, 512);
  k_wtrans<<<dim3(32, 32), 256, 0, stream>>>(wo, woT, 2048, 2048);
  k_gemm_bt<0><<<dim3(32, 24), 256, 0, stream>>>(xb, wT, qkvb, 4096, 3072, 2048);
  k_rope<<<5120, 256, 0, stream>>>(qkvb, fc, fs);
  k_vtrans<<<dim3(16, 4, 2), 256, 0, stream>>>(qkvb, vtb);
  k_attn<<<dim3(16, 16, 2), 256, 0, stream>>>(qkvb, vtb, attn);
  k_gemm_bt<1><<<dim3(32, 16), 256, 0, stream>>>(attn, woT, d_out, 4096, 2048, 2048);
}

// Round 6
// 231.632 us; speedup vs baseline: 1.4217x; 1.0251x over previous
//
#include <hip/hip_runtime.h>
#include <stdint.h>

#define SEQ   2048
#define NB    2
#define LDQKV 3072
#define HD    128
// 1/sqrt(128) * log2(e): QK^T scores land in base-2 domain -> exp2 directly.
#define QSCALE2 (0.08838834764831845f * 1.44269504088896340f)

typedef __attribute__((ext_vector_type(8))) short short8;
typedef __attribute__((ext_vector_type(4))) short short4v;
typedef __attribute__((ext_vector_type(4))) float f32x4;
typedef __attribute__((ext_vector_type(8))) __bf16 bf16x8;

__device__ __forceinline__ float bs2f(short s) {
  unsigned int u = ((unsigned int)(unsigned short)s) << 16;
  return __builtin_bit_cast(float, u);
}
__device__ __forceinline__ short f2bs(float f) {
  unsigned int u = __builtin_bit_cast(unsigned int, f);
  u += 0x7fffu + ((u >> 16) & 1u);
  return (short)(u >> 16);
}
__device__ __forceinline__ f32x4 mfma16(short8 a, short8 b, f32x4 c) {
  return __builtin_amdgcn_mfma_f32_16x16x32_bf16(
      __builtin_bit_cast(bf16x8, a), __builtin_bit_cast(bf16x8, b), c, 0, 0, 0);
}
__device__ __forceinline__ void gload_lds16(const void* g, void* l) {
  __builtin_amdgcn_global_load_lds(
      (__attribute__((address_space(1))) const void*)(uintptr_t)g,
      (__attribute__((address_space(3))) void*)(unsigned int)(uintptr_t)l,
      16, 0, 0);
}

// ---- fused prep: x fp32->bf16 convert + 4 weight transposes, 1D grid ----
// blocks [0,4096): cvt; [4096,5120): wq; [5120,5376): wk; [5376,5632): wv;
// [5632,6656): wo.
__global__ __launch_bounds__(256) void k_prep(const float* __restrict__ x,
                                              const float* __restrict__ wq,
                                              const float* __restrict__ wk,
                                              const float* __restrict__ wv,
                                              const float* __restrict__ wo,
                                              short* __restrict__ xb,
                                              short* __restrict__ wT,
                                              short* __restrict__ woT) {
  __shared__ __align__(16) float tile[64][68];
  const int bid = blockIdx.x, t = threadIdx.x;
  if (bid < 4096) {  // cvt
    int i = bid * 256 + t;
    f32x4 a = *(const f32x4*)(x + (size_t)i * 8);
    f32x4 b = *(const f32x4*)(x + (size_t)i * 8 + 4);
    short8 o;
#pragma unroll
    for (int j = 0; j < 4; ++j) { o[j] = f2bs(a[j]); o[4 + j] = f2bs(b[j]); }
    *(short8*)(xb + (size_t)i * 8) = o;
    return;
  }
  const float* src;
  short* dst;
  int N, id;
  if (bid < 5120)      { id = bid - 4096; src = wq; dst = wT;                        N = 2048; }
  else if (bid < 5376) { id = bid - 5120; src = wk; dst = wT + (size_t)2048 * 2048;  N = 512;  }
  else if (bid < 5632) { id = bid - 5376; src = wv; dst = wT + (size_t)2560 * 2048;  N = 512;  }
  else                 { id = bid - 5632; src = wo; dst = woT;                       N = 2048; }
  const int K = 2048;
  int k0 = (id & 31) * 64, n0 = (id >> 5) * 64;
#pragma unroll
  for (int rep = 0; rep < 4; ++rep) {
    int lin = rep * 1024 + t * 4;
    int kk = lin >> 6, nn = lin & 63;
    f32x4 v = *(const f32x4*)(src + (size_t)(k0 + kk) * N + n0 + nn);
    *(f32x4*)(&tile[kk][nn]) = v;
  }
  __syncthreads();
#pragma unroll
  for (int rep = 0; rep < 4; ++rep) {
    int lin = rep * 1024 + t * 4;
    int nn = lin >> 6, kk = lin & 63;
    short4v o;
#pragma unroll
    for (int j = 0; j < 4; ++j) o[j] = f2bs(tile[kk + j][nn]);
    *(short4v*)(dst + (size_t)(n0 + nn) * K + k0 + kk) = o;
  }
}

// ---------------- GEMM: C[M][N] = A[M][K] * Bt[N][K]^T ----------------
template <int FP32OUT>
__global__ __launch_bounds__(256) void k_gemm_bt(const short* __restrict__ A,
                                                 const short* __restrict__ Bt,
                                                 void* __restrict__ Cp,
                                                 int M, int N, int K) {
  __shared__ short As[128 * 32];
  __shared__ short Bs[128 * 32];
  const int t = threadIdx.x, l = t & 63, w = t >> 6;
  const int wr = w >> 1, wc = w & 1;
  const int gx = gridDim.x;
  const int id = blockIdx.y * gx + blockIdx.x;
  const int per = (gx * gridDim.y) >> 3;
  const int id2 = (id & 7) * per + (id >> 3);
  const int m0 = (id2 % gx) * 128, n0 = (id2 / gx) * 128;
  const int lrow = l & 15, lg = l >> 4;

  f32x4 acc[4][4] = {};

  const int srow0 = (t >> 2);
  const int srow1 = 64 + (t >> 2);
  const int sk0 = (((t & 3) ^ (srow0 & 3)) * 8);
  const int sk1 = (((t & 3) ^ (srow1 & 3)) * 8);
  const short* Ab = A + (size_t)m0 * K;
  const short* Bb = Bt + (size_t)n0 * K;
  short* AsB0 = As + w * 512;
  short* AsB1 = As + 2048 + w * 512;
  short* BsB0 = Bs + w * 512;
  short* BsB1 = Bs + 2048 + w * 512;

  for (int k0 = 0; k0 < K; k0 += 32) {
    gload_lds16(Ab + (size_t)srow0 * K + k0 + sk0, AsB0);
    gload_lds16(Ab + (size_t)srow1 * K + k0 + sk1, AsB1);
    gload_lds16(Bb + (size_t)srow0 * K + k0 + sk0, BsB0);
    gload_lds16(Bb + (size_t)srow1 * K + k0 + sk1, BsB1);
    __syncthreads();
    short8 af[4], bf[4];
#pragma unroll
    for (int mi = 0; mi < 4; ++mi) {
      int r = wr * 64 + mi * 16 + lrow;
      af[mi] = *(const short8*)(As + r * 32 + ((lg ^ (r & 3)) * 8));
    }
#pragma unroll
    for (int ni = 0; ni < 4; ++ni) {
      int r = wc * 64 + ni * 16 + lrow;
      bf[ni] = *(const short8*)(Bs + r * 32 + ((lg ^ (r & 3)) * 8));
    }
#pragma unroll
    for (int mi = 0; mi < 4; ++mi)
#pragma unroll
      for (int ni = 0; ni < 4; ++ni)
        acc[mi][ni] = mfma16(af[mi], bf[ni], acc[mi][ni]);
    __syncthreads();
  }
#pragma unroll
  for (int mi = 0; mi < 4; ++mi)
#pragma unroll
    for (int ni = 0; ni < 4; ++ni) {
      int row = m0 + wr * 64 + mi * 16 + lg * 4;
      int col = n0 + wc * 64 + ni * 16 + lrow;
#pragma unroll
      for (int v = 0; v < 4; ++v) {
        float val = acc[mi][ni][v];
        if constexpr (FP32OUT)
          ((float*)Cp)[(size_t)(row + v) * N + col] = val;
        else
          ((short*)Cp)[(size_t)(row + v) * N + col] = f2bs(val);
      }
    }
}

// ---- fused RoPE (q,k in-place; q also *QSCALE2) + V transpose, 1D grid ----
// blocks [0,5120): rope; [5120,5248): vtrans.
__global__ __launch_bounds__(256) void k_rv(short* __restrict__ qkv,
                                            const float* __restrict__ fcos,
                                            const float* __restrict__ fsin,
                                            short* __restrict__ vt) {
  __shared__ short tile[128 * 137];
  const int bid = blockIdx.x, t = threadIdx.x;
  if (bid < 5120) {  // rope
    int tid = bid * 256 + t;
    int p16 = tid & 15;
    int slice = (tid >> 4) % 20;
    int bs = tid / 320;
    int col = (slice < 16) ? slice * 128 + p16 * 8
                           : 2048 + (slice - 16) * 128 + p16 * 8;
    short8 x = *(short8*)(qkv + (size_t)bs * LDQKV + col);
    f32x4 c = *(const f32x4*)(fcos + (size_t)bs * 64 + p16 * 4);
    f32x4 s = *(const f32x4*)(fsin + (size_t)bs * 64 + p16 * 4);
    float sc = (slice < 16) ? QSCALE2 : 1.0f;
    short8 o;
#pragma unroll
    for (int j = 0; j < 4; ++j) {
      float xr = bs2f(x[2 * j]), xi = bs2f(x[2 * j + 1]);
      o[2 * j] = f2bs((xr * c[j] - xi * s[j]) * sc);
      o[2 * j + 1] = f2bs((xr * s[j] + xi * c[j]) * sc);
    }
    *(short8*)(qkv + (size_t)bs * LDQKV + col) = o;
    return;
  }
  const int id = bid - 5120;
  int s0 = (id & 15) * 128;
  int kvh = (id >> 4) & 3, b = id >> 6;
  const short* src = qkv + (size_t)(b * SEQ) * LDQKV + 2560 + kvh * 128;
#pragma unroll
  for (int rep = 0; rep < 8; ++rep) {
    int lin = rep * 2048 + t * 8;
    int si = lin >> 7, d = lin & 127;
    short8 v = *(const short8*)(src + (size_t)(s0 + si) * LDQKV + d);
#pragma unroll
    for (int j = 0; j < 8; ++j) tile[si * 137 + d + j] = v[j];
  }
  __syncthreads();
  short* dst = vt + (size_t)((b * 4 + kvh) * 128) * SEQ;
#pragma unroll
  for (int rep = 0; rep < 8; ++rep) {
    int lin = rep * 2048 + t * 8;
    int d = lin >> 7, sb = lin & 127;
    short8 o;
#pragma unroll
    for (int j = 0; j < 8; ++j) o[j] = tile[(sb + j) * 137 + d];
    *(short8*)(dst + (size_t)d * SEQ + s0 + sb) = o;
  }
}

// ---------------- flash attention (causal, GQA) ----------------
// grid (16,16,2) = 512 blocks, 72KB LDS -> 2 blocks/CU. Q-tile 64 (wave=16
// rows); block does qt-pair {bx, 31-bx} = 33 iters (perfect balance).
// Defer-max base-2 softmax with per-lane deferred sums. P-path: proven R4
// form (f2bs + XOR-swizzled b16 stores + short8 readback).
__global__ __launch_bounds__(256) void k_attn(const short* __restrict__ qkv,
                                              const short* __restrict__ vt,
                                              short* __restrict__ outp) {
  __shared__ short Ks[2][64 * 128];
  __shared__ short Vs[2][128 * 64];
  __shared__ short Ps[4][16 * 64];
  const int t = threadIdx.x, l = t & 63, w = t >> 6;
  const int h = blockIdx.y, b = blockIdx.z;
  const int kvh = h >> 2;
  const int lrow = l & 15, lg = l >> 4;

  const int kkey = t >> 4, kd8 = t & 15;
  const int vdd = t >> 3, vs8 = t & 7;
  const short* kbase = qkv + (size_t)(b * SEQ) * LDQKV + 2048 + kvh * HD;
  const short* vbase = vt + (size_t)((b * 4 + kvh) * 128) * SEQ;

  auto stageKV = [&](int buf, int it) {
    const int kt = it * 64;
    short* kdst = &Ks[buf][w * 512];
    short* vdst = &Vs[buf][w * 512];
#pragma unroll
    for (int i = 0; i < 4; ++i) {
      int key = i * 16 + kkey;
      int sd = (kd8 ^ (key & 7)) * 8;
      gload_lds16(kbase + (size_t)(kt + key) * LDQKV + sd, kdst + i * 2048);
    }
#pragma unroll
    for (int i = 0; i < 4; ++i) {
      int d = i * 32 + vdd;
      int ss = (vs8 ^ (d & 7)) * 8;
      gload_lds16(vbase + (size_t)d * SEQ + kt + ss, vdst + i * 2048);
    }
  };

  for (int part = 0; part < 2; ++part) {
    const int qt = part ? (31 - (int)blockIdx.x) : (int)blockIdx.x;
    const int q0 = qt * 64;

    short8 qf[4];
    {
      const short* qrow =
          qkv + (size_t)(b * SEQ + q0 + w * 16 + lrow) * LDQKV + h * HD;
#pragma unroll
      for (int kk = 0; kk < 4; ++kk)
        qf[kk] = *(const short8*)(qrow + kk * 32 + lg * 8);
    }

    f32x4 of[8] = {};
    float mrun[4], lsum[4];
#pragma unroll
    for (int v = 0; v < 4; ++v) { mrun[v] = 0.f; lsum[v] = 0.f; }

    const int nt = qt + 1;
    stageKV(0, 0);
    __syncthreads();

    for (int it = 0; it < nt; ++it) {
      const int cur = it & 1;
      if (it + 1 < nt) stageKV(cur ^ 1, it + 1);  // prefetch; drained at barrier
      const int kt = it * 64;
      const short* KsC = Ks[cur];
      const short* VsC = Vs[cur];

      // QK^T
      f32x4 sc[4] = {};
      __builtin_amdgcn_s_setprio(1);
#pragma unroll
      for (int ni = 0; ni < 4; ++ni) {
        int key = ni * 16 + lrow;
#pragma unroll
        for (int kk = 0; kk < 4; ++kk) {
          int d0 = kk * 32 + lg * 8;
          short8 kf =
              *(const short8*)(KsC + key * 128 + (d0 ^ (8 * (key & 7))));
          sc[ni] = mfma16(qf[kk], kf, sc[ni]);
        }
      }
      __builtin_amdgcn_s_setprio(0);

      if (it == nt - 1) {  // diagonal masking (base-2 domain, exp2 -> 0)
        const int rowb = q0 + w * 16 + lg * 4;
#pragma unroll
        for (int ni = 0; ni < 4; ++ni) {
          int key = kt + ni * 16 + lrow;
#pragma unroll
          for (int v = 0; v < 4; ++v)
            if (key > rowb + v) sc[ni][v] = -1e30f;
        }
      }

      // defer-max check: rescale only if some lane's local max > mrun + 8
      float lmax[4];
      bool need = false;
#pragma unroll
      for (int v = 0; v < 4; ++v) {
        float mx = fmaxf(fmaxf(sc[0][v], sc[1][v]), fmaxf(sc[2][v], sc[3][v]));
        lmax[v] = mx;
        need |= (mx > mrun[v] + 8.f);
      }
      if (__any(need)) {  // rare slow path: full max-reduce + rescale
        float rs[4];
#pragma unroll
        for (int v = 0; v < 4; ++v) {
          float mx = lmax[v];
          mx = fmaxf(mx, __shfl_xor(mx, 1, 16));
          mx = fmaxf(mx, __shfl_xor(mx, 2, 16));
          mx = fmaxf(mx, __shfl_xor(mx, 4, 16));
          mx = fmaxf(mx, __shfl_xor(mx, 8, 16));
          float mm = fmaxf(mrun[v], mx);
          rs[v] = exp2f(mrun[v] - mm);
          mrun[v] = mm;
          lsum[v] *= rs[v];
        }
#pragma unroll
        for (int ni = 0; ni < 8; ++ni)
#pragma unroll
          for (int v = 0; v < 4; ++v) of[ni][v] *= rs[v];
      }

      // P = exp2(sc - m); accumulate per-lane partial row sums
#pragma unroll
      for (int ni = 0; ni < 4; ++ni)
#pragma unroll
        for (int v = 0; v < 4; ++v) {
          float p = exp2f(sc[ni][v] - mrun[v]);
          lsum[v] += p;
          int r = lg * 4 + v;
          Ps[w][r * 64 + ((ni * 16 + lrow) ^ (8 * (r & 7)))] = f2bs(p);
        }

      // PV (P is wave-private LDS; no barrier needed)
      short8 pa[2];
#pragma unroll
      for (int kk = 0; kk < 2; ++kk)
        pa[kk] = *(const short8*)(&Ps[w][lrow * 64 + ((kk * 32 + lg * 8) ^
                                                      (8 * (lrow & 7)))]);
      __builtin_amdgcn_s_setprio(1);
#pragma unroll
      for (int kk = 0; kk < 2; ++kk)
#pragma unroll
        for (int ni = 0; ni < 8; ++ni) {
          int d = ni * 16 + lrow;
          short8 vf = *(const short8*)(VsC + d * 64 +
                                       ((kk * 32 + lg * 8) ^ (8 * (d & 7))));
          of[ni] = mfma16(pa[kk], vf, of[ni]);
        }
      __builtin_amdgcn_s_setprio(0);
      __syncthreads();  // drains prefetch vmcnt + fences buffer swap
    }

    // final row-sum reduce (once per part) + output
    {
      short* ob = outp + (size_t)(b * SEQ + q0 + w * 16 + lg * 4) * 2048 +
                  h * HD;
#pragma unroll
      for (int v = 0; v < 4; ++v) {
        float s = lsum[v];
        s += __shfl_xor(s, 1, 16);
        s += __shfl_xor(s, 2, 16);
        s += __shfl_xor(s, 4, 16);
        s += __shfl_xor(s, 8, 16);
        float inv = 1.0f / s;
#pragma unroll
        for (int ni = 0; ni < 8; ++ni)
          ob[(size_t)v * 2048 + ni * 16 + lrow] = f2bs(of[ni][v] * inv);
      }
    }
  }
}

extern "C" void kernel_launch(void* const* d_in, const int* in_sizes, int n_in,
                              void* d_out, int out_size, void* d_ws,
                              size_t ws_size, hipStream_t stream) {
  const float* x = (const float*)d_in[0];
  const float* wq = (const float*)d_in[1];
  const float* wk = (const float*)d_in[2];
  const float* wv = (const float*)d_in[3];
  const float* wo = (const float*)d_in[4];
  const float* fc = (const float*)d_in[5];
  const float* fs = (const float*)d_in[6];

  char* ws = (char*)d_ws;
  short* xb = (short*)(ws);                           // [4096][2048] 16MB
  short* wT = (short*)(ws + (16ull << 20));           // [3072][2048] 12MB
  short* woT = (short*)(ws + (28ull << 20));          // [2048][2048] 8MB
  short* qkvb = (short*)(ws + (36ull << 20));         // [4096][3072] 24MB
  short* vtb = (short*)(ws + (16ull << 20));          // alias wT (dead) 4MB
  short* attn = (short*)(ws);                         // alias xb (dead) 16MB

  k_prep<<<6656, 256, 0, stream>>>(x, wq, wk, wv, wo, xb, wT, woT);
  k_gemm_bt<0><<<dim3(32, 24), 256, 0, stream>>>(xb, wT, qkvb, 4096, 3072, 2048);
  k_rv<<<5248, 256, 0, stream>>>(qkvb, fc, fs, vtb);
  k_attn<<<dim3(16, 16, 2), 256, 0, stream>>>(qkvb, vtb, attn);
  k_gemm_bt<1><<<dim3(32, 16), 256, 0, stream>>>(attn, woT, d_out, 4096, 2048, 2048);
}

// Round 8
// 222.510 us; speedup vs baseline: 1.4800x; 1.0410x over previous
//
#include <hip/hip_runtime.h>
#include <stdint.h>

#define SEQ   2048
#define NB    2
#define LDQKV 3072
#define HD    128
// 1/sqrt(128) * log2(e): QK^T scores land in base-2 domain -> exp2 directly.
#define QSCALE2 (0.08838834764831845f * 1.44269504088896340f)

typedef __attribute__((ext_vector_type(8))) short short8;
typedef __attribute__((ext_vector_type(4))) short short4v;
typedef __attribute__((ext_vector_type(4))) float f32x4;
typedef __attribute__((ext_vector_type(16))) float f32x16;
typedef __attribute__((ext_vector_type(4))) unsigned int u32x4;
typedef __attribute__((ext_vector_type(2))) unsigned int u32x2;
typedef __attribute__((ext_vector_type(8))) __bf16 bf16x8;

__device__ __forceinline__ float bs2f(short s) {
  unsigned int u = ((unsigned int)(unsigned short)s) << 16;
  return __builtin_bit_cast(float, u);
}
__device__ __forceinline__ short f2bs(float f) {
  unsigned int u = __builtin_bit_cast(unsigned int, f);
  u += 0x7fffu + ((u >> 16) & 1u);
  return (short)(u >> 16);
}
__device__ __forceinline__ unsigned int cvt_pk(float lo, float hi) {
  unsigned int r;
  asm("v_cvt_pk_bf16_f32 %0, %1, %2" : "=v"(r) : "v"(lo), "v"(hi));
  return r;
}
__device__ __forceinline__ f32x4 mfma16(short8 a, short8 b, f32x4 c) {
  return __builtin_amdgcn_mfma_f32_16x16x32_bf16(
      __builtin_bit_cast(bf16x8, a), __builtin_bit_cast(bf16x8, b), c, 0, 0, 0);
}
__device__ __forceinline__ f32x16 mfma32(short8 a, short8 b, f32x16 c) {
  return __builtin_amdgcn_mfma_f32_32x32x16_bf16(
      __builtin_bit_cast(bf16x8, a), __builtin_bit_cast(bf16x8, b), c, 0, 0, 0);
}
__device__ __forceinline__ void gload_lds16(const void* g, void* l) {
  __builtin_amdgcn_global_load_lds(
      (__attribute__((address_space(1))) const void*)(uintptr_t)g,
      (__attribute__((address_space(3))) void*)(unsigned int)(uintptr_t)l,
      16, 0, 0);
}

// ---- fused prep: x fp32->bf16 convert + 4 weight transposes, 1D grid ----
__global__ __launch_bounds__(256) void k_prep(const float* __restrict__ x,
                                              const float* __restrict__ wq,
                                              const float* __restrict__ wk,
                                              const float* __restrict__ wv,
                                              const float* __restrict__ wo,
                                              short* __restrict__ xb,
                                              short* __restrict__ wT,
                                              short* __restrict__ woT) {
  __shared__ __align__(16) float tile[64][68];
  const int bid = blockIdx.x, t = threadIdx.x;
  if (bid < 4096) {  // cvt
    int i = bid * 256 + t;
    f32x4 a = *(const f32x4*)(x + (size_t)i * 8);
    f32x4 b = *(const f32x4*)(x + (size_t)i * 8 + 4);
    short8 o;
#pragma unroll
    for (int j = 0; j < 4; ++j) { o[j] = f2bs(a[j]); o[4 + j] = f2bs(b[j]); }
    *(short8*)(xb + (size_t)i * 8) = o;
    return;
  }
  const float* src;
  short* dst;
  int N, id;
  if (bid < 5120)      { id = bid - 4096; src = wq; dst = wT;                        N = 2048; }
  else if (bid < 5376) { id = bid - 5120; src = wk; dst = wT + (size_t)2048 * 2048;  N = 512;  }
  else if (bid < 5632) { id = bid - 5376; src = wv; dst = wT + (size_t)2560 * 2048;  N = 512;  }
  else                 { id = bid - 5632; src = wo; dst = woT;                       N = 2048; }
  const int K = 2048;
  int k0 = (id & 31) * 64, n0 = (id >> 5) * 64;
#pragma unroll
  for (int rep = 0; rep < 4; ++rep) {
    int lin = rep * 1024 + t * 4;
    int kk = lin >> 6, nn = lin & 63;
    f32x4 v = *(const f32x4*)(src + (size_t)(k0 + kk) * N + n0 + nn);
    *(f32x4*)(&tile[kk][nn]) = v;
  }
  __syncthreads();
#pragma unroll
  for (int rep = 0; rep < 4; ++rep) {
    int lin = rep * 1024 + t * 4;
    int nn = lin >> 6, kk = lin & 63;
    short4v o;
#pragma unroll
    for (int j = 0; j < 4; ++j) o[j] = f2bs(tile[kk + j][nn]);
    *(short4v*)(dst + (size_t)(n0 + nn) * K + k0 + kk) = o;
  }
}

// ---------------- GEMM: C[M][N] = A[M][K] * Bt[N][K]^T ----------------
template <int FP32OUT>
__global__ __launch_bounds__(256) void k_gemm_bt(const short* __restrict__ A,
                                                 const short* __restrict__ Bt,
                                                 void* __restrict__ Cp,
                                                 int M, int N, int K) {
  __shared__ short As[128 * 32];
  __shared__ short Bs[128 * 32];
  const int t = threadIdx.x, l = t & 63, w = t >> 6;
  const int wr = w >> 1, wc = w & 1;
  const int gx = gridDim.x;
  const int id = blockIdx.y * gx + blockIdx.x;
  const int per = (gx * gridDim.y) >> 3;
  const int id2 = (id & 7) * per + (id >> 3);
  const int m0 = (id2 % gx) * 128, n0 = (id2 / gx) * 128;
  const int lrow = l & 15, lg = l >> 4;

  f32x4 acc[4][4] = {};

  const int srow0 = (t >> 2);
  const int srow1 = 64 + (t >> 2);
  const int sk0 = (((t & 3) ^ (srow0 & 3)) * 8);
  const int sk1 = (((t & 3) ^ (srow1 & 3)) * 8);
  const short* Ab = A + (size_t)m0 * K;
  const short* Bb = Bt + (size_t)n0 * K;
  short* AsB0 = As + w * 512;
  short* AsB1 = As + 2048 + w * 512;
  short* BsB0 = Bs + w * 512;
  short* BsB1 = Bs + 2048 + w * 512;

  for (int k0 = 0; k0 < K; k0 += 32) {
    gload_lds16(Ab + (size_t)srow0 * K + k0 + sk0, AsB0);
    gload_lds16(Ab + (size_t)srow1 * K + k0 + sk1, AsB1);
    gload_lds16(Bb + (size_t)srow0 * K + k0 + sk0, BsB0);
    gload_lds16(Bb + (size_t)srow1 * K + k0 + sk1, BsB1);
    __syncthreads();
    short8 af[4], bf[4];
#pragma unroll
    for (int mi = 0; mi < 4; ++mi) {
      int r = wr * 64 + mi * 16 + lrow;
      af[mi] = *(const short8*)(As + r * 32 + ((lg ^ (r & 3)) * 8));
    }
#pragma unroll
    for (int ni = 0; ni < 4; ++ni) {
      int r = wc * 64 + ni * 16 + lrow;
      bf[ni] = *(const short8*)(Bs + r * 32 + ((lg ^ (r & 3)) * 8));
    }
#pragma unroll
    for (int mi = 0; mi < 4; ++mi)
#pragma unroll
      for (int ni = 0; ni < 4; ++ni)
        acc[mi][ni] = mfma16(af[mi], bf[ni], acc[mi][ni]);
    __syncthreads();
  }
#pragma unroll
  for (int mi = 0; mi < 4; ++mi)
#pragma unroll
    for (int ni = 0; ni < 4; ++ni) {
      int row = m0 + wr * 64 + mi * 16 + lg * 4;
      int col = n0 + wc * 64 + ni * 16 + lrow;
#pragma unroll
      for (int v = 0; v < 4; ++v) {
        float val = acc[mi][ni][v];
        if constexpr (FP32OUT)
          ((float*)Cp)[(size_t)(row + v) * N + col] = val;
        else
          ((short*)Cp)[(size_t)(row + v) * N + col] = f2bs(val);
      }
    }
}

// ---- fused RoPE (q,k in-place; q also *QSCALE2) + V transpose, 1D grid ----
__global__ __launch_bounds__(256) void k_rv(short* __restrict__ qkv,
                                            const float* __restrict__ fcos,
                                            const float* __restrict__ fsin,
                                            short* __restrict__ vt) {
  __shared__ short tile[128 * 137];
  const int bid = blockIdx.x, t = threadIdx.x;
  if (bid < 5120) {  // rope
    int tid = bid * 256 + t;
    int p16 = tid & 15;
    int slice = (tid >> 4) % 20;
    int bs = tid / 320;
    int col = (slice < 16) ? slice * 128 + p16 * 8
                           : 2048 + (slice - 16) * 128 + p16 * 8;
    short8 x = *(short8*)(qkv + (size_t)bs * LDQKV + col);
    f32x4 c = *(const f32x4*)(fcos + (size_t)bs * 64 + p16 * 4);
    f32x4 s = *(const f32x4*)(fsin + (size_t)bs * 64 + p16 * 4);
    float sc = (slice < 16) ? QSCALE2 : 1.0f;
    short8 o;
#pragma unroll
    for (int j = 0; j < 4; ++j) {
      float xr = bs2f(x[2 * j]), xi = bs2f(x[2 * j + 1]);
      o[2 * j] = f2bs((xr * c[j] - xi * s[j]) * sc);
      o[2 * j + 1] = f2bs((xr * s[j] + xi * c[j]) * sc);
    }
    *(short8*)(qkv + (size_t)bs * LDQKV + col) = o;
    return;
  }
  const int id = bid - 5120;
  int s0 = (id & 15) * 128;
  int kvh = (id >> 4) & 3, b = id >> 6;
  const short* src = qkv + (size_t)(b * SEQ) * LDQKV + 2560 + kvh * 128;
#pragma unroll
  for (int rep = 0; rep < 8; ++rep) {
    int lin = rep * 2048 + t * 8;
    int si = lin >> 7, d = lin & 127;
    short8 v = *(const short8*)(src + (size_t)(s0 + si) * LDQKV + d);
#pragma unroll
    for (int j = 0; j < 8; ++j) tile[si * 137 + d + j] = v[j];
  }
  __syncthreads();
  short* dst = vt + (size_t)((b * 4 + kvh) * 128) * SEQ;
#pragma unroll
  for (int rep = 0; rep < 8; ++rep) {
    int lin = rep * 2048 + t * 8;
    int d = lin >> 7, sb = lin & 127;
    short8 o;
#pragma unroll
    for (int j = 0; j < 8; ++j) o[j] = tile[(sb + j) * 137 + d];
    *(short8*)(dst + (size_t)d * SEQ + s0 + sb) = o;
  }
}

// ---------------- flash attention (causal, GQA), 32x32 MFMA ----------------
// grid (16,16,2)=512 blocks x 256 th (4 waves), 64KB LDS -> 2 blocks/CU.
// Wave = (row-half wr, key-half wk). Swapped QK^T (S^T = mfma(K,Q)) -> P
// lane-local; P->bf16 via cvt_pk + __shfl_xor(32) exchange (no P LDS).
// Cross-wk online-softmax merge once per part through retired Ks/Vs LDS.
__global__ __launch_bounds__(256, 2) void k_attn(const short* __restrict__ qkv,
                                                 const short* __restrict__ vt,
                                                 short* __restrict__ outp) {
  __shared__ short Ks[2][64 * 128];
  __shared__ short Vs[2][128 * 64];
  const int t = threadIdx.x, l = t & 63, w = t >> 6;
  const int wr = w >> 1, wk = w & 1;
  const int h = blockIdx.y, b = blockIdx.z;
  const int kvh = h >> 2;
  const int lo5 = l & 31, hi = l >> 5;

  const int kkey = t >> 4, kd8 = t & 15;
  const int vdd = t >> 3, vs8 = t & 7;
  const short* kbase = qkv + (size_t)(b * SEQ) * LDQKV + 2048 + kvh * HD;
  const short* vbase = vt + (size_t)((b * 4 + kvh) * 128) * SEQ;

  auto stageKV = [&](int buf, int it) {
    const int kt = it * 64;
    short* kdst = &Ks[buf][w * 512];
    short* vdst = &Vs[buf][w * 512];
#pragma unroll
    for (int i = 0; i < 4; ++i) {
      int key = i * 16 + kkey;
      int sd = (kd8 ^ (key & 7)) * 8;
      gload_lds16(kbase + (size_t)(kt + key) * LDQKV + sd, kdst + i * 2048);
    }
#pragma unroll
    for (int i = 0; i < 4; ++i) {
      int d = i * 32 + vdd;
      int ss = (vs8 ^ (d & 7)) * 8;
      gload_lds16(vbase + (size_t)d * SEQ + kt + ss, vdst + i * 2048);
    }
  };

  // loop-invariant LDS short-offsets (XOR-swizzled 16B granules)
  int koff[8], voff[4][2];
#pragma unroll
  for (int s = 0; s < 8; ++s)
    koff[s] = (wk * 32 + lo5) * 128 + (((hi + 2 * s) ^ (l & 7)) * 8);
#pragma unroll
  for (int db = 0; db < 4; ++db)
#pragma unroll
    for (int s = 0; s < 2; ++s)
      voff[db][s] =
          (db * 32 + lo5) * 64 + (((4 * wk + hi + 2 * s) ^ (l & 7)) * 8);
  const int kbloc = wk * 32 + 4 * hi;   // key-local base for masking
  const int qloc = wr * 32 + lo5;       // q-local within 64-row tile

  for (int part = 0; part < 2; ++part) {
    const int qt = part ? (31 - (int)blockIdx.x) : (int)blockIdx.x;
    const int q0 = qt * 64;

    short8 qf[8];
    {
      const short* qrow =
          qkv + (size_t)(b * SEQ + q0 + wr * 32 + lo5) * LDQKV + h * HD;
#pragma unroll
      for (int s = 0; s < 8; ++s)
        qf[s] = *(const short8*)(qrow + s * 16 + hi * 8);
    }

    f32x16 of[4] = {};
    float mrun = 0.f, lsum = 0.f;

    const int nt = qt + 1;
    stageKV(0, 0);
    __syncthreads();

    for (int it = 0; it < nt; ++it) {
      const int buf = it & 1;
      if (it + 1 < nt) stageKV(buf ^ 1, it + 1);  // prefetch; drained at barrier
      const short* KsC = Ks[buf];
      const short* VsC = Vs[buf];

      // S^T = K . Q^T  (keys = this wave's 32-key half, q = 32 rows)
      f32x16 sc = {};
      __builtin_amdgcn_s_setprio(1);
#pragma unroll
      for (int s = 0; s < 8; ++s) {
        short8 kf = *(const short8*)(KsC + koff[s]);
        sc = mfma32(kf, qf[s], sc);
      }
      __builtin_amdgcn_s_setprio(0);

      if (it == nt - 1) {  // diagonal tile: mask key_local > q_local
#pragma unroll
        for (int r = 0; r < 16; ++r) {
          const int off = (r & 3) + 8 * (r >> 2);
          if (kbloc + off > qloc) sc[r] = -1e30f;
        }
      }

      // defer-max: rescale only if some lane's local max > mrun + 8
      float lmax = sc[0];
#pragma unroll
      for (int r = 1; r < 16; ++r) lmax = fmaxf(lmax, sc[r]);
      if (__any(lmax > mrun + 8.f)) {  // rare slow path
        float mx = fmaxf(lmax, __shfl_xor(lmax, 32));
        float mm = fmaxf(mrun, mx);
        float rs = exp2f(mrun - mm);
        mrun = mm;
        lsum *= rs;
#pragma unroll
        for (int db = 0; db < 4; ++db)
#pragma unroll
          for (int r = 0; r < 16; ++r) of[db][r] *= rs;
      }

      // P^T = exp2(S^T - m): lane-local; pack to bf16 pairs
      float p[16];
#pragma unroll
      for (int r = 0; r < 16; ++r) {
        p[r] = exp2f(sc[r] - mrun);
        lsum += p[r];
      }
      unsigned int pk[8];
#pragma unroll
      for (int j = 0; j < 8; ++j) pk[j] = cvt_pk(p[2 * j], p[2 * j + 1]);

      // lane<->lane^32 exchange via shfl_xor: build B-fragments
      // (keys 0-15 of this wave's half -> pb[0], 16-31 -> pb[1])
      unsigned int s0 = hi ? pk[0] : pk[2];
      unsigned int s1 = hi ? pk[1] : pk[3];
      unsigned int s2 = hi ? pk[4] : pk[6];
      unsigned int s3 = hi ? pk[5] : pk[7];
      unsigned int x0 = __shfl_xor(s0, 32);
      unsigned int x1 = __shfl_xor(s1, 32);
      unsigned int x2 = __shfl_xor(s2, 32);
      unsigned int x3 = __shfl_xor(s3, 32);
      u32x4 b0w, b1w;
      b0w.x = hi ? x0 : pk[0];
      b0w.y = hi ? x1 : pk[1];
      b0w.z = hi ? pk[2] : x0;
      b0w.w = hi ? pk[3] : x1;
      b1w.x = hi ? x2 : pk[4];
      b1w.y = hi ? x3 : pk[5];
      b1w.z = hi ? pk[6] : x2;
      b1w.w = hi ? pk[7] : x3;
      short8 pb[2] = {__builtin_bit_cast(short8, b0w),
                      __builtin_bit_cast(short8, b1w)};

      // of^T += V^T . P^T
      __builtin_amdgcn_s_setprio(1);
#pragma unroll
      for (int s = 0; s < 2; ++s)
#pragma unroll
        for (int db = 0; db < 4; ++db) {
          short8 vf = *(const short8*)(VsC + voff[db][s]);
          of[db] = mfma32(vf, pb[s], of[db]);
        }
      __builtin_amdgcn_s_setprio(0);
      __syncthreads();  // drains prefetch vmcnt + fences buffer swap
    }

    // ---- pair-merge (hi halves), then cross-wk merge via retired LDS ----
    lsum += __shfl_xor(lsum, 32);
    float* og = (float*)Ks;       // 32KB: of-exchange (wk=1 waves)
    float* sg = (float*)Vs;       // stats exchange
    if (wk == 1) {
#pragma unroll
      for (int db = 0; db < 4; ++db)
#pragma unroll
        for (int r4 = 0; r4 < 4; ++r4) {
          int g = db * 4 + r4;
          f32x4 v;
#pragma unroll
          for (int j = 0; j < 4; ++j) v[j] = of[db][r4 * 4 + j];
          *(f32x4*)&og[wr * 4096 + l * 64 + ((g ^ (l & 15)) * 4)] = v;
        }
      sg[wr * 64 + l] = mrun;
      sg[128 + wr * 64 + l] = lsum;
    }
    __syncthreads();
    if (wk == 0) {
      float m1 = sg[wr * 64 + l];
      float l1 = sg[128 + wr * 64 + l];
      float mt = fmaxf(mrun, m1);
      float r0 = exp2f(mrun - mt), r1 = exp2f(m1 - mt);
      float inv = 1.0f / (lsum * r0 + l1 * r1);
      short* ob =
          outp + (size_t)(b * SEQ + q0 + wr * 32 + lo5) * 2048 + h * HD;
#pragma unroll
      for (int db = 0; db < 4; ++db) {
#pragma unroll
        for (int r4 = 0; r4 < 4; ++r4) {
          int g = db * 4 + r4;
          f32x4 o1 = *(const f32x4*)&og[wr * 4096 + l * 64 +
                                        ((g ^ (l & 15)) * 4)];
          u32x2 pko;
          float v0 = (of[db][r4 * 4 + 0] * r0 + o1[0] * r1) * inv;
          float v1 = (of[db][r4 * 4 + 1] * r0 + o1[1] * r1) * inv;
          float v2 = (of[db][r4 * 4 + 2] * r0 + o1[2] * r1) * inv;
          float v3 = (of[db][r4 * 4 + 3] * r0 + o1[3] * r1) * inv;
          pko.x = cvt_pk(v0, v1);
          pko.y = cvt_pk(v2, v3);
          *(u32x2*)(ob + db * 32 + 8 * r4 + 4 * hi) = pko;
        }
      }
    }
    __syncthreads();  // protect merge region before next part's staging
  }
}

extern "C" void kernel_launch(void* const* d_in, const int* in_sizes, int n_in,
                              void* d_out, int out_size, void* d_ws,
                              size_t ws_size, hipStream_t stream) {
  const float* x = (const float*)d_in[0];
  const float* wq = (const float*)d_in[1];
  const float* wk = (const float*)d_in[2];
  const float* wv = (const float*)d_in[3];
  const float* wo = (const float*)d_in[4];
  const float* fc = (const float*)d_in[5];
  const float* fs = (const float*)d_in[6];

  char* ws = (char*)d_ws;
  short* xb = (short*)(ws);                           // [4096][2048] 16MB
  short* wT = (short*)(ws + (16ull << 20));           // [3072][2048] 12MB
  short* woT = (short*)(ws + (28ull << 20));          // [2048][2048] 8MB
  short* qkvb = (short*)(ws + (36ull << 20));         // [4096][3072] 24MB
  short* vtb = (short*)(ws + (16ull << 20));          // alias wT (dead) 4MB
  short* attn = (short*)(ws);                         // alias xb (dead) 16MB

  k_prep<<<6656, 256, 0, stream>>>(x, wq, wk, wv, wo, xb, wT, woT);
  k_gemm_bt<0><<<dim3(32, 24), 256, 0, stream>>>(xb, wT, qkvb, 4096, 3072, 2048);
  k_rv<<<5248, 256, 0, stream>>>(qkvb, fc, fs, vtb);
  k_attn<<<dim3(16, 16, 2), 256, 0, stream>>>(qkvb, vtb, attn);
  k_gemm_bt<1><<<dim3(32, 16), 256, 0, stream>>>(attn, woT, d_out, 4096, 2048, 2048);
}

// Round 9
// 213.087 us; speedup vs baseline: 1.5454x; 1.0442x over previous
//
#include <hip/hip_runtime.h>
#include <stdint.h>

#define SEQ   2048
#define NB    2
#define LDQKV 3072
#define HD    128
// 1/sqrt(128) * log2(e): QK^T scores land in base-2 domain -> exp2 directly.
#define QSCALE2 (0.08838834764831845f * 1.44269504088896340f)

typedef __attribute__((ext_vector_type(8))) short short8;
typedef __attribute__((ext_vector_type(4))) short short4v;
typedef __attribute__((ext_vector_type(4))) float f32x4;
typedef __attribute__((ext_vector_type(16))) float f32x16;
typedef __attribute__((ext_vector_type(4))) unsigned int u32x4;
typedef __attribute__((ext_vector_type(2))) unsigned int u32x2;
typedef __attribute__((ext_vector_type(8))) __bf16 bf16x8;

__device__ __forceinline__ float bs2f(short s) {
  unsigned int u = ((unsigned int)(unsigned short)s) << 16;
  return __builtin_bit_cast(float, u);
}
__device__ __forceinline__ short f2bs(float f) {
  unsigned int u = __builtin_bit_cast(unsigned int, f);
  u += 0x7fffu + ((u >> 16) & 1u);
  return (short)(u >> 16);
}
__device__ __forceinline__ unsigned int cvt_pk(float lo, float hi) {
  unsigned int r;
  asm("v_cvt_pk_bf16_f32 %0, %1, %2" : "=v"(r) : "v"(lo), "v"(hi));
  return r;
}
__device__ __forceinline__ f32x4 mfma16(short8 a, short8 b, f32x4 c) {
  return __builtin_amdgcn_mfma_f32_16x16x32_bf16(
      __builtin_bit_cast(bf16x8, a), __builtin_bit_cast(bf16x8, b), c, 0, 0, 0);
}
__device__ __forceinline__ f32x16 mfma32(short8 a, short8 b, f32x16 c) {
  return __builtin_amdgcn_mfma_f32_32x32x16_bf16(
      __builtin_bit_cast(bf16x8, a), __builtin_bit_cast(bf16x8, b), c, 0, 0, 0);
}
__device__ __forceinline__ void gload_lds16(const void* g, void* l) {
  __builtin_amdgcn_global_load_lds(
      (__attribute__((address_space(1))) const void*)(uintptr_t)g,
      (__attribute__((address_space(3))) void*)(unsigned int)(uintptr_t)l,
      16, 0, 0);
}

#define SBAR() asm volatile("s_barrier" ::: "memory")
#define LGKM0() asm volatile("s_waitcnt lgkmcnt(0)" ::: "memory")
#define VMC4() asm volatile("s_waitcnt vmcnt(4)" ::: "memory")
#define VMC0() asm volatile("s_waitcnt vmcnt(0)" ::: "memory")

// ---- fused prep: x fp32->bf16 convert + 4 weight transposes, 1D grid ----
__global__ __launch_bounds__(256) void k_prep(const float* __restrict__ x,
                                              const float* __restrict__ wq,
                                              const float* __restrict__ wk,
                                              const float* __restrict__ wv,
                                              const float* __restrict__ wo,
                                              short* __restrict__ xb,
                                              short* __restrict__ wT,
                                              short* __restrict__ woT) {
  __shared__ __align__(16) float tile[64][68];
  const int bid = blockIdx.x, t = threadIdx.x;
  if (bid < 4096) {  // cvt
    int i = bid * 256 + t;
    f32x4 a = *(const f32x4*)(x + (size_t)i * 8);
    f32x4 b = *(const f32x4*)(x + (size_t)i * 8 + 4);
    short8 o;
#pragma unroll
    for (int j = 0; j < 4; ++j) { o[j] = f2bs(a[j]); o[4 + j] = f2bs(b[j]); }
    *(short8*)(xb + (size_t)i * 8) = o;
    return;
  }
  const float* src;
  short* dst;
  int N, id;
  if (bid < 5120)      { id = bid - 4096; src = wq; dst = wT;                        N = 2048; }
  else if (bid < 5376) { id = bid - 5120; src = wk; dst = wT + (size_t)2048 * 2048;  N = 512;  }
  else if (bid < 5632) { id = bid - 5376; src = wv; dst = wT + (size_t)2560 * 2048;  N = 512;  }
  else                 { id = bid - 5632; src = wo; dst = woT;                       N = 2048; }
  const int K = 2048;
  int k0 = (id & 31) * 64, n0 = (id >> 5) * 64;
#pragma unroll
  for (int rep = 0; rep < 4; ++rep) {
    int lin = rep * 1024 + t * 4;
    int kk = lin >> 6, nn = lin & 63;
    f32x4 v = *(const f32x4*)(src + (size_t)(k0 + kk) * N + n0 + nn);
    *(f32x4*)(&tile[kk][nn]) = v;
  }
  __syncthreads();
#pragma unroll
  for (int rep = 0; rep < 4; ++rep) {
    int lin = rep * 1024 + t * 4;
    int nn = lin >> 6, kk = lin & 63;
    short4v o;
#pragma unroll
    for (int j = 0; j < 4; ++j) o[j] = f2bs(tile[kk + j][nn]);
    *(short4v*)(dst + (size_t)(n0 + nn) * K + k0 + kk) = o;
  }
}

// ------- GEMM 256x256 tile, 8-phase counted-vmcnt schedule (T2+T3+T4+T5) ----
// C[M][N] = A[M][K] * Bt[N][K]^T. 512 threads (8 waves, 2M x 4N), BK=64,
// LDS 128 KB (2 dbuf x 2 half x 128x64 x {A,B}). Phases = block quadrants
// (0,0),(0,1),(1,1),(1,0); one half-tile staged per phase into the slot
// freed the previous phase; vmcnt(4) at K-tile boundaries (never 0 until
// the end-game). XOR-8 granule swizzle on 128B rows (conflict-free b128).
template <int FP32OUT>
__global__ __launch_bounds__(512, 2) void k_gemm256(const short* __restrict__ A,
                                                    const short* __restrict__ Bt,
                                                    void* __restrict__ Cp,
                                                    int M, int N, int K) {
  __shared__ short Al[2][2][128 * 64];
  __shared__ short Bl[2][2][128 * 64];
  const int t = threadIdx.x, l = t & 63, w = t >> 6;
  const int pm = w >> 2, pn = w & 3;
  const int lrow = l & 15, lg = l >> 4;
  const int NT = K >> 6;

  const int nbm = M >> 8;
  const int per = gridDim.x >> 3;
  const int id2 = (blockIdx.x & 7) * per + (blockIdx.x >> 3);
  const int m0 = (id2 % nbm) * 256, n0 = (id2 / nbm) * 256;

  // staging: thread covers (row = j*64 + w*8 + l/8, granule slot l&7),
  // global source pre-swizzled so linear LDS holds XOR-8 swizzled layout.
  const int srow = w * 8 + (l >> 3);
  const int sgx = ((l & 7) ^ (srow & 7)) * 8;
  const short* Abase = A + (size_t)(m0 + srow) * K + sgx;
  const short* Bbase = Bt + (size_t)(n0 + srow) * K + sgx;

  f32x4 acc[8][4] = {};
  short8 aFr[4][2], bFr[2][2];

  auto stgA = [&](int d, int h, int tv) {
    const short* g = Abase + (size_t)(h * 128) * K + (size_t)tv * 64;
    gload_lds16(g, &Al[d][h][w * 512]);
    gload_lds16(g + (size_t)64 * K, &Al[d][h][w * 512 + 4096]);
  };
  auto stgB = [&](int d, int h, int tv) {
    const short* g = Bbase + (size_t)(h * 128) * K + (size_t)tv * 64;
    gload_lds16(g, &Bl[d][h][w * 512]);
    gload_lds16(g + (size_t)64 * K, &Bl[d][h][w * 512 + 4096]);
  };
  auto rdA = [&](int d, int Mh) {
#pragma unroll
    for (int mi = 0; mi < 4; ++mi) {
      int rl = pm * 64 + mi * 16 + lrow;
#pragma unroll
      for (int kk = 0; kk < 2; ++kk)
        aFr[mi][kk] = *(const short8*)&Al[d][Mh][rl * 64 +
                                                 (((kk * 4 + lg) ^ (rl & 7)) * 8)];
    }
  };
  auto rdB = [&](int d, int Nh) {
#pragma unroll
    for (int ni = 0; ni < 2; ++ni) {
      int rl = pn * 32 + ni * 16 + lrow;
#pragma unroll
      for (int kk = 0; kk < 2; ++kk)
        bFr[ni][kk] = *(const short8*)&Bl[d][Nh][rl * 64 +
                                                 (((kk * 4 + lg) ^ (rl & 7)) * 8)];
    }
  };

#define MMQ(Mh, Nh)                                                          \
  do {                                                                       \
    __builtin_amdgcn_s_setprio(1);                                           \
    _Pragma("unroll") for (int mi = 0; mi < 4; ++mi)                         \
        _Pragma("unroll") for (int ni = 0; ni < 2; ++ni)                     \
            _Pragma("unroll") for (int kk = 0; kk < 2; ++kk)                 \
                acc[(Mh)*4 + mi][(Nh)*2 + ni] =                              \
                    mfma16(aFr[mi][kk], bFr[ni][kk],                         \
                           acc[(Mh)*4 + mi][(Nh)*2 + ni]);                   \
    __builtin_amdgcn_s_setprio(0);                                           \
    __builtin_amdgcn_sched_barrier(0);                                       \
  } while (0)

  // prologue: A0(0),B0(0),B1(0),A1(0) complete; A0(1),B1(1) in flight
  stgA(0, 0, 0); stgB(0, 0, 0); stgB(0, 1, 0); stgA(0, 1, 0);
  stgA(1, 0, 1); stgB(1, 1, 1);
  VMC4();
  SBAR();

  for (int v = 0; v < NT; ++v) {
    const int d = v & 1, d1 = d ^ 1;
    // phase 0: quadrant (0,0); stage B0(v+1)
    rdA(d, 0); rdB(d, 0);
    if (v + 1 < NT) stgB(d1, 0, v + 1);
    SBAR(); LGKM0(); __builtin_amdgcn_sched_barrier(0);
    MMQ(0, 0);
    SBAR();
    // phase 1: (0,1); stage A1(v+1)
    rdB(d, 1);
    if (v + 1 < NT) stgA(d1, 1, v + 1);
    SBAR(); LGKM0(); __builtin_amdgcn_sched_barrier(0);
    MMQ(0, 1);
    SBAR();
    // phase 2: (1,1); stage A0(v+2)
    rdA(d, 1);
    if (v + 2 < NT) stgA(d, 0, v + 2);
    SBAR(); LGKM0(); __builtin_amdgcn_sched_barrier(0);
    MMQ(1, 1);
    SBAR();
    // phase 3: (1,0); stage B1(v+2)
    rdB(d, 0);
    if (v + 2 < NT) stgB(d, 1, v + 2);
    SBAR(); LGKM0(); __builtin_amdgcn_sched_barrier(0);
    MMQ(1, 0);
    // K-tile boundary: counted drain (tile v+1 forced complete)
    if (v + 2 < NT) { VMC4(); } else { VMC0(); }
    SBAR();
  }
#undef MMQ

#pragma unroll
  for (int Mh = 0; Mh < 2; ++Mh)
#pragma unroll
    for (int mi = 0; mi < 4; ++mi)
#pragma unroll
      for (int Nh = 0; Nh < 2; ++Nh)
#pragma unroll
        for (int ni = 0; ni < 2; ++ni) {
          int row = m0 + Mh * 128 + pm * 64 + mi * 16 + lg * 4;
          int col = n0 + Nh * 128 + pn * 32 + ni * 16 + lrow;
          f32x4 vv = acc[Mh * 4 + mi][Nh * 2 + ni];
#pragma unroll
          for (int v2 = 0; v2 < 4; ++v2) {
            if constexpr (FP32OUT)
              ((float*)Cp)[(size_t)(row + v2) * N + col] = vv[v2];
            else
              ((short*)Cp)[(size_t)(row + v2) * N + col] = f2bs(vv[v2]);
          }
        }
}

// ---- fused RoPE (q,k in-place; q also *QSCALE2) + V transpose, 1D grid ----
__global__ __launch_bounds__(256) void k_rv(short* __restrict__ qkv,
                                            const float* __restrict__ fcos,
                                            const float* __restrict__ fsin,
                                            short* __restrict__ vt) {
  __shared__ short tile[128 * 137];
  const int bid = blockIdx.x, t = threadIdx.x;
  if (bid < 5120) {  // rope
    int tid = bid * 256 + t;
    int p16 = tid & 15;
    int slice = (tid >> 4) % 20;
    int bs = tid / 320;
    int col = (slice < 16) ? slice * 128 + p16 * 8
                           : 2048 + (slice - 16) * 128 + p16 * 8;
    short8 x = *(short8*)(qkv + (size_t)bs * LDQKV + col);
    f32x4 c = *(const f32x4*)(fcos + (size_t)bs * 64 + p16 * 4);
    f32x4 s = *(const f32x4*)(fsin + (size_t)bs * 64 + p16 * 4);
    float sc = (slice < 16) ? QSCALE2 : 1.0f;
    short8 o;
#pragma unroll
    for (int j = 0; j < 4; ++j) {
      float xr = bs2f(x[2 * j]), xi = bs2f(x[2 * j + 1]);
      o[2 * j] = f2bs((xr * c[j] - xi * s[j]) * sc);
      o[2 * j + 1] = f2bs((xr * s[j] + xi * c[j]) * sc);
    }
    *(short8*)(qkv + (size_t)bs * LDQKV + col) = o;
    return;
  }
  const int id = bid - 5120;
  int s0 = (id & 15) * 128;
  int kvh = (id >> 4) & 3, b = id >> 6;
  const short* src = qkv + (size_t)(b * SEQ) * LDQKV + 2560 + kvh * 128;
#pragma unroll
  for (int rep = 0; rep < 8; ++rep) {
    int lin = rep * 2048 + t * 8;
    int si = lin >> 7, d = lin & 127;
    short8 v = *(const short8*)(src + (size_t)(s0 + si) * LDQKV + d);
#pragma unroll
    for (int j = 0; j < 8; ++j) tile[si * 137 + d + j] = v[j];
  }
  __syncthreads();
  short* dst = vt + (size_t)((b * 4 + kvh) * 128) * SEQ;
#pragma unroll
  for (int rep = 0; rep < 8; ++rep) {
    int lin = rep * 2048 + t * 8;
    int d = lin >> 7, sb = lin & 127;
    short8 o;
#pragma unroll
    for (int j = 0; j < 8; ++j) o[j] = tile[(sb + j) * 137 + d];
    *(short8*)(dst + (size_t)d * SEQ + s0 + sb) = o;
  }
}

// ---------------- flash attention (causal, GQA), 32x32 MFMA ----------------
__global__ __launch_bounds__(256, 2) void k_attn(const short* __restrict__ qkv,
                                                 const short* __restrict__ vt,
                                                 short* __restrict__ outp) {
  __shared__ short Ks[2][64 * 128];
  __shared__ short Vs[2][128 * 64];
  const int t = threadIdx.x, l = t & 63, w = t >> 6;
  const int wr = w >> 1, wk = w & 1;
  const int h = blockIdx.y, b = blockIdx.z;
  const int kvh = h >> 2;
  const int lo5 = l & 31, hi = l >> 5;

  const int kkey = t >> 4, kd8 = t & 15;
  const int vdd = t >> 3, vs8 = t & 7;
  const short* kbase = qkv + (size_t)(b * SEQ) * LDQKV + 2048 + kvh * HD;
  const short* vbase = vt + (size_t)((b * 4 + kvh) * 128) * SEQ;

  auto stageKV = [&](int buf, int it) {
    const int kt = it * 64;
    short* kdst = &Ks[buf][w * 512];
    short* vdst = &Vs[buf][w * 512];
#pragma unroll
    for (int i = 0; i < 4; ++i) {
      int key = i * 16 + kkey;
      int sd = (kd8 ^ (key & 7)) * 8;
      gload_lds16(kbase + (size_t)(kt + key) * LDQKV + sd, kdst + i * 2048);
    }
#pragma unroll
    for (int i = 0; i < 4; ++i) {
      int d = i * 32 + vdd;
      int ss = (vs8 ^ (d & 7)) * 8;
      gload_lds16(vbase + (size_t)d * SEQ + kt + ss, vdst + i * 2048);
    }
  };

  int koff[8], voff[4][2];
#pragma unroll
  for (int s = 0; s < 8; ++s)
    koff[s] = (wk * 32 + lo5) * 128 + (((hi + 2 * s) ^ (l & 7)) * 8);
#pragma unroll
  for (int db = 0; db < 4; ++db)
#pragma unroll
    for (int s = 0; s < 2; ++s)
      voff[db][s] =
          (db * 32 + lo5) * 64 + (((4 * wk + hi + 2 * s) ^ (l & 7)) * 8);
  const int kbloc = wk * 32 + 4 * hi;
  const int qloc = wr * 32 + lo5;

  for (int part = 0; part < 2; ++part) {
    const int qt = part ? (31 - (int)blockIdx.x) : (int)blockIdx.x;
    const int q0 = qt * 64;

    short8 qf[8];
    {
      const short* qrow =
          qkv + (size_t)(b * SEQ + q0 + wr * 32 + lo5) * LDQKV + h * HD;
#pragma unroll
      for (int s = 0; s < 8; ++s)
        qf[s] = *(const short8*)(qrow + s * 16 + hi * 8);
    }

    f32x16 of[4] = {};
    float mrun = 0.f, lsum = 0.f;

    const int nt = qt + 1;
    stageKV(0, 0);
    __syncthreads();

    for (int it = 0; it < nt; ++it) {
      const int buf = it & 1;
      if (it + 1 < nt) stageKV(buf ^ 1, it + 1);
      const short* KsC = Ks[buf];
      const short* VsC = Vs[buf];

      f32x16 sc = {};
      __builtin_amdgcn_s_setprio(1);
#pragma unroll
      for (int s = 0; s < 8; ++s) {
        short8 kf = *(const short8*)(KsC + koff[s]);
        sc = mfma32(kf, qf[s], sc);
      }
      __builtin_amdgcn_s_setprio(0);

      if (it == nt - 1) {
#pragma unroll
        for (int r = 0; r < 16; ++r) {
          const int off = (r & 3) + 8 * (r >> 2);
          if (kbloc + off > qloc) sc[r] = -1e30f;
        }
      }

      float lmax = sc[0];
#pragma unroll
      for (int r = 1; r < 16; ++r) lmax = fmaxf(lmax, sc[r]);
      if (__any(lmax > mrun + 8.f)) {
        float mx = fmaxf(lmax, __shfl_xor(lmax, 32));
        float mm = fmaxf(mrun, mx);
        float rs = exp2f(mrun - mm);
        mrun = mm;
        lsum *= rs;
#pragma unroll
        for (int db = 0; db < 4; ++db)
#pragma unroll
          for (int r = 0; r < 16; ++r) of[db][r] *= rs;
      }

      float p[16];
#pragma unroll
      for (int r = 0; r < 16; ++r) {
        p[r] = exp2f(sc[r] - mrun);
        lsum += p[r];
      }
      unsigned int pk[8];
#pragma unroll
      for (int j = 0; j < 8; ++j) pk[j] = cvt_pk(p[2 * j], p[2 * j + 1]);

      unsigned int s0 = hi ? pk[0] : pk[2];
      unsigned int s1 = hi ? pk[1] : pk[3];
      unsigned int s2 = hi ? pk[4] : pk[6];
      unsigned int s3 = hi ? pk[5] : pk[7];
      unsigned int x0 = __shfl_xor(s0, 32);
      unsigned int x1 = __shfl_xor(s1, 32);
      unsigned int x2 = __shfl_xor(s2, 32);
      unsigned int x3 = __shfl_xor(s3, 32);
      u32x4 b0w, b1w;
      b0w.x = hi ? x0 : pk[0];
      b0w.y = hi ? x1 : pk[1];
      b0w.z = hi ? pk[2] : x0;
      b0w.w = hi ? pk[3] : x1;
      b1w.x = hi ? x2 : pk[4];
      b1w.y = hi ? x3 : pk[5];
      b1w.z = hi ? pk[6] : x2;
      b1w.w = hi ? pk[7] : x3;
      short8 pb[2] = {__builtin_bit_cast(short8, b0w),
                      __builtin_bit_cast(short8, b1w)};

      __builtin_amdgcn_s_setprio(1);
#pragma unroll
      for (int s = 0; s < 2; ++s)
#pragma unroll
        for (int db = 0; db < 4; ++db) {
          short8 vf = *(const short8*)(VsC + voff[db][s]);
          of[db] = mfma32(vf, pb[s], of[db]);
        }
      __builtin_amdgcn_s_setprio(0);
      __syncthreads();
    }

    lsum += __shfl_xor(lsum, 32);
    float* og = (float*)Ks;
    float* sg = (float*)Vs;
    if (wk == 1) {
#pragma unroll
      for (int db = 0; db < 4; ++db)
#pragma unroll
        for (int r4 = 0; r4 < 4; ++r4) {
          int g = db * 4 + r4;
          f32x4 v;
#pragma unroll
          for (int j = 0; j < 4; ++j) v[j] = of[db][r4 * 4 + j];
          *(f32x4*)&og[wr * 4096 + l * 64 + ((g ^ (l & 15)) * 4)] = v;
        }
      sg[wr * 64 + l] = mrun;
      sg[128 + wr * 64 + l] = lsum;
    }
    __syncthreads();
    if (wk == 0) {
      float m1 = sg[wr * 64 + l];
      float l1 = sg[128 + wr * 64 + l];
      float mt = fmaxf(mrun, m1);
      float r0 = exp2f(mrun - mt), r1 = exp2f(m1 - mt);
      float inv = 1.0f / (lsum * r0 + l1 * r1);
      short* ob =
          outp + (size_t)(b * SEQ + q0 + wr * 32 + lo5) * 2048 + h * HD;
#pragma unroll
      for (int db = 0; db < 4; ++db) {
#pragma unroll
        for (int r4 = 0; r4 < 4; ++r4) {
          int g = db * 4 + r4;
          f32x4 o1 = *(const f32x4*)&og[wr * 4096 + l * 64 +
                                        ((g ^ (l & 15)) * 4)];
          u32x2 pko;
          float v0 = (of[db][r4 * 4 + 0] * r0 + o1[0] * r1) * inv;
          float v1 = (of[db][r4 * 4 + 1] * r0 + o1[1] * r1) * inv;
          float v2 = (of[db][r4 * 4 + 2] * r0 + o1[2] * r1) * inv;
          float v3 = (of[db][r4 * 4 + 3] * r0 + o1[3] * r1) * inv;
          pko.x = cvt_pk(v0, v1);
          pko.y = cvt_pk(v2, v3);
          *(u32x2*)(ob + db * 32 + 8 * r4 + 4 * hi) = pko;
        }
      }
    }
    __syncthreads();
  }
}

extern "C" void kernel_launch(void* const* d_in, const int* in_sizes, int n_in,
                              void* d_out, int out_size, void* d_ws,
                              size_t ws_size, hipStream_t stream) {
  const float* x = (const float*)d_in[0];
  const float* wq = (const float*)d_in[1];
  const float* wk = (const float*)d_in[2];
  const float* wv = (const float*)d_in[3];
  const float* wo = (const float*)d_in[4];
  const float* fc = (const float*)d_in[5];
  const float* fs = (const float*)d_in[6];

  char* ws = (char*)d_ws;
  short* xb = (short*)(ws);                           // [4096][2048] 16MB
  short* wT = (short*)(ws + (16ull << 20));           // [3072][2048] 12MB
  short* woT = (short*)(ws + (28ull << 20));          // [2048][2048] 8MB
  short* qkvb = (short*)(ws + (36ull << 20));         // [4096][3072] 24MB
  short* vtb = (short*)(ws + (16ull << 20));          // alias wT (dead) 4MB
  short* attn = (short*)(ws);                         // alias xb (dead) 16MB

  k_prep<<<6656, 256, 0, stream>>>(x, wq, wk, wv, wo, xb, wT, woT);
  k_gemm256<0><<<192, 512, 0, stream>>>(xb, wT, qkvb, 4096, 3072, 2048);
  k_rv<<<5248, 256, 0, stream>>>(qkvb, fc, fs, vtb);
  k_attn<<<dim3(16, 16, 2), 256, 0, stream>>>(qkvb, vtb, attn);
  k_gemm256<1><<<128, 512, 0, stream>>>(attn, woT, d_out, 4096, 2048, 2048);
}

// Round 10
// 205.268 us; speedup vs baseline: 1.6043x; 1.0381x over previous
//
#include <hip/hip_runtime.h>
#include <stdint.h>

#define SEQ   2048
#define NB    2
#define LDQKV 3072
#define HD    128
// 1/sqrt(128) * log2(e): QK^T scores land in base-2 domain -> exp2 directly.
#define QSCALE2 (0.08838834764831845f * 1.44269504088896340f)

typedef __attribute__((ext_vector_type(8))) short short8;
typedef __attribute__((ext_vector_type(4))) short short4v;
typedef __attribute__((ext_vector_type(4))) float f32x4;
typedef __attribute__((ext_vector_type(16))) float f32x16;
typedef __attribute__((ext_vector_type(4))) unsigned int u32x4;
typedef __attribute__((ext_vector_type(2))) unsigned int u32x2;
typedef __attribute__((ext_vector_type(8))) __bf16 bf16x8;

__device__ __forceinline__ float bs2f(short s) {
  unsigned int u = ((unsigned int)(unsigned short)s) << 16;
  return __builtin_bit_cast(float, u);
}
__device__ __forceinline__ short f2bs(float f) {
  unsigned int u = __builtin_bit_cast(unsigned int, f);
  u += 0x7fffu + ((u >> 16) & 1u);
  return (short)(u >> 16);
}
__device__ __forceinline__ unsigned int cvt_pk(float lo, float hi) {
  unsigned int r;
  asm("v_cvt_pk_bf16_f32 %0, %1, %2" : "=v"(r) : "v"(lo), "v"(hi));
  return r;
}
__device__ __forceinline__ f32x4 mfma16(short8 a, short8 b, f32x4 c) {
  return __builtin_amdgcn_mfma_f32_16x16x32_bf16(
      __builtin_bit_cast(bf16x8, a), __builtin_bit_cast(bf16x8, b), c, 0, 0, 0);
}
__device__ __forceinline__ f32x16 mfma32(short8 a, short8 b, f32x16 c) {
  return __builtin_amdgcn_mfma_f32_32x32x16_bf16(
      __builtin_bit_cast(bf16x8, a), __builtin_bit_cast(bf16x8, b), c, 0, 0, 0);
}
__device__ __forceinline__ void gload_lds16(const void* g, void* l) {
  __builtin_amdgcn_global_load_lds(
      (__attribute__((address_space(1))) const void*)(uintptr_t)g,
      (__attribute__((address_space(3))) void*)(unsigned int)(uintptr_t)l,
      16, 0, 0);
}

#define SBAR() asm volatile("s_barrier" ::: "memory")
#define VMC4() asm volatile("s_waitcnt vmcnt(4)" ::: "memory")
#define VMC0() asm volatile("s_waitcnt vmcnt(0)" ::: "memory")

// ---- fused prep: x fp32->bf16 convert + 4 weight transposes, 1D grid ----
__global__ __launch_bounds__(256) void k_prep(const float* __restrict__ x,
                                              const float* __restrict__ wq,
                                              const float* __restrict__ wk,
                                              const float* __restrict__ wv,
                                              const float* __restrict__ wo,
                                              short* __restrict__ xb,
                                              short* __restrict__ wT,
                                              short* __restrict__ woT) {
  __shared__ __align__(16) float tile[64][68];
  const int bid = blockIdx.x, t = threadIdx.x;
  if (bid < 4096) {  // cvt
    int i = bid * 256 + t;
    f32x4 a = *(const f32x4*)(x + (size_t)i * 8);
    f32x4 b = *(const f32x4*)(x + (size_t)i * 8 + 4);
    short8 o;
#pragma unroll
    for (int j = 0; j < 4; ++j) { o[j] = f2bs(a[j]); o[4 + j] = f2bs(b[j]); }
    *(short8*)(xb + (size_t)i * 8) = o;
    return;
  }
  const float* src;
  short* dst;
  int N, id;
  if (bid < 5120)      { id = bid - 4096; src = wq; dst = wT;                        N = 2048; }
  else if (bid < 5376) { id = bid - 5120; src = wk; dst = wT + (size_t)2048 * 2048;  N = 512;  }
  else if (bid < 5632) { id = bid - 5376; src = wv; dst = wT + (size_t)2560 * 2048;  N = 512;  }
  else                 { id = bid - 5632; src = wo; dst = woT;                       N = 2048; }
  const int K = 2048;
  int k0 = (id & 31) * 64, n0 = (id >> 5) * 64;
#pragma unroll
  for (int rep = 0; rep < 4; ++rep) {
    int lin = rep * 1024 + t * 4;
    int kk = lin >> 6, nn = lin & 63;
    f32x4 v = *(const f32x4*)(src + (size_t)(k0 + kk) * N + n0 + nn);
    *(f32x4*)(&tile[kk][nn]) = v;
  }
  __syncthreads();
#pragma unroll
  for (int rep = 0; rep < 4; ++rep) {
    int lin = rep * 1024 + t * 4;
    int nn = lin >> 6, kk = lin & 63;
    short4v o;
#pragma unroll
    for (int j = 0; j < 4; ++j) o[j] = f2bs(tile[kk + j][nn]);
    *(short4v*)(dst + (size_t)(n0 + nn) * K + k0 + kk) = o;
  }
}

// ------- GEMM 256x256 tile, 4-phase counted-vmcnt schedule ----
// C[M][N] = A[M][K] * Bt[N][K]^T. 512 threads (8 waves, 2M x 4N), BK=64.
// Per phase: {reads; stage; SBAR; MFMA} — 5 barriers/K-tile. Slot ledger:
// stage targets are freed >=1 barrier before (s0<-r3[v-1], s1<-r2[v-1],
// s2<-r0[v], s3<-r1[v]); boundary vmcnt(4)+SBAR forces next tile's slots.
template <int FP32OUT>
__global__ __launch_bounds__(512, 2) void k_gemm256(const short* __restrict__ A,
                                                    const short* __restrict__ Bt,
                                                    void* __restrict__ Cp,
                                                    int M, int N, int K) {
  __shared__ short Al[2][2][128 * 64];
  __shared__ short Bl[2][2][128 * 64];
  const int t = threadIdx.x, l = t & 63, w = t >> 6;
  const int pm = w >> 2, pn = w & 3;
  const int lrow = l & 15, lg = l >> 4;
  const int NT = K >> 6;

  const int nbm = M >> 8;
  const int per = gridDim.x >> 3;
  const int id2 = (blockIdx.x & 7) * per + (blockIdx.x >> 3);
  const int m0 = (id2 % nbm) * 256, n0 = (id2 / nbm) * 256;

  const int srow = w * 8 + (l >> 3);
  const int sgx = ((l & 7) ^ (srow & 7)) * 8;
  const short* Abase = A + (size_t)(m0 + srow) * K + sgx;
  const short* Bbase = Bt + (size_t)(n0 + srow) * K + sgx;

  f32x4 acc[8][4] = {};
  short8 aFr[4][2], bFr[2][2];

  auto stgA = [&](int d, int h, int tv) {
    const short* g = Abase + (size_t)(h * 128) * K + (size_t)tv * 64;
    gload_lds16(g, &Al[d][h][w * 512]);
    gload_lds16(g + (size_t)64 * K, &Al[d][h][w * 512 + 4096]);
  };
  auto stgB = [&](int d, int h, int tv) {
    const short* g = Bbase + (size_t)(h * 128) * K + (size_t)tv * 64;
    gload_lds16(g, &Bl[d][h][w * 512]);
    gload_lds16(g + (size_t)64 * K, &Bl[d][h][w * 512 + 4096]);
  };
  auto rdA = [&](int d, int Mh) {
#pragma unroll
    for (int mi = 0; mi < 4; ++mi) {
      int rl = pm * 64 + mi * 16 + lrow;
#pragma unroll
      for (int kk = 0; kk < 2; ++kk)
        aFr[mi][kk] = *(const short8*)&Al[d][Mh][rl * 64 +
                                                 (((kk * 4 + lg) ^ (rl & 7)) * 8)];
    }
  };
  auto rdB = [&](int d, int Nh) {
#pragma unroll
    for (int ni = 0; ni < 2; ++ni) {
      int rl = pn * 32 + ni * 16 + lrow;
#pragma unroll
      for (int kk = 0; kk < 2; ++kk)
        bFr[ni][kk] = *(const short8*)&Bl[d][Nh][rl * 64 +
                                                 (((kk * 4 + lg) ^ (rl & 7)) * 8)];
    }
  };

#define MMQ(Mh, Nh)                                                          \
  do {                                                                       \
    __builtin_amdgcn_s_setprio(1);                                           \
    _Pragma("unroll") for (int mi = 0; mi < 4; ++mi)                         \
        _Pragma("unroll") for (int ni = 0; ni < 2; ++ni)                     \
            _Pragma("unroll") for (int kk = 0; kk < 2; ++kk)                 \
                acc[(Mh)*4 + mi][(Nh)*2 + ni] =                              \
                    mfma16(aFr[mi][kk], bFr[ni][kk],                         \
                           acc[(Mh)*4 + mi][(Nh)*2 + ni]);                   \
    __builtin_amdgcn_s_setprio(0);                                           \
  } while (0)

  // prologue: tile-0 slots complete; A0(1),B1(1) in flight
  stgA(0, 0, 0); stgB(0, 0, 0); stgB(0, 1, 0); stgA(0, 1, 0);
  stgA(1, 0, 1); stgB(1, 1, 1);
  VMC4();
  SBAR();

  for (int v = 0; v < NT; ++v) {
    const int d = v & 1, d1 = d ^ 1;
    // phase 0: quadrant (0,0); stage B0(v+1)
    rdA(d, 0); rdB(d, 0);
    if (v + 1 < NT) stgB(d1, 0, v + 1);
    SBAR();
    MMQ(0, 0);
    // phase 1: (0,1); stage A1(v+1)
    rdB(d, 1);
    if (v + 1 < NT) stgA(d1, 1, v + 1);
    SBAR();
    MMQ(0, 1);
    // phase 2: (1,1); stage A0(v+2)
    rdA(d, 1);
    if (v + 2 < NT) stgA(d, 0, v + 2);
    SBAR();
    MMQ(1, 1);
    // phase 3: (1,0); stage B1(v+2)
    rdB(d, 0);
    if (v + 2 < NT) stgB(d, 1, v + 2);
    SBAR();
    MMQ(1, 0);
    // K-tile boundary: counted drain (tile v+1 forced complete)
    if (v + 2 < NT) { VMC4(); } else { VMC0(); }
    SBAR();
  }
#undef MMQ

#pragma unroll
  for (int Mh = 0; Mh < 2; ++Mh)
#pragma unroll
    for (int mi = 0; mi < 4; ++mi)
#pragma unroll
      for (int Nh = 0; Nh < 2; ++Nh)
#pragma unroll
        for (int ni = 0; ni < 2; ++ni) {
          int row = m0 + Mh * 128 + pm * 64 + mi * 16 + lg * 4;
          int col = n0 + Nh * 128 + pn * 32 + ni * 16 + lrow;
          f32x4 vv = acc[Mh * 4 + mi][Nh * 2 + ni];
#pragma unroll
          for (int v2 = 0; v2 < 4; ++v2) {
            if constexpr (FP32OUT)
              ((float*)Cp)[(size_t)(row + v2) * N + col] = vv[v2];
            else
              ((short*)Cp)[(size_t)(row + v2) * N + col] = f2bs(vv[v2]);
          }
        }
}

// ---- fused RoPE (q,k in-place; q also *QSCALE2) + V transpose, 1D grid ----
__global__ __launch_bounds__(256) void k_rv(short* __restrict__ qkv,
                                            const float* __restrict__ fcos,
                                            const float* __restrict__ fsin,
                                            short* __restrict__ vt) {
  __shared__ short tile[128 * 137];
  const int bid = blockIdx.x, t = threadIdx.x;
  if (bid < 5120) {  // rope
    int tid = bid * 256 + t;
    int p16 = tid & 15;
    int slice = (tid >> 4) % 20;
    int bs = tid / 320;
    int col = (slice < 16) ? slice * 128 + p16 * 8
                           : 2048 + (slice - 16) * 128 + p16 * 8;
    short8 x = *(short8*)(qkv + (size_t)bs * LDQKV + col);
    f32x4 c = *(const f32x4*)(fcos + (size_t)bs * 64 + p16 * 4);
    f32x4 s = *(const f32x4*)(fsin + (size_t)bs * 64 + p16 * 4);
    float sc = (slice < 16) ? QSCALE2 : 1.0f;
    short8 o;
#pragma unroll
    for (int j = 0; j < 4; ++j) {
      float xr = bs2f(x[2 * j]), xi = bs2f(x[2 * j + 1]);
      o[2 * j] = f2bs((xr * c[j] - xi * s[j]) * sc);
      o[2 * j + 1] = f2bs((xr * s[j] + xi * c[j]) * sc);
    }
    *(short8*)(qkv + (size_t)bs * LDQKV + col) = o;
    return;
  }
  const int id = bid - 5120;
  int s0 = (id & 15) * 128;
  int kvh = (id >> 4) & 3, b = id >> 6;
  const short* src = qkv + (size_t)(b * SEQ) * LDQKV + 2560 + kvh * 128;
#pragma unroll
  for (int rep = 0; rep < 8; ++rep) {
    int lin = rep * 2048 + t * 8;
    int si = lin >> 7, d = lin & 127;
    short8 v = *(const short8*)(src + (size_t)(s0 + si) * LDQKV + d);
#pragma unroll
    for (int j = 0; j < 8; ++j) tile[si * 137 + d + j] = v[j];
  }
  __syncthreads();
  short* dst = vt + (size_t)((b * 4 + kvh) * 128) * SEQ;
#pragma unroll
  for (int rep = 0; rep < 8; ++rep) {
    int lin = rep * 2048 + t * 8;
    int d = lin >> 7, sb = lin & 127;
    short8 o;
#pragma unroll
    for (int j = 0; j < 8; ++j) o[j] = tile[(sb + j) * 137 + d];
    *(short8*)(dst + (size_t)d * SEQ + s0 + sb) = o;
  }
}

// ---------------- flash attention (causal, GQA), 32x32 MFMA ----------------
// K LDS rows = 256B = 16 granules: full 4-bit XOR swizzle (2-way, free).
__global__ __launch_bounds__(256, 2) void k_attn(const short* __restrict__ qkv,
                                                 const short* __restrict__ vt,
                                                 short* __restrict__ outp) {
  __shared__ short Ks[2][64 * 128];
  __shared__ short Vs[2][128 * 64];
  const int t = threadIdx.x, l = t & 63, w = t >> 6;
  const int wr = w >> 1, wk = w & 1;
  const int h = blockIdx.y, b = blockIdx.z;
  const int kvh = h >> 2;
  const int lo5 = l & 31, hi = l >> 5;

  const int kkey = t >> 4, kd8 = t & 15;
  const int vdd = t >> 3, vs8 = t & 7;
  const short* kbase = qkv + (size_t)(b * SEQ) * LDQKV + 2048 + kvh * HD;
  const short* vbase = vt + (size_t)((b * 4 + kvh) * 128) * SEQ;

  auto stageKV = [&](int buf, int it) {
    const int kt = it * 64;
    short* kdst = &Ks[buf][w * 512];
    short* vdst = &Vs[buf][w * 512];
#pragma unroll
    for (int i = 0; i < 4; ++i) {
      int key = i * 16 + kkey;
      int sd = (kd8 ^ (key & 15)) * 8;
      gload_lds16(kbase + (size_t)(kt + key) * LDQKV + sd, kdst + i * 2048);
    }
#pragma unroll
    for (int i = 0; i < 4; ++i) {
      int d = i * 32 + vdd;
      int ss = (vs8 ^ (d & 7)) * 8;
      gload_lds16(vbase + (size_t)d * SEQ + kt + ss, vdst + i * 2048);
    }
  };

  int koff[8], voff[4][2];
#pragma unroll
  for (int s = 0; s < 8; ++s)
    koff[s] = (wk * 32 + lo5) * 128 + (((hi + 2 * s) ^ (l & 15)) * 8);
#pragma unroll
  for (int db = 0; db < 4; ++db)
#pragma unroll
    for (int s = 0; s < 2; ++s)
      voff[db][s] =
          (db * 32 + lo5) * 64 + (((4 * wk + hi + 2 * s) ^ (l & 7)) * 8);
  const int kbloc = wk * 32 + 4 * hi;
  const int qloc = wr * 32 + lo5;

  for (int part = 0; part < 2; ++part) {
    const int qt = part ? (31 - (int)blockIdx.x) : (int)blockIdx.x;
    const int q0 = qt * 64;

    short8 qf[8];
    {
      const short* qrow =
          qkv + (size_t)(b * SEQ + q0 + wr * 32 + lo5) * LDQKV + h * HD;
#pragma unroll
      for (int s = 0; s < 8; ++s)
        qf[s] = *(const short8*)(qrow + s * 16 + hi * 8);
    }

    f32x16 of[4] = {};
    float mrun = 0.f, lsum = 0.f;

    const int nt = qt + 1;
    stageKV(0, 0);
    __syncthreads();

    for (int it = 0; it < nt; ++it) {
      const int buf = it & 1;
      if (it + 1 < nt) stageKV(buf ^ 1, it + 1);
      const short* KsC = Ks[buf];
      const short* VsC = Vs[buf];

      f32x16 sc = {};
      __builtin_amdgcn_s_setprio(1);
#pragma unroll
      for (int s = 0; s < 8; ++s) {
        short8 kf = *(const short8*)(KsC + koff[s]);
        sc = mfma32(kf, qf[s], sc);
      }
      __builtin_amdgcn_s_setprio(0);

      if (it == nt - 1) {
#pragma unroll
        for (int r = 0; r < 16; ++r) {
          const int off = (r & 3) + 8 * (r >> 2);
          if (kbloc + off > qloc) sc[r] = -1e30f;
        }
      }

      float lmax = sc[0];
#pragma unroll
      for (int r = 1; r < 16; ++r) lmax = fmaxf(lmax, sc[r]);
      if (__any(lmax > mrun + 8.f)) {
        float mx = fmaxf(lmax, __shfl_xor(lmax, 32));
        float mm = fmaxf(mrun, mx);
        float rs = exp2f(mrun - mm);
        mrun = mm;
        lsum *= rs;
#pragma unroll
        for (int db = 0; db < 4; ++db)
#pragma unroll
          for (int r = 0; r < 16; ++r) of[db][r] *= rs;
      }

      float p[16];
#pragma unroll
      for (int r = 0; r < 16; ++r) {
        p[r] = exp2f(sc[r] - mrun);
        lsum += p[r];
      }
      unsigned int pk[8];
#pragma unroll
      for (int j = 0; j < 8; ++j) pk[j] = cvt_pk(p[2 * j], p[2 * j + 1]);

      unsigned int s0 = hi ? pk[0] : pk[2];
      unsigned int s1 = hi ? pk[1] : pk[3];
      unsigned int s2 = hi ? pk[4] : pk[6];
      unsigned int s3 = hi ? pk[5] : pk[7];
      unsigned int x0 = __shfl_xor(s0, 32);
      unsigned int x1 = __shfl_xor(s1, 32);
      unsigned int x2 = __shfl_xor(s2, 32);
      unsigned int x3 = __shfl_xor(s3, 32);
      u32x4 b0w, b1w;
      b0w.x = hi ? x0 : pk[0];
      b0w.y = hi ? x1 : pk[1];
      b0w.z = hi ? pk[2] : x0;
      b0w.w = hi ? pk[3] : x1;
      b1w.x = hi ? x2 : pk[4];
      b1w.y = hi ? x3 : pk[5];
      b1w.z = hi ? pk[6] : x2;
      b1w.w = hi ? pk[7] : x3;
      short8 pb[2] = {__builtin_bit_cast(short8, b0w),
                      __builtin_bit_cast(short8, b1w)};

      __builtin_amdgcn_s_setprio(1);
#pragma unroll
      for (int s = 0; s < 2; ++s)
#pragma unroll
        for (int db = 0; db < 4; ++db) {
          short8 vf = *(const short8*)(VsC + voff[db][s]);
          of[db] = mfma32(vf, pb[s], of[db]);
        }
      __builtin_amdgcn_s_setprio(0);
      __syncthreads();
    }

    lsum += __shfl_xor(lsum, 32);
    float* og = (float*)Ks;
    float* sg = (float*)Vs;
    if (wk == 1) {
#pragma unroll
      for (int db = 0; db < 4; ++db)
#pragma unroll
        for (int r4 = 0; r4 < 4; ++r4) {
          int g = db * 4 + r4;
          f32x4 v;
#pragma unroll
          for (int j = 0; j < 4; ++j) v[j] = of[db][r4 * 4 + j];
          *(f32x4*)&og[wr * 4096 + l * 64 + ((g ^ (l & 15)) * 4)] = v;
        }
      sg[wr * 64 + l] = mrun;
      sg[128 + wr * 64 + l] = lsum;
    }
    __syncthreads();
    if (wk == 0) {
      float m1 = sg[wr * 64 + l];
      float l1 = sg[128 + wr * 64 + l];
      float mt = fmaxf(mrun, m1);
      float r0 = exp2f(mrun - mt), r1 = exp2f(m1 - mt);
      float inv = 1.0f / (lsum * r0 + l1 * r1);
      short* ob =
          outp + (size_t)(b * SEQ + q0 + wr * 32 + lo5) * 2048 + h * HD;
#pragma unroll
      for (int db = 0; db < 4; ++db) {
#pragma unroll
        for (int r4 = 0; r4 < 4; ++r4) {
          int g = db * 4 + r4;
          f32x4 o1 = *(const f32x4*)&og[wr * 4096 + l * 64 +
                                        ((g ^ (l & 15)) * 4)];
          u32x2 pko;
          float v0 = (of[db][r4 * 4 + 0] * r0 + o1[0] * r1) * inv;
          float v1 = (of[db][r4 * 4 + 1] * r0 + o1[1] * r1) * inv;
          float v2 = (of[db][r4 * 4 + 2] * r0 + o1[2] * r1) * inv;
          float v3 = (of[db][r4 * 4 + 3] * r0 + o1[3] * r1) * inv;
          pko.x = cvt_pk(v0, v1);
          pko.y = cvt_pk(v2, v3);
          *(u32x2*)(ob + db * 32 + 8 * r4 + 4 * hi) = pko;
        }
      }
    }
    __syncthreads();
  }
}

extern "C" void kernel_launch(void* const* d_in, const int* in_sizes, int n_in,
                              void* d_out, int out_size, void* d_ws,
                              size_t ws_size, hipStream_t stream) {
  const float* x = (const float*)d_in[0];
  const float* wq = (const float*)d_in[1];
  const float* wk = (const float*)d_in[2];
  const float* wv = (const float*)d_in[3];
  const float* wo = (const float*)d_in[4];
  const float* fc = (const float*)d_in[5];
  const float* fs = (const float*)d_in[6];

  char* ws = (char*)d_ws;
  short* xb = (short*)(ws);                           // [4096][2048] 16MB
  short* wT = (short*)(ws + (16ull << 20));           // [3072][2048] 12MB
  short* woT = (short*)(ws + (28ull << 20));          // [2048][2048] 8MB
  short* qkvb = (short*)(ws + (36ull << 20));         // [4096][3072] 24MB
  short* vtb = (short*)(ws + (16ull << 20));          // alias wT (dead) 4MB
  short* attn = (short*)(ws);                         // alias xb (dead) 16MB

  k_prep<<<6656, 256, 0, stream>>>(x, wq, wk, wv, wo, xb, wT, woT);
  k_gemm256<0><<<192, 512, 0, stream>>>(xb, wT, qkvb, 4096, 3072, 2048);
  k_rv<<<5248, 256, 0, stream>>>(qkvb, fc, fs, vtb);
  k_attn<<<dim3(16, 16, 2), 256, 0, stream>>>(qkvb, vtb, attn);
  k_gemm256<1><<<128, 512, 0, stream>>>(attn, woT, d_out, 4096, 2048, 2048);
}

// Round 11
// 189.943 us; speedup vs baseline: 1.7337x; 1.0807x over previous
//
#include <hip/hip_runtime.h>
#include <stdint.h>

#define SEQ   2048
#define NB    2
#define LDQKV 3072
#define HD    128
// 1/sqrt(128) * log2(e): QK^T scores land in base-2 domain -> exp2 directly.
#define QSCALE2 (0.08838834764831845f * 1.44269504088896340f)

typedef __attribute__((ext_vector_type(8))) short short8;
typedef __attribute__((ext_vector_type(4))) short short4v;
typedef __attribute__((ext_vector_type(4))) float f32x4;
typedef __attribute__((ext_vector_type(16))) float f32x16;
typedef __attribute__((ext_vector_type(4))) unsigned int u32x4;
typedef __attribute__((ext_vector_type(2))) unsigned int u32x2;
typedef __attribute__((ext_vector_type(8))) __bf16 bf16x8;

__device__ __forceinline__ float bs2f(short s) {
  unsigned int u = ((unsigned int)(unsigned short)s) << 16;
  return __builtin_bit_cast(float, u);
}
__device__ __forceinline__ short f2bs(float f) {
  unsigned int u = __builtin_bit_cast(unsigned int, f);
  u += 0x7fffu + ((u >> 16) & 1u);
  return (short)(u >> 16);
}
__device__ __forceinline__ unsigned int cvt_pk(float lo, float hi) {
  unsigned int r;
  asm("v_cvt_pk_bf16_f32 %0, %1, %2" : "=v"(r) : "v"(lo), "v"(hi));
  return r;
}
__device__ __forceinline__ f32x4 mfma16(short8 a, short8 b, f32x4 c) {
  return __builtin_amdgcn_mfma_f32_16x16x32_bf16(
      __builtin_bit_cast(bf16x8, a), __builtin_bit_cast(bf16x8, b), c, 0, 0, 0);
}
__device__ __forceinline__ f32x16 mfma32(short8 a, short8 b, f32x16 c) {
  return __builtin_amdgcn_mfma_f32_32x32x16_bf16(
      __builtin_bit_cast(bf16x8, a), __builtin_bit_cast(bf16x8, b), c, 0, 0, 0);
}
__device__ __forceinline__ void gload_lds16(const void* g, void* l) {
  __builtin_amdgcn_global_load_lds(
      (__attribute__((address_space(1))) const void*)(uintptr_t)g,
      (__attribute__((address_space(3))) void*)(unsigned int)(uintptr_t)l,
      16, 0, 0);
}

#define SBAR() asm volatile("s_barrier" ::: "memory")
#define VMC(n) asm volatile("s_waitcnt vmcnt(" #n ")" ::: "memory")

// ---- fused prep: x fp32->bf16 convert + 4 weight transposes, 1D grid ----
__global__ __launch_bounds__(256) void k_prep(const float* __restrict__ x,
                                              const float* __restrict__ wq,
                                              const float* __restrict__ wk,
                                              const float* __restrict__ wv,
                                              const float* __restrict__ wo,
                                              short* __restrict__ xb,
                                              short* __restrict__ wT,
                                              short* __restrict__ woT) {
  __shared__ __align__(16) float tile[64][68];
  const int bid = blockIdx.x, t = threadIdx.x;
  if (bid < 4096) {  // cvt
    int i = bid * 256 + t;
    f32x4 a = *(const f32x4*)(x + (size_t)i * 8);
    f32x4 b = *(const f32x4*)(x + (size_t)i * 8 + 4);
    short8 o;
#pragma unroll
    for (int j = 0; j < 4; ++j) { o[j] = f2bs(a[j]); o[4 + j] = f2bs(b[j]); }
    *(short8*)(xb + (size_t)i * 8) = o;
    return;
  }
  const float* src;
  short* dst;
  int N, id;
  if (bid < 5120)      { id = bid - 4096; src = wq; dst = wT;                        N = 2048; }
  else if (bid < 5376) { id = bid - 5120; src = wk; dst = wT + (size_t)2048 * 2048;  N = 512;  }
  else if (bid < 5632) { id = bid - 5376; src = wv; dst = wT + (size_t)2560 * 2048;  N = 512;  }
  else                 { id = bid - 5632; src = wo; dst = woT;                       N = 2048; }
  const int K = 2048;
  int k0 = (id & 31) * 64, n0 = (id >> 5) * 64;
#pragma unroll
  for (int rep = 0; rep < 4; ++rep) {
    int lin = rep * 1024 + t * 4;
    int kk = lin >> 6, nn = lin & 63;
    f32x4 v = *(const f32x4*)(src + (size_t)(k0 + kk) * N + n0 + nn);
    *(f32x4*)(&tile[kk][nn]) = v;
  }
  __syncthreads();
#pragma unroll
  for (int rep = 0; rep < 4; ++rep) {
    int lin = rep * 1024 + t * 4;
    int nn = lin >> 6, kk = lin & 63;
    short4v o;
#pragma unroll
    for (int j = 0; j < 4; ++j) o[j] = f2bs(tile[kk + j][nn]);
    *(short4v*)(dst + (size_t)(n0 + nn) * K + k0 + kk) = o;
  }
}

// ------- GEMM 256x(NH*128) tile, 2-barrier/K-tile read-ahead schedule ----
// C[M][N] = A[M][K] * Bt[N][K]^T. 512 threads (8 waves, 2M x 4N), BK=64.
// Per K-tile: {read all frags (aFr0,bFr,aFr1); early stages (d1, v+1);
// MFMA Mh=0; SBAR; late stages (d, v+2); MFMA Mh=1; counted vmcnt; SBAR}.
// Boundary vmcnt completes late(v-1)+early(v) = all of tile v+1 exactly.
template <int NH, int FP32OUT>
__global__ __launch_bounds__(512, 2) void k_gemm256(const short* __restrict__ A,
                                                    const short* __restrict__ Bt,
                                                    void* __restrict__ Cp,
                                                    int M, int N, int K) {
  __shared__ short Al[2][2][128 * 64];
  __shared__ short Bl[2][NH][128 * 64];
  const int t = threadIdx.x, l = t & 63, w = t >> 6;
  const int pm = w >> 2, pn = w & 3;
  const int lrow = l & 15, lg = l >> 4;
  const int NT = K >> 6;

  const int nbm = M >> 8;
  const int per = gridDim.x >> 3;
  const int id2 = (blockIdx.x & 7) * per + (blockIdx.x >> 3);
  const int m0 = (id2 % nbm) * 256, n0 = (id2 / nbm) * (NH * 128);

  const int srow = w * 8 + (l >> 3);
  const int sgx = ((l & 7) ^ (srow & 7)) * 8;
  const short* Abase = A + (size_t)(m0 + srow) * K + sgx;
  const short* Bbase = Bt + (size_t)(n0 + srow) * K + sgx;

  f32x4 acc[8][NH * 2] = {};
  short8 aFr0[4][2], aFr1[4][2], bFr[NH][2][2];

  auto stgA = [&](int d, int h, int tv) {
    const short* g = Abase + (size_t)(h * 128) * K + (size_t)tv * 64;
    gload_lds16(g, &Al[d][h][w * 512]);
    gload_lds16(g + (size_t)64 * K, &Al[d][h][w * 512 + 4096]);
  };
  auto stgB = [&](int d, int h, int tv) {
    const short* g = Bbase + (size_t)(h * 128) * K + (size_t)tv * 64;
    gload_lds16(g, &Bl[d][h][w * 512]);
    gload_lds16(g + (size_t)64 * K, &Bl[d][h][w * 512 + 4096]);
  };
  auto rdA = [&](int d, int Mh, short8 (*dst)[2]) {
#pragma unroll
    for (int mi = 0; mi < 4; ++mi) {
      int rl = pm * 64 + mi * 16 + lrow;
#pragma unroll
      for (int kk = 0; kk < 2; ++kk)
        dst[mi][kk] = *(const short8*)&Al[d][Mh][rl * 64 +
                                                 (((kk * 4 + lg) ^ (rl & 7)) * 8)];
    }
  };
  auto rdB = [&](int d) {
#pragma unroll
    for (int h = 0; h < NH; ++h)
#pragma unroll
      for (int ni = 0; ni < 2; ++ni) {
        int rl = pn * 32 + ni * 16 + lrow;
#pragma unroll
        for (int kk = 0; kk < 2; ++kk)
          bFr[h][ni][kk] =
              *(const short8*)&Bl[d][h][rl * 64 +
                                        (((kk * 4 + lg) ^ (rl & 7)) * 8)];
      }
  };

#define MMH(Mh, FR)                                                          \
  do {                                                                       \
    __builtin_amdgcn_s_setprio(1);                                           \
    _Pragma("unroll") for (int h = 0; h < NH; ++h)                           \
        _Pragma("unroll") for (int mi = 0; mi < 4; ++mi)                     \
            _Pragma("unroll") for (int ni = 0; ni < 2; ++ni)                 \
                _Pragma("unroll") for (int kk = 0; kk < 2; ++kk)             \
                    acc[(Mh)*4 + mi][h * 2 + ni] =                           \
                        mfma16(FR[mi][kk], bFr[h][ni][kk],                   \
                               acc[(Mh)*4 + mi][h * 2 + ni]);                \
    __builtin_amdgcn_s_setprio(0);                                           \
  } while (0)

  // prologue: tile-0 fully staged; late-slots for tile 1 in flight
  stgA(0, 0, 0);
  for (int h = 0; h < NH; ++h) stgB(0, h, 0);
  stgA(0, 1, 0);
  stgA(1, 0, 1);
  if (NH == 2) stgB(1, 1, 1);
  if (NH == 2) { VMC(4); } else { VMC(2); }
  SBAR();

  for (int v = 0; v < NT; ++v) {
    const int d = v & 1, d1 = d ^ 1;
    // read everything for this tile (resident since boundary)
    rdA(d, 0, aFr0);
    rdB(d);
    rdA(d, 1, aFr1);
    // early stages: d1 slots (for v+1) — not touched this tile
    if (v + 1 < NT) { stgB(d1, 0, v + 1); stgA(d1, 1, v + 1); }
    MMH(0, aFr0);
    SBAR();  // all waves' reads done -> d slots may be overwritten
    // late stages: d slots (for v+2)
    if (v + 2 < NT) {
      stgA(d, 0, v + 2);
      if (NH == 2) stgB(d, 1, v + 2);
    }
    MMH(1, aFr1);
    // boundary: counted drain (forces all of tile v+1 resident)
    if (v + 2 < NT) {
      if (NH == 2) { VMC(4); } else { VMC(2); }
    } else {
      VMC(0);
    }
    SBAR();
  }
#undef MMH

#pragma unroll
  for (int Mh = 0; Mh < 2; ++Mh)
#pragma unroll
    for (int mi = 0; mi < 4; ++mi)
#pragma unroll
      for (int h = 0; h < NH; ++h)
#pragma unroll
        for (int ni = 0; ni < 2; ++ni) {
          int row = m0 + Mh * 128 + pm * 64 + mi * 16 + lg * 4;
          int col = n0 + h * 128 + pn * 32 + ni * 16 + lrow;
          f32x4 vv = acc[Mh * 4 + mi][h * 2 + ni];
#pragma unroll
          for (int v2 = 0; v2 < 4; ++v2) {
            if constexpr (FP32OUT)
              ((float*)Cp)[(size_t)(row + v2) * N + col] = vv[v2];
            else
              ((short*)Cp)[(size_t)(row + v2) * N + col] = f2bs(vv[v2]);
          }
        }
}

// ---- fused RoPE (q,k in-place; q also *QSCALE2) + V transpose, 1D grid ----
__global__ __launch_bounds__(256) void k_rv(short* __restrict__ qkv,
                                            const float* __restrict__ fcos,
                                            const float* __restrict__ fsin,
                                            short* __restrict__ vt) {
  __shared__ short tile[128 * 137];
  const int bid = blockIdx.x, t = threadIdx.x;
  if (bid < 5120) {  // rope
    int tid = bid * 256 + t;
    int p16 = tid & 15;
    int slice = (tid >> 4) % 20;
    int bs = tid / 320;
    int col = (slice < 16) ? slice * 128 + p16 * 8
                           : 2048 + (slice - 16) * 128 + p16 * 8;
    short8 x = *(short8*)(qkv + (size_t)bs * LDQKV + col);
    f32x4 c = *(const f32x4*)(fcos + (size_t)bs * 64 + p16 * 4);
    f32x4 s = *(const f32x4*)(fsin + (size_t)bs * 64 + p16 * 4);
    float sc = (slice < 16) ? QSCALE2 : 1.0f;
    short8 o;
#pragma unroll
    for (int j = 0; j < 4; ++j) {
      float xr = bs2f(x[2 * j]), xi = bs2f(x[2 * j + 1]);
      o[2 * j] = f2bs((xr * c[j] - xi * s[j]) * sc);
      o[2 * j + 1] = f2bs((xr * s[j] + xi * c[j]) * sc);
    }
    *(short8*)(qkv + (size_t)bs * LDQKV + col) = o;
    return;
  }
  const int id = bid - 5120;
  int s0 = (id & 15) * 128;
  int kvh = (id >> 4) & 3, b = id >> 6;
  const short* src = qkv + (size_t)(b * SEQ) * LDQKV + 2560 + kvh * 128;
#pragma unroll
  for (int rep = 0; rep < 8; ++rep) {
    int lin = rep * 2048 + t * 8;
    int si = lin >> 7, d = lin & 127;
    short8 v = *(const short8*)(src + (size_t)(s0 + si) * LDQKV + d);
#pragma unroll
    for (int j = 0; j < 8; ++j) tile[si * 137 + d + j] = v[j];
  }
  __syncthreads();
  short* dst = vt + (size_t)((b * 4 + kvh) * 128) * SEQ;
#pragma unroll
  for (int rep = 0; rep < 8; ++rep) {
    int lin = rep * 2048 + t * 8;
    int d = lin >> 7, sb = lin & 127;
    short8 o;
#pragma unroll
    for (int j = 0; j < 8; ++j) o[j] = tile[(sb + j) * 137 + d];
    *(short8*)(dst + (size_t)d * SEQ + s0 + sb) = o;
  }
}

// ---------------- flash attention (causal, GQA), 32x32 MFMA ----------------
// K LDS rows = 256B = 16 granules: full 4-bit XOR swizzle (2-way, free).
__global__ __launch_bounds__(256, 2) void k_attn(const short* __restrict__ qkv,
                                                 const short* __restrict__ vt,
                                                 short* __restrict__ outp) {
  __shared__ short Ks[2][64 * 128];
  __shared__ short Vs[2][128 * 64];
  const int t = threadIdx.x, l = t & 63, w = t >> 6;
  const int wr = w >> 1, wk = w & 1;
  const int h = blockIdx.y, b = blockIdx.z;
  const int kvh = h >> 2;
  const int lo5 = l & 31, hi = l >> 5;

  const int kkey = t >> 4, kd8 = t & 15;
  const int vdd = t >> 3, vs8 = t & 7;
  const short* kbase = qkv + (size_t)(b * SEQ) * LDQKV + 2048 + kvh * HD;
  const short* vbase = vt + (size_t)((b * 4 + kvh) * 128) * SEQ;

  auto stageKV = [&](int buf, int it) {
    const int kt = it * 64;
    short* kdst = &Ks[buf][w * 512];
    short* vdst = &Vs[buf][w * 512];
#pragma unroll
    for (int i = 0; i < 4; ++i) {
      int key = i * 16 + kkey;
      int sd = (kd8 ^ (key & 15)) * 8;
      gload_lds16(kbase + (size_t)(kt + key) * LDQKV + sd, kdst + i * 2048);
    }
#pragma unroll
    for (int i = 0; i < 4; ++i) {
      int d = i * 32 + vdd;
      int ss = (vs8 ^ (d & 7)) * 8;
      gload_lds16(vbase + (size_t)d * SEQ + kt + ss, vdst + i * 2048);
    }
  };

  int koff[8], voff[4][2];
#pragma unroll
  for (int s = 0; s < 8; ++s)
    koff[s] = (wk * 32 + lo5) * 128 + (((hi + 2 * s) ^ (l & 15)) * 8);
#pragma unroll
  for (int db = 0; db < 4; ++db)
#pragma unroll
    for (int s = 0; s < 2; ++s)
      voff[db][s] =
          (db * 32 + lo5) * 64 + (((4 * wk + hi + 2 * s) ^ (l & 7)) * 8);
  const int kbloc = wk * 32 + 4 * hi;
  const int qloc = wr * 32 + lo5;

  for (int part = 0; part < 2; ++part) {
    const int qt = part ? (31 - (int)blockIdx.x) : (int)blockIdx.x;
    const int q0 = qt * 64;

    short8 qf[8];
    {
      const short* qrow =
          qkv + (size_t)(b * SEQ + q0 + wr * 32 + lo5) * LDQKV + h * HD;
#pragma unroll
      for (int s = 0; s < 8; ++s)
        qf[s] = *(const short8*)(qrow + s * 16 + hi * 8);
    }

    f32x16 of[4] = {};
    float mrun = 0.f, lsum = 0.f;

    const int nt = qt + 1;
    stageKV(0, 0);
    __syncthreads();

    for (int it = 0; it < nt; ++it) {
      const int buf = it & 1;
      if (it + 1 < nt) stageKV(buf ^ 1, it + 1);
      const short* KsC = Ks[buf];
      const short* VsC = Vs[buf];

      f32x16 sc = {};
      __builtin_amdgcn_s_setprio(1);
#pragma unroll
      for (int s = 0; s < 8; ++s) {
        short8 kf = *(const short8*)(KsC + koff[s]);
        sc = mfma32(kf, qf[s], sc);
      }
      __builtin_amdgcn_s_setprio(0);

      if (it == nt - 1) {
#pragma unroll
        for (int r = 0; r < 16; ++r) {
          const int off = (r & 3) + 8 * (r >> 2);
          if (kbloc + off > qloc) sc[r] = -1e30f;
        }
      }

      float lmax = sc[0];
#pragma unroll
      for (int r = 1; r < 16; ++r) lmax = fmaxf(lmax, sc[r]);
      if (__any(lmax > mrun + 8.f)) {
        float mx = fmaxf(lmax, __shfl_xor(lmax, 32));
        float mm = fmaxf(mrun, mx);
        float rs = exp2f(mrun - mm);
        mrun = mm;
        lsum *= rs;
#pragma unroll
        for (int db = 0; db < 4; ++db)
#pragma unroll
          for (int r = 0; r < 16; ++r) of[db][r] *= rs;
      }

      float p[16];
#pragma unroll
      for (int r = 0; r < 16; ++r) {
        p[r] = exp2f(sc[r] - mrun);
        lsum += p[r];
      }
      unsigned int pk[8];
#pragma unroll
      for (int j = 0; j < 8; ++j) pk[j] = cvt_pk(p[2 * j], p[2 * j + 1]);

      unsigned int s0 = hi ? pk[0] : pk[2];
      unsigned int s1 = hi ? pk[1] : pk[3];
      unsigned int s2 = hi ? pk[4] : pk[6];
      unsigned int s3 = hi ? pk[5] : pk[7];
      unsigned int x0 = __shfl_xor(s0, 32);
      unsigned int x1 = __shfl_xor(s1, 32);
      unsigned int x2 = __shfl_xor(s2, 32);
      unsigned int x3 = __shfl_xor(s3, 32);
      u32x4 b0w, b1w;
      b0w.x = hi ? x0 : pk[0];
      b0w.y = hi ? x1 : pk[1];
      b0w.z = hi ? pk[2] : x0;
      b0w.w = hi ? pk[3] : x1;
      b1w.x = hi ? x2 : pk[4];
      b1w.y = hi ? x3 : pk[5];
      b1w.z = hi ? pk[6] : x2;
      b1w.w = hi ? pk[7] : x3;
      short8 pb[2] = {__builtin_bit_cast(short8, b0w),
                      __builtin_bit_cast(short8, b1w)};

      __builtin_amdgcn_s_setprio(1);
#pragma unroll
      for (int s = 0; s < 2; ++s)
#pragma unroll
        for (int db = 0; db < 4; ++db) {
          short8 vf = *(const short8*)(VsC + voff[db][s]);
          of[db] = mfma32(vf, pb[s], of[db]);
        }
      __builtin_amdgcn_s_setprio(0);
      __syncthreads();
    }

    lsum += __shfl_xor(lsum, 32);
    float* og = (float*)Ks;
    float* sg = (float*)Vs;
    if (wk == 1) {
#pragma unroll
      for (int db = 0; db < 4; ++db)
#pragma unroll
        for (int r4 = 0; r4 < 4; ++r4) {
          int g = db * 4 + r4;
          f32x4 v;
#pragma unroll
          for (int j = 0; j < 4; ++j) v[j] = of[db][r4 * 4 + j];
          *(f32x4*)&og[wr * 4096 + l * 64 + ((g ^ (l & 15)) * 4)] = v;
        }
      sg[wr * 64 + l] = mrun;
      sg[128 + wr * 64 + l] = lsum;
    }
    __syncthreads();
    if (wk == 0) {
      float m1 = sg[wr * 64 + l];
      float l1 = sg[128 + wr * 64 + l];
      float mt = fmaxf(mrun, m1);
      float r0 = exp2f(mrun - mt), r1 = exp2f(m1 - mt);
      float inv = 1.0f / (lsum * r0 + l1 * r1);
      short* ob =
          outp + (size_t)(b * SEQ + q0 + wr * 32 + lo5) * 2048 + h * HD;
#pragma unroll
      for (int db = 0; db < 4; ++db) {
#pragma unroll
        for (int r4 = 0; r4 < 4; ++r4) {
          int g = db * 4 + r4;
          f32x4 o1 = *(const f32x4*)&og[wr * 4096 + l * 64 +
                                        ((g ^ (l & 15)) * 4)];
          u32x2 pko;
          float v0 = (of[db][r4 * 4 + 0] * r0 + o1[0] * r1) * inv;
          float v1 = (of[db][r4 * 4 + 1] * r0 + o1[1] * r1) * inv;
          float v2 = (of[db][r4 * 4 + 2] * r0 + o1[2] * r1) * inv;
          float v3 = (of[db][r4 * 4 + 3] * r0 + o1[3] * r1) * inv;
          pko.x = cvt_pk(v0, v1);
          pko.y = cvt_pk(v2, v3);
          *(u32x2*)(ob + db * 32 + 8 * r4 + 4 * hi) = pko;
        }
      }
    }
    __syncthreads();
  }
}

extern "C" void kernel_launch(void* const* d_in, const int* in_sizes, int n_in,
                              void* d_out, int out_size, void* d_ws,
                              size_t ws_size, hipStream_t stream) {
  const float* x = (const float*)d_in[0];
  const float* wq = (const float*)d_in[1];
  const float* wk = (const float*)d_in[2];
  const float* wv = (const float*)d_in[3];
  const float* wo = (const float*)d_in[4];
  const float* fc = (const float*)d_in[5];
  const float* fs = (const float*)d_in[6];

  char* ws = (char*)d_ws;
  short* xb = (short*)(ws);                           // [4096][2048] 16MB
  short* wT = (short*)(ws + (16ull << 20));           // [3072][2048] 12MB
  short* woT = (short*)(ws + (28ull << 20));          // [2048][2048] 8MB
  short* qkvb = (short*)(ws + (36ull << 20));         // [4096][3072] 24MB
  short* vtb = (short*)(ws + (16ull << 20));          // alias wT (dead) 4MB
  short* attn = (short*)(ws);                         // alias xb (dead) 16MB

  k_prep<<<6656, 256, 0, stream>>>(x, wq, wk, wv, wo, xb, wT, woT);
  k_gemm256<2, 0><<<192, 512, 0, stream>>>(xb, wT, qkvb, 4096, 3072, 2048);
  k_rv<<<5248, 256, 0, stream>>>(qkvb, fc, fs, vtb);
  k_attn<<<dim3(16, 16, 2), 256, 0, stream>>>(qkvb, vtb, attn);
  k_gemm256<1, 1><<<256, 512, 0, stream>>>(attn, woT, d_out, 4096, 2048, 2048);
}

// Round 12
// 183.053 us; speedup vs baseline: 1.7990x; 1.0376x over previous
//
#include <hip/hip_runtime.h>
#include <stdint.h>

#define SEQ   2048
#define NB    2
#define LDQKV 3072
#define HD    128
// 1/sqrt(128) * log2(e): QK^T scores land in base-2 domain -> exp2 directly.
#define QSCALE2 (0.08838834764831845f * 1.44269504088896340f)

typedef __attribute__((ext_vector_type(8))) short short8;
typedef __attribute__((ext_vector_type(4))) short short4v;
typedef __attribute__((ext_vector_type(4))) float f32x4;
typedef __attribute__((ext_vector_type(16))) float f32x16;
typedef __attribute__((ext_vector_type(4))) unsigned int u32x4;
typedef __attribute__((ext_vector_type(2))) unsigned int u32x2;
typedef __attribute__((ext_vector_type(8))) __bf16 bf16x8;

__device__ __forceinline__ float bs2f(short s) {
  unsigned int u = ((unsigned int)(unsigned short)s) << 16;
  return __builtin_bit_cast(float, u);
}
__device__ __forceinline__ short f2bs(float f) {
  unsigned int u = __builtin_bit_cast(unsigned int, f);
  u += 0x7fffu + ((u >> 16) & 1u);
  return (short)(u >> 16);
}
__device__ __forceinline__ unsigned int cvt_pk(float lo, float hi) {
  unsigned int r;
  asm("v_cvt_pk_bf16_f32 %0, %1, %2" : "=v"(r) : "v"(lo), "v"(hi));
  return r;
}
// bare v_exp_f32 (2^x): avoids ocml exp2f edge-handling (~15 VALU each)
__device__ __forceinline__ float fexp2(float x) {
  float r;
  asm("v_exp_f32 %0, %1" : "=v"(r) : "v"(x));
  return r;
}
__device__ __forceinline__ f32x4 mfma16(short8 a, short8 b, f32x4 c) {
  return __builtin_amdgcn_mfma_f32_16x16x32_bf16(
      __builtin_bit_cast(bf16x8, a), __builtin_bit_cast(bf16x8, b), c, 0, 0, 0);
}
__device__ __forceinline__ f32x16 mfma32(short8 a, short8 b, f32x16 c) {
  return __builtin_amdgcn_mfma_f32_32x32x16_bf16(
      __builtin_bit_cast(bf16x8, a), __builtin_bit_cast(bf16x8, b), c, 0, 0, 0);
}
__device__ __forceinline__ void gload_lds16(const void* g, void* l) {
  __builtin_amdgcn_global_load_lds(
      (__attribute__((address_space(1))) const void*)(uintptr_t)g,
      (__attribute__((address_space(3))) void*)(unsigned int)(uintptr_t)l,
      16, 0, 0);
}

#define SBAR() asm volatile("s_barrier" ::: "memory")
#define VMC(n) asm volatile("s_waitcnt vmcnt(" #n ")" ::: "memory")

// ---- fused prep: x fp32->bf16 convert + 4 weight transposes, 1D grid ----
__global__ __launch_bounds__(256) void k_prep(const float* __restrict__ x,
                                              const float* __restrict__ wq,
                                              const float* __restrict__ wk,
                                              const float* __restrict__ wv,
                                              const float* __restrict__ wo,
                                              short* __restrict__ xb,
                                              short* __restrict__ wT,
                                              short* __restrict__ woT) {
  __shared__ __align__(16) float tile[64][68];
  const int bid = blockIdx.x, t = threadIdx.x;
  if (bid < 4096) {  // cvt
    int i = bid * 256 + t;
    f32x4 a = *(const f32x4*)(x + (size_t)i * 8);
    f32x4 b = *(const f32x4*)(x + (size_t)i * 8 + 4);
    short8 o;
#pragma unroll
    for (int j = 0; j < 4; ++j) { o[j] = f2bs(a[j]); o[4 + j] = f2bs(b[j]); }
    *(short8*)(xb + (size_t)i * 8) = o;
    return;
  }
  const float* src;
  short* dst;
  int N, id;
  if (bid < 5120)      { id = bid - 4096; src = wq; dst = wT;                        N = 2048; }
  else if (bid < 5376) { id = bid - 5120; src = wk; dst = wT + (size_t)2048 * 2048;  N = 512;  }
  else if (bid < 5632) { id = bid - 5376; src = wv; dst = wT + (size_t)2560 * 2048;  N = 512;  }
  else                 { id = bid - 5632; src = wo; dst = woT;                       N = 2048; }
  const int K = 2048;
  int k0 = (id & 31) * 64, n0 = (id >> 5) * 64;
#pragma unroll
  for (int rep = 0; rep < 4; ++rep) {
    int lin = rep * 1024 + t * 4;
    int kk = lin >> 6, nn = lin & 63;
    f32x4 v = *(const f32x4*)(src + (size_t)(k0 + kk) * N + n0 + nn);
    *(f32x4*)(&tile[kk][nn]) = v;
  }
  __syncthreads();
#pragma unroll
  for (int rep = 0; rep < 4; ++rep) {
    int lin = rep * 1024 + t * 4;
    int nn = lin >> 6, kk = lin & 63;
    short4v o;
#pragma unroll
    for (int j = 0; j < 4; ++j) o[j] = f2bs(tile[kk + j][nn]);
    *(short4v*)(dst + (size_t)(n0 + nn) * K + k0 + kk) = o;
  }
}

// ------- GEMM 256x(NH*128) tile, 2-barrier/K-tile read-ahead schedule ----
// ROPE: apply RoPE (+q scale) to the fp32 acc in the epilogue (QKV GEMM).
// Pair col^1 lives in lane l^1 -> one shfl_xor; cos/sin L2-hot (2MB).
template <int NH, int FP32OUT, int ROPE>
__global__ __launch_bounds__(512, 2) void k_gemm256(const short* __restrict__ A,
                                                    const short* __restrict__ Bt,
                                                    void* __restrict__ Cp,
                                                    const float* __restrict__ fcos,
                                                    const float* __restrict__ fsin,
                                                    int M, int N, int K) {
  __shared__ short Al[2][2][128 * 64];
  __shared__ short Bl[2][NH][128 * 64];
  const int t = threadIdx.x, l = t & 63, w = t >> 6;
  const int pm = w >> 2, pn = w & 3;
  const int lrow = l & 15, lg = l >> 4;
  const int NT = K >> 6;

  const int nbm = M >> 8;
  const int per = gridDim.x >> 3;
  const int id2 = (blockIdx.x & 7) * per + (blockIdx.x >> 3);
  const int m0 = (id2 % nbm) * 256, n0 = (id2 / nbm) * (NH * 128);

  const int srow = w * 8 + (l >> 3);
  const int sgx = ((l & 7) ^ (srow & 7)) * 8;
  const short* Abase = A + (size_t)(m0 + srow) * K + sgx;
  const short* Bbase = Bt + (size_t)(n0 + srow) * K + sgx;

  f32x4 acc[8][NH * 2] = {};
  short8 aFr0[4][2], aFr1[4][2], bFr[NH][2][2];

  auto stgA = [&](int d, int h, int tv) {
    const short* g = Abase + (size_t)(h * 128) * K + (size_t)tv * 64;
    gload_lds16(g, &Al[d][h][w * 512]);
    gload_lds16(g + (size_t)64 * K, &Al[d][h][w * 512 + 4096]);
  };
  auto stgB = [&](int d, int h, int tv) {
    const short* g = Bbase + (size_t)(h * 128) * K + (size_t)tv * 64;
    gload_lds16(g, &Bl[d][h][w * 512]);
    gload_lds16(g + (size_t)64 * K, &Bl[d][h][w * 512 + 4096]);
  };
  auto rdA = [&](int d, int Mh, short8 (*dst)[2]) {
#pragma unroll
    for (int mi = 0; mi < 4; ++mi) {
      int rl = pm * 64 + mi * 16 + lrow;
#pragma unroll
      for (int kk = 0; kk < 2; ++kk)
        dst[mi][kk] = *(const short8*)&Al[d][Mh][rl * 64 +
                                                 (((kk * 4 + lg) ^ (rl & 7)) * 8)];
    }
  };
  auto rdB = [&](int d) {
#pragma unroll
    for (int h = 0; h < NH; ++h)
#pragma unroll
      for (int ni = 0; ni < 2; ++ni) {
        int rl = pn * 32 + ni * 16 + lrow;
#pragma unroll
        for (int kk = 0; kk < 2; ++kk)
          bFr[h][ni][kk] =
              *(const short8*)&Bl[d][h][rl * 64 +
                                        (((kk * 4 + lg) ^ (rl & 7)) * 8)];
      }
  };

#define MMH(Mh, FR)                                                          \
  do {                                                                       \
    __builtin_amdgcn_s_setprio(1);                                           \
    _Pragma("unroll") for (int h = 0; h < NH; ++h)                           \
        _Pragma("unroll") for (int mi = 0; mi < 4; ++mi)                     \
            _Pragma("unroll") for (int ni = 0; ni < 2; ++ni)                 \
                _Pragma("unroll") for (int kk = 0; kk < 2; ++kk)             \
                    acc[(Mh)*4 + mi][h * 2 + ni] =                           \
                        mfma16(FR[mi][kk], bFr[h][ni][kk],                   \
                               acc[(Mh)*4 + mi][h * 2 + ni]);                \
    __builtin_amdgcn_s_setprio(0);                                           \
  } while (0)

  // prologue: tile-0 fully staged; late-slots for tile 1 in flight
  stgA(0, 0, 0);
  for (int h = 0; h < NH; ++h) stgB(0, h, 0);
  stgA(0, 1, 0);
  stgA(1, 0, 1);
  if (NH == 2) stgB(1, 1, 1);
  if (NH == 2) { VMC(4); } else { VMC(2); }
  SBAR();

  for (int v = 0; v < NT; ++v) {
    const int d = v & 1, d1 = d ^ 1;
    rdA(d, 0, aFr0);
    rdB(d);
    rdA(d, 1, aFr1);
    if (v + 1 < NT) { stgB(d1, 0, v + 1); stgA(d1, 1, v + 1); }
    MMH(0, aFr0);
    SBAR();  // all waves' reads done -> d slots may be overwritten
    if (v + 2 < NT) {
      stgA(d, 0, v + 2);
      if (NH == 2) stgB(d, 1, v + 2);
    }
    MMH(1, aFr1);
    if (v + 2 < NT) {
      if (NH == 2) { VMC(4); } else { VMC(2); }
    } else {
      VMC(0);
    }
    SBAR();
  }
#undef MMH

#pragma unroll
  for (int Mh = 0; Mh < 2; ++Mh)
#pragma unroll
    for (int mi = 0; mi < 4; ++mi)
#pragma unroll
      for (int h = 0; h < NH; ++h)
#pragma unroll
        for (int ni = 0; ni < 2; ++ni) {
          int row = m0 + Mh * 128 + pm * 64 + mi * 16 + lg * 4;
          int col = n0 + h * 128 + pn * 32 + ni * 16 + lrow;
          f32x4 vv = acc[Mh * 4 + mi][h * 2 + ni];
          if constexpr (ROPE) {
            if (col < 2560) {  // q,k regions (uniform per store: 16-aligned)
              const float qs = (col < 2048) ? QSCALE2 : 1.0f;
              const int p = (col & 127) >> 1;
              const bool ev = ((lrow & 1) == 0);
#pragma unroll
              for (int v2 = 0; v2 < 4; ++v2) {
                float c = fcos[(size_t)(row + v2) * 64 + p] * qs;
                float s = fsin[(size_t)(row + v2) * 64 + p] * qs;
                float xx = vv[v2];
                float xp = __shfl_xor(xx, 1);
                vv[v2] = ev ? (xx * c - xp * s) : (xp * s + xx * c);
              }
            }
          }
#pragma unroll
          for (int v2 = 0; v2 < 4; ++v2) {
            if constexpr (FP32OUT)
              ((float*)Cp)[(size_t)(row + v2) * N + col] = vv[v2];
            else
              ((short*)Cp)[(size_t)(row + v2) * N + col] = f2bs(vv[v2]);
          }
        }
}

// ---- V transpose only (rope now fused into QKV GEMM epilogue) ----
__global__ __launch_bounds__(256) void k_vt(const short* __restrict__ qkv,
                                            short* __restrict__ vt) {
  __shared__ short tile[128 * 137];
  const int id = blockIdx.x, t = threadIdx.x;
  int s0 = (id & 15) * 128;
  int kvh = (id >> 4) & 3, b = id >> 6;
  const short* src = qkv + (size_t)(b * SEQ) * LDQKV + 2560 + kvh * 128;
#pragma unroll
  for (int rep = 0; rep < 8; ++rep) {
    int lin = rep * 2048 + t * 8;
    int si = lin >> 7, d = lin & 127;
    short8 v = *(const short8*)(src + (size_t)(s0 + si) * LDQKV + d);
#pragma unroll
    for (int j = 0; j < 8; ++j) tile[si * 137 + d + j] = v[j];
  }
  __syncthreads();
  short* dst = vt + (size_t)((b * 4 + kvh) * 128) * SEQ;
#pragma unroll
  for (int rep = 0; rep < 8; ++rep) {
    int lin = rep * 2048 + t * 8;
    int d = lin >> 7, sb = lin & 127;
    short8 o;
#pragma unroll
    for (int j = 0; j < 8; ++j) o[j] = tile[(sb + j) * 137 + d];
    *(short8*)(dst + (size_t)d * SEQ + s0 + sb) = o;
  }
}

// ---------------- flash attention (causal, GQA), 32x32 MFMA ----------------
// K LDS rows = 256B = 16 granules: full 4-bit XOR swizzle (2-way, free).
// QK^T uses 2 accumulator chains; exp2 via bare v_exp_f32.
__global__ __launch_bounds__(256, 2) void k_attn(const short* __restrict__ qkv,
                                                 const short* __restrict__ vt,
                                                 short* __restrict__ outp) {
  __shared__ short Ks[2][64 * 128];
  __shared__ short Vs[2][128 * 64];
  const int t = threadIdx.x, l = t & 63, w = t >> 6;
  const int wr = w >> 1, wk = w & 1;
  const int h = blockIdx.y, b = blockIdx.z;
  const int kvh = h >> 2;
  const int lo5 = l & 31, hi = l >> 5;

  const int kkey = t >> 4, kd8 = t & 15;
  const int vdd = t >> 3, vs8 = t & 7;
  const short* kbase = qkv + (size_t)(b * SEQ) * LDQKV + 2048 + kvh * HD;
  const short* vbase = vt + (size_t)((b * 4 + kvh) * 128) * SEQ;

  auto stageKV = [&](int buf, int it) {
    const int kt = it * 64;
    short* kdst = &Ks[buf][w * 512];
    short* vdst = &Vs[buf][w * 512];
#pragma unroll
    for (int i = 0; i < 4; ++i) {
      int key = i * 16 + kkey;
      int sd = (kd8 ^ (key & 15)) * 8;
      gload_lds16(kbase + (size_t)(kt + key) * LDQKV + sd, kdst + i * 2048);
    }
#pragma unroll
    for (int i = 0; i < 4; ++i) {
      int d = i * 32 + vdd;
      int ss = (vs8 ^ (d & 7)) * 8;
      gload_lds16(vbase + (size_t)d * SEQ + kt + ss, vdst + i * 2048);
    }
  };

  int koff[8], voff[4][2];
#pragma unroll
  for (int s = 0; s < 8; ++s)
    koff[s] = (wk * 32 + lo5) * 128 + (((hi + 2 * s) ^ (l & 15)) * 8);
#pragma unroll
  for (int db = 0; db < 4; ++db)
#pragma unroll
    for (int s = 0; s < 2; ++s)
      voff[db][s] =
          (db * 32 + lo5) * 64 + (((4 * wk + hi + 2 * s) ^ (l & 7)) * 8);
  const int kbloc = wk * 32 + 4 * hi;
  const int qloc = wr * 32 + lo5;

  for (int part = 0; part < 2; ++part) {
    const int qt = part ? (31 - (int)blockIdx.x) : (int)blockIdx.x;
    const int q0 = qt * 64;

    short8 qf[8];
    {
      const short* qrow =
          qkv + (size_t)(b * SEQ + q0 + wr * 32 + lo5) * LDQKV + h * HD;
#pragma unroll
      for (int s = 0; s < 8; ++s)
        qf[s] = *(const short8*)(qrow + s * 16 + hi * 8);
    }

    f32x16 of[4] = {};
    float mrun = 0.f, lsum = 0.f;

    const int nt = qt + 1;
    stageKV(0, 0);
    __syncthreads();

    for (int it = 0; it < nt; ++it) {
      const int buf = it & 1;
      if (it + 1 < nt) stageKV(buf ^ 1, it + 1);
      const short* KsC = Ks[buf];
      const short* VsC = Vs[buf];

      // QK^T: 2 accumulator chains (even/odd s), summed once
      f32x16 sca = {}, scb = {};
      __builtin_amdgcn_s_setprio(1);
#pragma unroll
      for (int s = 0; s < 4; ++s) {
        short8 kf0 = *(const short8*)(KsC + koff[2 * s]);
        short8 kf1 = *(const short8*)(KsC + koff[2 * s + 1]);
        sca = mfma32(kf0, qf[2 * s], sca);
        scb = mfma32(kf1, qf[2 * s + 1], scb);
      }
      __builtin_amdgcn_s_setprio(0);
      f32x16 sc = sca + scb;

      if (it == nt - 1) {
#pragma unroll
        for (int r = 0; r < 16; ++r) {
          const int off = (r & 3) + 8 * (r >> 2);
          if (kbloc + off > qloc) sc[r] = -1e30f;
        }
      }

      float lmax = sc[0];
#pragma unroll
      for (int r = 1; r < 16; ++r) lmax = fmaxf(lmax, sc[r]);
      if (__any(lmax > mrun + 8.f)) {
        float mx = fmaxf(lmax, __shfl_xor(lmax, 32));
        float mm = fmaxf(mrun, mx);
        float rs = fexp2(mrun - mm);
        mrun = mm;
        lsum *= rs;
#pragma unroll
        for (int db = 0; db < 4; ++db)
#pragma unroll
          for (int r = 0; r < 16; ++r) of[db][r] *= rs;
      }

      float p[16];
#pragma unroll
      for (int r = 0; r < 16; ++r) {
        p[r] = fexp2(sc[r] - mrun);
        lsum += p[r];
      }
      unsigned int pk[8];
#pragma unroll
      for (int j = 0; j < 8; ++j) pk[j] = cvt_pk(p[2 * j], p[2 * j + 1]);

      unsigned int s0 = hi ? pk[0] : pk[2];
      unsigned int s1 = hi ? pk[1] : pk[3];
      unsigned int s2 = hi ? pk[4] : pk[6];
      unsigned int s3 = hi ? pk[5] : pk[7];
      unsigned int x0 = __shfl_xor(s0, 32);
      unsigned int x1 = __shfl_xor(s1, 32);
      unsigned int x2 = __shfl_xor(s2, 32);
      unsigned int x3 = __shfl_xor(s3, 32);
      u32x4 b0w, b1w;
      b0w.x = hi ? x0 : pk[0];
      b0w.y = hi ? x1 : pk[1];
      b0w.z = hi ? pk[2] : x0;
      b0w.w = hi ? pk[3] : x1;
      b1w.x = hi ? x2 : pk[4];
      b1w.y = hi ? x3 : pk[5];
      b1w.z = hi ? pk[6] : x2;
      b1w.w = hi ? pk[7] : x3;
      short8 pb[2] = {__builtin_bit_cast(short8, b0w),
                      __builtin_bit_cast(short8, b1w)};

      __builtin_amdgcn_s_setprio(1);
#pragma unroll
      for (int s = 0; s < 2; ++s)
#pragma unroll
        for (int db = 0; db < 4; ++db) {
          short8 vf = *(const short8*)(VsC + voff[db][s]);
          of[db] = mfma32(vf, pb[s], of[db]);
        }
      __builtin_amdgcn_s_setprio(0);
      __syncthreads();
    }

    lsum += __shfl_xor(lsum, 32);
    float* og = (float*)Ks;
    float* sg = (float*)Vs;
    if (wk == 1) {
#pragma unroll
      for (int db = 0; db < 4; ++db)
#pragma unroll
        for (int r4 = 0; r4 < 4; ++r4) {
          int g = db * 4 + r4;
          f32x4 v;
#pragma unroll
          for (int j = 0; j < 4; ++j) v[j] = of[db][r4 * 4 + j];
          *(f32x4*)&og[wr * 4096 + l * 64 + ((g ^ (l & 15)) * 4)] = v;
        }
      sg[wr * 64 + l] = mrun;
      sg[128 + wr * 64 + l] = lsum;
    }
    __syncthreads();
    if (wk == 0) {
      float m1 = sg[wr * 64 + l];
      float l1 = sg[128 + wr * 64 + l];
      float mt = fmaxf(mrun, m1);
      float r0 = fexp2(mrun - mt), r1 = fexp2(m1 - mt);
      float inv = 1.0f / (lsum * r0 + l1 * r1);
      short* ob =
          outp + (size_t)(b * SEQ + q0 + wr * 32 + lo5) * 2048 + h * HD;
#pragma unroll
      for (int db = 0; db < 4; ++db) {
#pragma unroll
        for (int r4 = 0; r4 < 4; ++r4) {
          int g = db * 4 + r4;
          f32x4 o1 = *(const f32x4*)&og[wr * 4096 + l * 64 +
                                        ((g ^ (l & 15)) * 4)];
          u32x2 pko;
          float v0 = (of[db][r4 * 4 + 0] * r0 + o1[0] * r1) * inv;
          float v1 = (of[db][r4 * 4 + 1] * r0 + o1[1] * r1) * inv;
          float v2 = (of[db][r4 * 4 + 2] * r0 + o1[2] * r1) * inv;
          float v3 = (of[db][r4 * 4 + 3] * r0 + o1[3] * r1) * inv;
          pko.x = cvt_pk(v0, v1);
          pko.y = cvt_pk(v2, v3);
          *(u32x2*)(ob + db * 32 + 8 * r4 + 4 * hi) = pko;
        }
      }
    }
    __syncthreads();
  }
}

extern "C" void kernel_launch(void* const* d_in, const int* in_sizes, int n_in,
                              void* d_out, int out_size, void* d_ws,
                              size_t ws_size, hipStream_t stream) {
  const float* x = (const float*)d_in[0];
  const float* wq = (const float*)d_in[1];
  const float* wk = (const float*)d_in[2];
  const float* wv = (const float*)d_in[3];
  const float* wo = (const float*)d_in[4];
  const float* fc = (const float*)d_in[5];
  const float* fs = (const float*)d_in[6];

  char* ws = (char*)d_ws;
  short* xb = (short*)(ws);                           // [4096][2048] 16MB
  short* wT = (short*)(ws + (16ull << 20));           // [3072][2048] 12MB
  short* woT = (short*)(ws + (28ull << 20));          // [2048][2048] 8MB
  short* qkvb = (short*)(ws + (36ull << 20));         // [4096][3072] 24MB
  short* vtb = (short*)(ws + (16ull << 20));          // alias wT (dead) 4MB
  short* attn = (short*)(ws);                         // alias xb (dead) 16MB

  k_prep<<<6656, 256, 0, stream>>>(x, wq, wk, wv, wo, xb, wT, woT);
  k_gemm256<2, 0, 1><<<192, 512, 0, stream>>>(xb, wT, qkvb, fc, fs,
                                              4096, 3072, 2048);
  k_vt<<<128, 256, 0, stream>>>(qkvb, vtb);
  k_attn<<<dim3(16, 16, 2), 256, 0, stream>>>(qkvb, vtb, attn);
  k_gemm256<1, 1, 0><<<256, 512, 0, stream>>>(attn, woT, d_out, nullptr,
                                              nullptr, 4096, 2048, 2048);
}